// Round 1
// baseline (2341.423 us; speedup 1.0000x reference)
//
#include <hip/hip_runtime.h>
#include <cmath>

#define NB 8
#define NN 16384
#define NDIM 256
#define NHEAD 4
#define HDH 32
#define NCH 128
#define DIN 23
#define DOUT 16

// workspace offsets in floats
#define WS_V      ((size_t)0)          // 16,777,216
#define WS_XSP    ((size_t)16777216)   // 16,777,216
#define WS_FS     ((size_t)33554432)   // 2,097,152
#define WS_FC     ((size_t)35651584)   // 2,097,152
#define WS_INV    ((size_t)37748736)   // 64
#define WS_CS     ((size_t)37748800)   // 1536
#define WS_CC     ((size_t)37750336)   // 1536
#define WS_KVPART ((size_t)37751872)   // 1,048,576
#define WS_KMPART ((size_t)38800448)   // 32,768
#define WS_KV     ((size_t)38833216)   // 65,536
#define WS_KMEAN  ((size_t)38898752)   // 2,048
#define WS_QN2    ((size_t)38900800)   // 1,024
#define WS_KN2    ((size_t)38901824)   // 1,024
#define WS_G      ((size_t)38902848)   // 131,072
#define WS_ATTN   ((size_t)39033920)   // 131,072
#define WS_BMAT   ((size_t)39164992)   // 524,288

// ---------------------------------------------------------------- setup
__global__ void k_setup(const float* __restrict__ sc, const float* __restrict__ ccin,
                        float* __restrict__ inv, float* __restrict__ cs, float* __restrict__ cc)
{
    int t = threadIdx.x; // 64 threads
    if (t < DIN) inv[t] = (float)pow(10000.0, -((double)(2 * t)) / 64.0);
    int h = t >> 4, d = t & 15;
    float ss = 0.f, s2 = 0.f;
    for (int D = 0; D < DIN; ++D) { ss += sc[(h*DIN + D)*DOUT + d]; s2 += ccin[(h*DIN + D)*DOUT + d]; }
    float rs = 1.f / ss, r2 = 1.f / s2;
    for (int D = 0; D < DIN; ++D) {
        cs[(h*DIN + D)*DOUT + d] = sc[(h*DIN + D)*DOUT + d] * rs;
        cc[(h*DIN + D)*DOUT + d] = ccin[(h*DIN + D)*DOUT + d] * r2;
    }
}

// ---------------------------------------------------------------- FoPE tables fs/fc: [h][t][32]
__global__ __launch_bounds__(64) void k_tables(const float* __restrict__ inv, const float* __restrict__ cs,
                                               const float* __restrict__ cc,
                                               float* __restrict__ fs, float* __restrict__ fc)
{
    int tpos = blockIdx.x;
    int t = threadIdx.x;
    __shared__ float ssin[DIN], scos[DIN];
    if (t < DIN) { float fr = (float)tpos * inv[t]; ssin[t] = sinf(fr); scos[t] = cosf(fr); }
    __syncthreads();
    int h = t >> 4, d = t & 15;
    float as = 0.f, ac = 0.f;
    for (int D = 0; D < DIN; ++D) { as += ssin[D]*cs[(h*DIN + D)*DOUT + d]; ac += scos[D]*cc[(h*DIN + D)*DOUT + d]; }
    size_t base = ((size_t)h*NN + tpos)*32;
    fs[base + d] = as;      fc[base + d] = ac;
    fs[base + 16 + d] = 1.f; fc[base + 16 + d] = 1.f;
}

// ---------------------------------------------------------------- QKV GEMM: C[m, 0:384] = x @ [Wq;Wk;Wv]^T
__global__ __launch_bounds__(256) void k_qkv(const float* __restrict__ x,
    const float* __restrict__ Wq, const float* __restrict__ Wk, const float* __restrict__ Wv,
    const float* __restrict__ bq, const float* __restrict__ bk, const float* __restrict__ bv,
    float* __restrict__ q, float* __restrict__ k, float* __restrict__ v)
{
    __shared__ float As[32][68];
    __shared__ float Bs[32][68];
    int m0 = blockIdx.x * 64;
    int col0 = blockIdx.y * 64;
    int t = threadIdx.x;
    int tx = t & 15, ty = t >> 4;
    float acc[4][4] = {};
    for (int k0 = 0; k0 < 256; k0 += 32) {
        #pragma unroll
        for (int i = 0; i < 8; ++i) {
            int lin = t + i*256;
            int r = lin >> 5, c = lin & 31;
            As[c][r] = x[(size_t)(m0 + r)*256 + k0 + c];
        }
        #pragma unroll
        for (int i = 0; i < 8; ++i) {
            int lin = t + i*256;
            int col = lin >> 5, c = lin & 31;
            int g = col0 + col;
            const float* W = (g < 128) ? Wq : (g < 256) ? Wk : Wv;
            Bs[c][col] = W[(size_t)(g & 127)*256 + k0 + c];
        }
        __syncthreads();
        #pragma unroll
        for (int kk = 0; kk < 32; ++kk) {
            float4 av = *reinterpret_cast<const float4*>(&As[kk][ty*4]);
            float4 bv4 = *reinterpret_cast<const float4*>(&Bs[kk][tx*4]);
            float a[4] = {av.x, av.y, av.z, av.w};
            float bb[4] = {bv4.x, bv4.y, bv4.z, bv4.w};
            #pragma unroll
            for (int i = 0; i < 4; ++i)
                #pragma unroll
                for (int j = 0; j < 4; ++j) acc[i][j] += a[i]*bb[j];
        }
        __syncthreads();
    }
    #pragma unroll
    for (int i = 0; i < 4; ++i) {
        size_t m = (size_t)m0 + ty*4 + i;
        #pragma unroll
        for (int j = 0; j < 4; ++j) {
            int g = col0 + tx*4 + j;
            if (g < 128)      q[m*128 + g]       = acc[i][j] + bq[g];
            else if (g < 256) k[m*128 + (g-128)] = acc[i][j] + bk[g-128];
            else              v[m*128 + (g-256)] = acc[i][j] + bv[g-256];
        }
    }
}

// ---------------------------------------------------------------- depthwise 3x3 LEPE conv -> xsp
__global__ __launch_bounds__(256) void k_conv(const float* __restrict__ v, const float* __restrict__ w,
                                              const float* __restrict__ bias, float* __restrict__ xsp)
{
    __shared__ float wsm[NCH*9];
    __shared__ float bsm[NCH];
    int t = threadIdx.x;
    for (int i = t; i < NCH*9; i += 256) wsm[i] = w[i];
    if (t < NCH) bsm[t] = bias[t];
    __syncthreads();
    int c = t & 127, jj = t >> 7;
    int j = blockIdx.x*2 + jj;
    int i = blockIdx.y;
    int b = blockIdx.z;
    float acc = bsm[c];
    #pragma unroll
    for (int ki = 0; ki < 3; ++ki) {
        int ii = i + ki - 1;
        if (ii < 0 || ii >= 128) continue;
        #pragma unroll
        for (int kj = 0; kj < 3; ++kj) {
            int jx = j + kj - 1;
            if (jx < 0 || jx >= 128) continue;
            acc += wsm[c*9 + ki*3 + kj] * v[((size_t)b*NN + ii*128 + jx)*128 + c];
        }
    }
    xsp[((size_t)b*NN + i*128 + j)*128 + c] = acc;
}

// ---------------------------------------------------------------- kv-state + kmean accumulation (per-position wave)
__global__ __launch_bounds__(256) void k_kvacc(const float* __restrict__ k, const float* __restrict__ v,
    const float* __restrict__ Whk, const float* __restrict__ bhk,
    const float* __restrict__ fs, const float* __restrict__ fc,
    float* __restrict__ kvpart, float* __restrict__ kmpart)
{
    __shared__ float Wsh[32][33];
    __shared__ float bsh[32];
    __shared__ float kvred[4][64][33];
    __shared__ float kms[4][64];
    int bh = blockIdx.y, b = bh >> 2, h = bh & 3;
    int chunk = blockIdx.x;
    int t = threadIdx.x, wave = t >> 6, lane = t & 63;
    for (int i = t; i < 1024; i += 256) Wsh[i>>5][i&31] = Whk[i];
    if (t < 32) bsh[t] = bhk[t];
    __syncthreads();
    float kvacc[32];
    #pragma unroll
    for (int d = 0; d < 32; ++d) kvacc[d] = 0.f;
    float kmacc = 0.f;
    int n0 = chunk*1024 + wave*256;
    int e = lane & 31;
    size_t rb = ((size_t)(b*NN + n0))*128 + h*32;
    size_t fb = ((size_t)h*NN + n0)*32 + e;
    float rv = (lane < 32) ? k[rb + lane] : v[rb + (lane - 32)];
    float fsv = fs[fb], fcv = fc[fb];
    for (int it = 0; it < 256; ++it) {
        float rvn = 0.f, fsn = 0.f, fcn = 0.f;
        if (it < 255) {
            rvn = (lane < 32) ? k[rb + 128 + lane] : v[rb + 128 + (lane - 32)];
            fsn = fs[fb + 32]; fcn = fc[fb + 32];
        }
        float y = bsh[e];
        #pragma unroll
        for (int dd = 0; dd < 32; ++dd) y += Wsh[e][dd] * __shfl(rv, dd);
        float sgn = (lane < 32) ? 2.f : -2.f;
        float scv = sgn * y;
        float m = scv;
        #pragma unroll
        for (int off = 32; off >= 1; off >>= 1) m = fmaxf(m, __shfl_xor(m, off));
        float p = expf(scv - m);
        float sum = p;
        #pragma unroll
        for (int off = 32; off >= 1; off >>= 1) sum += __shfl_xor(sum, off);
        float kf = p / sum;
        kmacc += kf;
        float other = __shfl_xor(kf, 32);
        float rot = (lane < 32) ? -other : other;
        float kfope = kf*fcv - rot*fsv;
        #pragma unroll
        for (int d = 0; d < 32; ++d) kvacc[d] += kfope * __shfl(rv, 32 + d);
        rv = rvn; fsv = fsn; fcv = fcn;
        rb += 128; fb += 32;
    }
    #pragma unroll
    for (int d = 0; d < 32; ++d) kvred[wave][lane][d] = kvacc[d];
    kms[wave][lane] = kmacc;
    __syncthreads();
    size_t pbase = (size_t)(bh*16 + chunk);
    for (int idx = t; idx < 2048; idx += 256) {
        int ee = idx >> 5, d = idx & 31;
        kvpart[pbase*2048 + idx] = kvred[0][ee][d]+kvred[1][ee][d]+kvred[2][ee][d]+kvred[3][ee][d];
    }
    if (t < 64) kmpart[pbase*64 + t] = kms[0][t]+kms[1][t]+kms[2][t]+kms[3][t];
}

// ---------------------------------------------------------------- reduce partials -> kv, kmean (x 1/N)
__global__ __launch_bounds__(256) void k_kvred(const float* __restrict__ kvpart, const float* __restrict__ kmpart,
                                               float* __restrict__ kv, float* __restrict__ kmean)
{
    int bh = blockIdx.x, t = threadIdx.x;
    const float scale = 1.f/16384.f;
    for (int idx = t; idx < 2048; idx += 256) {
        float s = 0.f;
        for (int c = 0; c < 16; ++c) s += kvpart[((size_t)(bh*16 + c))*2048 + idx];
        kv[(size_t)bh*2048 + idx] = s*scale;
    }
    if (t < 64) {
        float s = 0.f;
        for (int c = 0; c < 16; ++c) s += kmpart[(bh*16 + c)*64 + t];
        kmean[bh*64 + t] = s*scale;
    }
}

// ---------------------------------------------------------------- xs = z * (q_fope @ kv); adds into xsp
__global__ __launch_bounds__(256) void k_xs(const float* __restrict__ q,
    const float* __restrict__ Whq, const float* __restrict__ bhq,
    const float* __restrict__ fs, const float* __restrict__ fc,
    const float* __restrict__ kv, const float* __restrict__ kmean,
    float* __restrict__ xsp)
{
    __shared__ float Wsh[32][33];
    __shared__ float bsh[32];
    __shared__ float kvs[64][33];
    int bh = blockIdx.y, b = bh >> 2, h = bh & 3;
    int chunk = blockIdx.x;
    int t = threadIdx.x, wave = t >> 6, lane = t & 63;
    for (int i = t; i < 1024; i += 256) Wsh[i>>5][i&31] = Whq[i];
    if (t < 32) bsh[t] = bhq[t];
    for (int i = t; i < 2048; i += 256) kvs[i>>5][i&31] = kv[(size_t)bh*2048 + i];
    __syncthreads();
    int e = lane & 31;
    float kmv = kmean[bh*64 + lane];
    int n0 = chunk*1024 + wave*256;
    size_t rb = ((size_t)(b*NN + n0))*128 + h*32;
    size_t fb = ((size_t)h*NN + n0)*32 + e;
    float rv = (lane < 32) ? q[rb + lane] : 0.f;
    float fsv = fs[fb], fcv = fc[fb];
    for (int it = 0; it < 256; ++it) {
        float rvn = 0.f, fsn = 0.f, fcn = 0.f;
        if (it < 255) {
            rvn = (lane < 32) ? q[rb + 128 + lane] : 0.f;
            fsn = fs[fb + 32]; fcn = fc[fb + 32];
        }
        float y = bsh[e];
        #pragma unroll
        for (int dd = 0; dd < 32; ++dd) y += Wsh[e][dd] * __shfl(rv, dd);
        float sgn = (lane < 32) ? 2.f : -2.f;
        float scv = sgn * y;
        float m = scv;
        #pragma unroll
        for (int off = 32; off >= 1; off >>= 1) m = fmaxf(m, __shfl_xor(m, off));
        float p = expf(scv - m);
        float sum = p;
        #pragma unroll
        for (int off = 32; off >= 1; off >>= 1) sum += __shfl_xor(sum, off);
        float qf = p / sum;
        float zd = qf * kmv;
        #pragma unroll
        for (int off = 32; off >= 1; off >>= 1) zd += __shfl_xor(zd, off);
        float z = 1.f / (zd + 1e-6f);
        float other = __shfl_xor(qf, 32);
        float rot = (lane < 32) ? -other : other;
        float qfope = qf*fcv - rot*fsv;
        float acc = 0.f;
        #pragma unroll
        for (int ee = 0; ee < 64; ++ee) acc += __shfl(qfope, ee) * kvs[ee][e];
        acc *= z;
        if (lane < 32) xsp[rb + lane] += acc;
        rv = rvn; fsv = fsn; fcv = fcn;
        rb += 128; fb += 32;
    }
}

// ---------------------------------------------------------------- channel norms (sum of squares over n)
__global__ __launch_bounds__(256) void k_norms(const float* __restrict__ q, const float* __restrict__ k,
                                               float* __restrict__ qn2, float* __restrict__ kn2)
{
    __shared__ float sq[256], sk[256];
    int b = blockIdx.y, chunk = blockIdx.x;
    int t = threadIdx.x, c = t & 127, half = t >> 7;
    float qa = 0.f, ka = 0.f;
    size_t base = ((size_t)b*NN + chunk*256 + half)*128 + c;
    for (int r = 0; r < 128; ++r) {
        float xq = q[base], xk = k[base];
        qa += xq*xq; ka += xk*xk;
        base += 256;
    }
    sq[t] = qa; sk[t] = ka;
    __syncthreads();
    if (t < 128) {
        atomicAdd(&qn2[b*128 + c], sq[t] + sq[t+128]);
        atomicAdd(&kn2[b*128 + c], sk[t] + sk[t+128]);
    }
}

// ---------------------------------------------------------------- gram G[b,c,d] = sum_l q[b,l,c] k[b,l,d]
__global__ __launch_bounds__(256) void k_gram(const float* __restrict__ q, const float* __restrict__ k,
                                              float* __restrict__ G)
{
    __shared__ float qt[64][36], kt[64][36];
    int ls = blockIdx.x;
    int ct = blockIdx.y >> 2, dt = blockIdx.y & 3;
    int b = blockIdx.z;
    int c0 = ct*32, d0 = dt*32;
    int t = threadIdx.x;
    int di = t & 31, cb = (t >> 5)*4;
    float acc[4] = {};
    for (int sub = 0; sub < 32; ++sub) {
        int l0 = ls*2048 + sub*64;
        #pragma unroll
        for (int i = 0; i < 8; ++i) {
            int lin = t + i*256;
            int r = lin >> 5, col = lin & 31;
            size_t rowb = ((size_t)b*NN + l0 + r)*128;
            qt[r][col] = q[rowb + c0 + col];
            kt[r][col] = k[rowb + d0 + col];
        }
        __syncthreads();
        #pragma unroll 8
        for (int l = 0; l < 64; ++l) {
            float kvl = kt[l][di];
            float4 qv = *reinterpret_cast<const float4*>(&qt[l][cb]);
            acc[0] += qv.x*kvl; acc[1] += qv.y*kvl; acc[2] += qv.z*kvl; acc[3] += qv.w*kvl;
        }
        __syncthreads();
    }
    #pragma unroll
    for (int j = 0; j < 4; ++j)
        atomicAdd(&G[((size_t)b*128 + c0 + cb + j)*128 + d0 + di], acc[j]);
}

// ---------------------------------------------------------------- channel attention softmax
__global__ __launch_bounds__(128) void k_attnsm(const float* __restrict__ G, const float* __restrict__ qn2,
    const float* __restrict__ kn2, const float* __restrict__ temp, float* __restrict__ attn)
{
    __shared__ float red[128];
    int row = blockIdx.x;            // b*128 + c
    int b = row >> 7, c = row & 127;
    int t = threadIdx.x;             // d
    float qn = fmaxf(sqrtf(qn2[b*128 + c]), 1e-12f);
    float kn = fmaxf(sqrtf(kn2[b*128 + t]), 1e-12f);
    float val = G[(size_t)row*128 + t] / (qn*kn) * temp[c];
    red[t] = val; __syncthreads();
    for (int s = 64; s > 0; s >>= 1) { if (t < s) red[t] = fmaxf(red[t], red[t+s]); __syncthreads(); }
    float mm = red[0]; __syncthreads();
    float ev = expf(val - mm);
    red[t] = ev; __syncthreads();
    for (int s = 64; s > 0; s >>= 1) { if (t < s) red[t] += red[t+s]; __syncthreads(); }
    attn[(size_t)row*128 + t] = ev / red[0];
}

// ---------------------------------------------------------------- build per-batch B matrix: [Wp_left^T ; M2]
__global__ __launch_bounds__(256) void k_bmat(const float* __restrict__ attn, const float* __restrict__ Wp,
                                              float* __restrict__ Bmat)
{
    int b = blockIdx.y, kk = blockIdx.x, o = threadIdx.x;
    if (kk < 128) {
        Bmat[((size_t)b*256 + kk)*256 + o] = Wp[(size_t)o*256 + kk];
    } else {
        int d = kk - 128;
        __shared__ float a[128];
        if (o < 128) a[o] = attn[((size_t)b*128 + o)*128 + d];
        __syncthreads();
        float acc = 0.f;
        for (int c = 0; c < 128; ++c) acc += a[c] * Wp[(size_t)o*256 + 128 + c];
        Bmat[((size_t)b*256 + kk)*256 + o] = acc;
    }
}

// ---------------------------------------------------------------- final GEMM: out = [xsp | v] @ Bmat_b + bp
__global__ __launch_bounds__(256) void k_out(const float* __restrict__ xsp, const float* __restrict__ v,
    const float* __restrict__ Bmat, const float* __restrict__ bp, float* __restrict__ out)
{
    __shared__ float As[32][68];
    __shared__ float Bs[32][68];
    int b = blockIdx.z;
    int m0 = blockIdx.x*64, col0 = blockIdx.y*64;
    int t = threadIdx.x, tx = t & 15, ty = t >> 4;
    const float* Bb = Bmat + (size_t)b*65536;
    float acc[4][4] = {};
    for (int k0 = 0; k0 < 256; k0 += 32) {
        const float* Asrc = (k0 < 128) ? xsp : v;
        int kk0 = k0 & 127;
        #pragma unroll
        for (int i = 0; i < 8; ++i) {
            int lin = t + i*256;
            int r = lin >> 5, c = lin & 31;
            As[c][r] = Asrc[((size_t)b*NN + m0 + r)*128 + kk0 + c];
        }
        #pragma unroll
        for (int i = 0; i < 8; ++i) {
            int lin = t + i*256;
            int r = lin >> 6, col = lin & 63;
            Bs[r][col] = Bb[(size_t)(k0 + r)*256 + col0 + col];
        }
        __syncthreads();
        #pragma unroll
        for (int kk = 0; kk < 32; ++kk) {
            float4 av = *reinterpret_cast<const float4*>(&As[kk][ty*4]);
            float4 bv4 = *reinterpret_cast<const float4*>(&Bs[kk][tx*4]);
            float a[4] = {av.x, av.y, av.z, av.w};
            float bb[4] = {bv4.x, bv4.y, bv4.z, bv4.w};
            #pragma unroll
            for (int i = 0; i < 4; ++i)
                #pragma unroll
                for (int j = 0; j < 4; ++j) acc[i][j] += a[i]*bb[j];
        }
        __syncthreads();
    }
    #pragma unroll
    for (int i = 0; i < 4; ++i) {
        size_t m = (size_t)b*NN + m0 + ty*4 + i;
        #pragma unroll
        for (int j = 0; j < 4; ++j) {
            int g = col0 + tx*4 + j;
            out[m*256 + g] = acc[i][j] + bp[g];
        }
    }
}

extern "C" void kernel_launch(void* const* d_in, const int* in_sizes, int n_in,
                              void* d_out, int out_size, void* d_ws, size_t ws_size,
                              hipStream_t stream)
{
    (void)in_sizes; (void)n_in; (void)out_size; (void)ws_size;
    const float* x    = (const float*)d_in[0];
    const float* Wq   = (const float*)d_in[1];
    const float* bq   = (const float*)d_in[2];
    const float* Wk   = (const float*)d_in[3];
    const float* bk   = (const float*)d_in[4];
    const float* Wv   = (const float*)d_in[5];
    const float* bv   = (const float*)d_in[6];
    const float* Whq  = (const float*)d_in[7];
    const float* bhq  = (const float*)d_in[8];
    const float* Whk  = (const float*)d_in[9];
    const float* bhk  = (const float*)d_in[10];
    const float* sinc = (const float*)d_in[11];
    const float* cosc = (const float*)d_in[12];
    const float* lw   = (const float*)d_in[13];
    const float* lb   = (const float*)d_in[14];
    const float* temp = (const float*)d_in[15];
    const float* Wp   = (const float*)d_in[16];
    const float* bp   = (const float*)d_in[17];

    float* out = (float*)d_out;
    float* q   = out + 33554432;   // (8,16384,128)
    float* k   = out + 50331648;   // (8,16384,128)
    float* ws  = (float*)d_ws;

    float* v      = ws + WS_V;
    float* xsp    = ws + WS_XSP;
    float* fs     = ws + WS_FS;
    float* fc     = ws + WS_FC;
    float* inv    = ws + WS_INV;
    float* cs     = ws + WS_CS;
    float* cc     = ws + WS_CC;
    float* kvpart = ws + WS_KVPART;
    float* kmpart = ws + WS_KMPART;
    float* kv     = ws + WS_KV;
    float* kmean  = ws + WS_KMEAN;
    float* qn2    = ws + WS_QN2;
    float* kn2    = ws + WS_KN2;
    float* G      = ws + WS_G;
    float* attn   = ws + WS_ATTN;
    float* Bmat   = ws + WS_BMAT;

    // zero atomic targets (qn2 and kn2 are contiguous)
    hipMemsetAsync(qn2, 0, 2048*sizeof(float), stream);
    hipMemsetAsync(G, 0, 131072*sizeof(float), stream);

    k_setup<<<1, 64, 0, stream>>>(sinc, cosc, inv, cs, cc);
    k_tables<<<16384, 64, 0, stream>>>(inv, cs, cc, fs, fc);
    k_qkv<<<dim3(2048, 6), 256, 0, stream>>>(x, Wq, Wk, Wv, bq, bk, bv, q, k, v);
    k_conv<<<dim3(64, 128, 8), 256, 0, stream>>>(v, lw, lb, xsp);
    k_kvacc<<<dim3(16, 32), 256, 0, stream>>>(k, v, Whk, bhk, fs, fc, kvpart, kmpart);
    k_kvred<<<32, 256, 0, stream>>>(kvpart, kmpart, kv, kmean);
    k_xs<<<dim3(16, 32), 256, 0, stream>>>(q, Whq, bhq, fs, fc, kv, kmean, xsp);
    k_norms<<<dim3(64, 8), 256, 0, stream>>>(q, k, qn2, kn2);
    k_gram<<<dim3(8, 16, 8), 256, 0, stream>>>(q, k, G);
    k_attnsm<<<1024, 128, 0, stream>>>(G, qn2, kn2, temp, attn);
    k_bmat<<<dim3(256, 8), 256, 0, stream>>>(attn, Wp, Bmat);
    k_out<<<dim3(256, 4, 8), 256, 0, stream>>>(xsp, v, Bmat, bp, out);
}

// Round 2
// 1387.445 us; speedup vs baseline: 1.6876x; 1.6876x over previous
//
#include <hip/hip_runtime.h>
#include <cmath>

#define NB 8
#define NN 16384
#define NDIM 256
#define NHEAD 4
#define HDH 32
#define NCH 128
#define DIN 23
#define DOUT 16

// workspace offsets in floats (total 38,673,472 floats = 154.7 MB)
#define WS_V      ((size_t)0)          // 16,777,216
#define WS_XSP    ((size_t)16777216)   // 16,777,216
#define WS_FS     ((size_t)33554432)   // 1,048,576  [4][16384][16]
#define WS_FC     ((size_t)34603008)   // 1,048,576
#define WS_INV    ((size_t)35651584)   // 64
#define WS_CS     ((size_t)35651648)   // 1536
#define WS_CC     ((size_t)35653184)   // 1536
#define WS_KVPART ((size_t)35654720)   // 32*32*2048 = 2,097,152
#define WS_KMPART ((size_t)37751872)   // 32*32*64 = 65,536
#define WS_KV     ((size_t)37817408)   // 65,536
#define WS_KMEAN  ((size_t)37882944)   // 2,048
#define WS_QN2    ((size_t)37884992)   // 1,024
#define WS_KN2    ((size_t)37886016)   // 1,024
#define WS_G      ((size_t)37887040)   // 131,072
#define WS_ATTN   ((size_t)38018112)   // 131,072
#define WS_BMAT   ((size_t)38149184)   // 524,288

// ---------------------------------------------------------------- setup
__global__ void k_setup(const float* __restrict__ sc, const float* __restrict__ ccin,
                        float* __restrict__ inv, float* __restrict__ cs, float* __restrict__ cc)
{
    int t = threadIdx.x; // 64 threads
    if (t < DIN) inv[t] = (float)pow(10000.0, -((double)(2 * t)) / 64.0);
    int h = t >> 4, d = t & 15;
    float ss = 0.f, s2 = 0.f;
    for (int D = 0; D < DIN; ++D) { ss += sc[(h*DIN + D)*DOUT + d]; s2 += ccin[(h*DIN + D)*DOUT + d]; }
    float rs = 1.f / ss, r2 = 1.f / s2;
    for (int D = 0; D < DIN; ++D) {
        cs[(h*DIN + D)*DOUT + d] = sc[(h*DIN + D)*DOUT + d] * rs;
        cc[(h*DIN + D)*DOUT + d] = ccin[(h*DIN + D)*DOUT + d] * r2;
    }
}

// ---------------------------------------------------------------- FoPE tables fs/fc: [h][t][16]
__global__ __launch_bounds__(64) void k_tables(const float* __restrict__ inv, const float* __restrict__ cs,
                                               const float* __restrict__ cc,
                                               float* __restrict__ fs, float* __restrict__ fc)
{
    int tpos = blockIdx.x;
    int t = threadIdx.x;
    __shared__ float ssin[DIN], scos[DIN];
    if (t < DIN) { float fr = (float)tpos * inv[t]; ssin[t] = sinf(fr); scos[t] = cosf(fr); }
    __syncthreads();
    int h = t >> 4, d = t & 15;
    float as = 0.f, ac = 0.f;
    for (int D = 0; D < DIN; ++D) { as += ssin[D]*cs[(h*DIN + D)*DOUT + d]; ac += scos[D]*cc[(h*DIN + D)*DOUT + d]; }
    size_t base = ((size_t)h*NN + tpos)*16;
    fs[base + d] = as;      fc[base + d] = ac;
}

// ---------------------------------------------------------------- QKV GEMM: C[m, 0:384] = x @ [Wq;Wk;Wv]^T
__global__ __launch_bounds__(256) void k_qkv(const float* __restrict__ x,
    const float* __restrict__ Wq, const float* __restrict__ Wk, const float* __restrict__ Wv,
    const float* __restrict__ bq, const float* __restrict__ bk, const float* __restrict__ bv,
    float* __restrict__ q, float* __restrict__ k, float* __restrict__ v)
{
    __shared__ float As[32][68];
    __shared__ float Bs[32][68];
    int m0 = blockIdx.x * 64;
    int col0 = blockIdx.y * 64;
    int t = threadIdx.x;
    int tx = t & 15, ty = t >> 4;
    float acc[4][4] = {};
    for (int k0 = 0; k0 < 256; k0 += 32) {
        #pragma unroll
        for (int i = 0; i < 8; ++i) {
            int lin = t + i*256;
            int r = lin >> 5, c = lin & 31;
            As[c][r] = x[(size_t)(m0 + r)*256 + k0 + c];
        }
        #pragma unroll
        for (int i = 0; i < 8; ++i) {
            int lin = t + i*256;
            int col = lin >> 5, c = lin & 31;
            int g = col0 + col;
            const float* W = (g < 128) ? Wq : (g < 256) ? Wk : Wv;
            Bs[c][col] = W[(size_t)(g & 127)*256 + k0 + c];
        }
        __syncthreads();
        #pragma unroll
        for (int kk = 0; kk < 32; ++kk) {
            float4 av = *reinterpret_cast<const float4*>(&As[kk][ty*4]);
            float4 bv4 = *reinterpret_cast<const float4*>(&Bs[kk][tx*4]);
            float a[4] = {av.x, av.y, av.z, av.w};
            float bb[4] = {bv4.x, bv4.y, bv4.z, bv4.w};
            #pragma unroll
            for (int i = 0; i < 4; ++i)
                #pragma unroll
                for (int j = 0; j < 4; ++j) acc[i][j] += a[i]*bb[j];
        }
        __syncthreads();
    }
    #pragma unroll
    for (int i = 0; i < 4; ++i) {
        size_t m = (size_t)m0 + ty*4 + i;
        #pragma unroll
        for (int j = 0; j < 4; ++j) {
            int g = col0 + tx*4 + j;
            if (g < 128)      q[m*128 + g]       = acc[i][j] + bq[g];
            else if (g < 256) k[m*128 + (g-128)] = acc[i][j] + bk[g-128];
            else              v[m*128 + (g-256)] = acc[i][j] + bv[g-256];
        }
    }
}

// ---------------------------------------------------------------- depthwise 3x3 LEPE conv -> xsp
__global__ __launch_bounds__(256) void k_conv(const float* __restrict__ v, const float* __restrict__ w,
                                              const float* __restrict__ bias, float* __restrict__ xsp)
{
    __shared__ float wsm[NCH*9];
    __shared__ float bsm[NCH];
    int t = threadIdx.x;
    for (int i = t; i < NCH*9; i += 256) wsm[i] = w[i];
    if (t < NCH) bsm[t] = bias[t];
    __syncthreads();
    int c = t & 127, jj = t >> 7;
    int j = blockIdx.x*2 + jj;
    int i = blockIdx.y;
    int b = blockIdx.z;
    float acc = bsm[c];
    #pragma unroll
    for (int ki = 0; ki < 3; ++ki) {
        int ii = i + ki - 1;
        if (ii < 0 || ii >= 128) continue;
        #pragma unroll
        for (int kj = 0; kj < 3; ++kj) {
            int jx = j + kj - 1;
            if (jx < 0 || jx >= 128) continue;
            acc += wsm[c*9 + ki*3 + kj] * v[((size_t)b*NN + ii*128 + jx)*128 + c];
        }
    }
    xsp[((size_t)b*NN + i*128 + j)*128 + c] = acc;
}

// ---------------------------------------------------------------- fused k-features + kv partial accumulation
// grid (32 chunks, 32 bh), block 256. Each block: 512 positions in 4 subtiles of 128.
// lane e = t&31 (feature), group g = t>>5 (8 groups of 16 positions).
__global__ __launch_bounds__(256) void k_featkv(
    const float* __restrict__ kin, const float* __restrict__ vin,
    const float* __restrict__ W, const float* __restrict__ bvec,
    const float* __restrict__ fs, const float* __restrict__ fc,
    float* __restrict__ kvpart, float* __restrict__ kmpart)
{
    __shared__ float th[128][32];    // k tile, then v tile
    __shared__ float kfs[128][68];   // k_fope features [pos][64]
    __shared__ float kms[8][64];
    int bh = blockIdx.y, b = bh >> 2, h = bh & 3;
    int chunk = blockIdx.x;
    int t = threadIdx.x;
    int e = t & 31, g = t >> 5;
    float Wr[32];
    #pragma unroll
    for (int dd = 0; dd < 32; ++dd) Wr[dd] = W[e*32 + dd];
    float bias = bvec[e];
    float km_lo = 0.f, km_hi = 0.f;
    float acc[8] = {};
    for (int sub = 0; sub < 4; ++sub) {
        int n0 = chunk*512 + sub*128;
        // stage k tile
        __syncthreads();
        for (int i = t; i < 4096; i += 256) {
            int pos = i >> 5, dd = i & 31;
            th[pos][dd] = kin[((size_t)(b*NN + n0 + pos))*128 + h*32 + dd];
        }
        __syncthreads();
        // phase 1: features
        for (int p = 0; p < 16; ++p) {
            int pos = g*16 + p;
            float y = bias;
            #pragma unroll
            for (int q4 = 0; q4 < 8; ++q4) {
                float4 tv = *reinterpret_cast<const float4*>(&th[pos][q4*4]);
                y += Wr[q4*4]*tv.x + Wr[q4*4+1]*tv.y + Wr[q4*4+2]*tv.z + Wr[q4*4+3]*tv.w;
            }
            float y2 = 2.f*y;
            float m = fmaxf(y2, -y2);
            #pragma unroll
            for (int off = 16; off >= 1; off >>= 1) m = fmaxf(m, __shfl_xor(m, off));
            float elo = __expf(y2 - m), ehi = __expf(-y2 - m);
            float s = elo + ehi;
            #pragma unroll
            for (int off = 16; off >= 1; off >>= 1) s += __shfl_xor(s, off);
            float rs = 1.f / s;
            float klo = elo*rs, khi = ehi*rs;
            km_lo += klo; km_hi += khi;
            size_t fbase = ((size_t)h*NN + n0 + pos)*16 + e;
            float fsv = (e < 16) ? fs[fbase] : 1.0f;
            float fcv = (e < 16) ? fc[fbase] : 1.0f;
            kfs[pos][e]      = klo*fcv + khi*fsv;
            kfs[pos][32 + e] = khi*fcv - klo*fsv;
        }
        // stage v tile (reuse th)
        __syncthreads();
        for (int i = t; i < 4096; i += 256) {
            int pos = i >> 5, dd = i & 31;
            th[pos][dd] = vin[((size_t)(b*NN + n0 + pos))*128 + h*32 + dd];
        }
        __syncthreads();
        // phase 2: kv partial: acc[j] += kfs[n][g*8+j] * v[n][e]
        for (int n = 0; n < 128; ++n) {
            float vv = th[n][e];
            float4 ka = *reinterpret_cast<const float4*>(&kfs[n][g*8]);
            float4 kb = *reinterpret_cast<const float4*>(&kfs[n][g*8+4]);
            acc[0] += ka.x*vv; acc[1] += ka.y*vv; acc[2] += ka.z*vv; acc[3] += ka.w*vv;
            acc[4] += kb.x*vv; acc[5] += kb.y*vv; acc[6] += kb.z*vv; acc[7] += kb.w*vv;
        }
    }
    // write kv partials
    size_t pb = ((size_t)(bh*32 + chunk))*2048 + (size_t)(g*8)*32 + e;
    #pragma unroll
    for (int j = 0; j < 8; ++j) kvpart[pb + (size_t)j*32] = acc[j];
    // kmean partials
    kms[g][e] = km_lo; kms[g][32 + e] = km_hi;
    __syncthreads();
    if (t < 64) {
        float s = 0.f;
        #pragma unroll
        for (int gg = 0; gg < 8; ++gg) s += kms[gg][t];
        kmpart[(size_t)(bh*32 + chunk)*64 + t] = s;
    }
}

// ---------------------------------------------------------------- reduce kv partials (x 1/N)
__global__ __launch_bounds__(256) void k_kvred2(const float* __restrict__ kvpart, float* __restrict__ kv)
{
    int bh = blockIdx.x >> 3, part = blockIdx.x & 7;
    int idx = part*256 + threadIdx.x;
    float s = 0.f;
    for (int c = 0; c < 32; ++c) s += kvpart[((size_t)(bh*32 + c))*2048 + idx];
    kv[(size_t)bh*2048 + idx] = s * (1.f/16384.f);
}

__global__ __launch_bounds__(64) void k_kmred(const float* __restrict__ kmpart, float* __restrict__ kmean)
{
    int bh = blockIdx.x, t = threadIdx.x;
    float s = 0.f;
    for (int c = 0; c < 32; ++c) s += kmpart[(size_t)(bh*32 + c)*64 + t];
    kmean[bh*64 + t] = s * (1.f/16384.f);
}

// ---------------------------------------------------------------- fused q-features + xs GEMM (adds into xsp)
// grid (128 chunks, 32 bh), block 256; 128 positions per block.
__global__ __launch_bounds__(256) void k_featxs(
    const float* __restrict__ qin, const float* __restrict__ W, const float* __restrict__ bvec,
    const float* __restrict__ fs, const float* __restrict__ fc,
    const float* __restrict__ kv, const float* __restrict__ kmean,
    float* __restrict__ xsp)
{
    __shared__ float th[128][32];    // q tile
    __shared__ float qfs[128][68];   // z * q_fope [pos][64]
    __shared__ float kvs[64][32];    // kv[e1][e2]
    int bh = blockIdx.y, b = bh >> 2, h = bh & 3;
    int n0 = blockIdx.x * 128;
    int t = threadIdx.x;
    int e = t & 31, g = t >> 5;
    float Wr[32];
    #pragma unroll
    for (int dd = 0; dd < 32; ++dd) Wr[dd] = W[e*32 + dd];
    float bias = bvec[e];
    float km_lo = kmean[bh*64 + e], km_hi = kmean[bh*64 + 32 + e];
    for (int i = t; i < 2048; i += 256) kvs[i>>5][i&31] = kv[(size_t)bh*2048 + i];
    for (int i = t; i < 4096; i += 256) {
        int pos = i >> 5, dd = i & 31;
        th[pos][dd] = qin[((size_t)(b*NN + n0 + pos))*128 + h*32 + dd];
    }
    __syncthreads();
    // phase 1: q features, z folded in
    for (int p = 0; p < 16; ++p) {
        int pos = g*16 + p;
        float y = bias;
        #pragma unroll
        for (int q4 = 0; q4 < 8; ++q4) {
            float4 tv = *reinterpret_cast<const float4*>(&th[pos][q4*4]);
            y += Wr[q4*4]*tv.x + Wr[q4*4+1]*tv.y + Wr[q4*4+2]*tv.z + Wr[q4*4+3]*tv.w;
        }
        float y2 = 2.f*y;
        float m = fmaxf(y2, -y2);
        #pragma unroll
        for (int off = 16; off >= 1; off >>= 1) m = fmaxf(m, __shfl_xor(m, off));
        float elo = __expf(y2 - m), ehi = __expf(-y2 - m);
        float s = elo + ehi;
        #pragma unroll
        for (int off = 16; off >= 1; off >>= 1) s += __shfl_xor(s, off);
        float rs = 1.f / s;
        float qlo = elo*rs, qhi = ehi*rs;
        float zd = qlo*km_lo + qhi*km_hi;
        #pragma unroll
        for (int off = 16; off >= 1; off >>= 1) zd += __shfl_xor(zd, off);
        float z = 1.f / (zd + 1e-6f);
        size_t fbase = ((size_t)h*NN + n0 + pos)*16 + e;
        float fsv = (e < 16) ? fs[fbase] : 1.0f;
        float fcv = (e < 16) ? fc[fbase] : 1.0f;
        qfs[pos][e]      = z*(qlo*fcv + qhi*fsv);
        qfs[pos][32 + e] = z*(qhi*fcv - qlo*fsv);
    }
    __syncthreads();
    // phase 2: xs[row][e] = sum_e1 qfs[row][e1]*kvs[e1][e], rows g*16..g*16+15
    float acc[16] = {};
    #pragma unroll
    for (int c = 0; c < 4; ++c) {
        float kreg[16];
        #pragma unroll
        for (int j = 0; j < 16; ++j) kreg[j] = kvs[c*16 + j][e];
        #pragma unroll
        for (int r = 0; r < 16; ++r) {
            int row = g*16 + r;
            float4 qa = *reinterpret_cast<const float4*>(&qfs[row][c*16]);
            float4 qb = *reinterpret_cast<const float4*>(&qfs[row][c*16+4]);
            float4 qc2 = *reinterpret_cast<const float4*>(&qfs[row][c*16+8]);
            float4 qd = *reinterpret_cast<const float4*>(&qfs[row][c*16+12]);
            acc[r] += qa.x*kreg[0] + qa.y*kreg[1] + qa.z*kreg[2] + qa.w*kreg[3]
                    + qb.x*kreg[4] + qb.y*kreg[5] + qb.z*kreg[6] + qb.w*kreg[7]
                    + qc2.x*kreg[8] + qc2.y*kreg[9] + qc2.z*kreg[10] + qc2.w*kreg[11]
                    + qd.x*kreg[12] + qd.y*kreg[13] + qd.z*kreg[14] + qd.w*kreg[15];
        }
    }
    #pragma unroll
    for (int r = 0; r < 16; ++r) {
        size_t off = ((size_t)(b*NN + n0 + g*16 + r))*128 + h*32 + e;
        xsp[off] += acc[r];
    }
}

// ---------------------------------------------------------------- channel norms (sum of squares over n)
__global__ __launch_bounds__(256) void k_norms(const float* __restrict__ q, const float* __restrict__ k,
                                               float* __restrict__ qn2, float* __restrict__ kn2)
{
    __shared__ float sq[256], sk[256];
    int b = blockIdx.y, chunk = blockIdx.x;
    int t = threadIdx.x, c = t & 127, half = t >> 7;
    float qa = 0.f, ka = 0.f;
    size_t base = ((size_t)b*NN + chunk*256 + half)*128 + c;
    for (int r = 0; r < 128; ++r) {
        float xq = q[base], xk = k[base];
        qa += xq*xq; ka += xk*xk;
        base += 256;
    }
    sq[t] = qa; sk[t] = ka;
    __syncthreads();
    if (t < 128) {
        atomicAdd(&qn2[b*128 + c], sq[t] + sq[t+128]);
        atomicAdd(&kn2[b*128 + c], sk[t] + sk[t+128]);
    }
}

// ---------------------------------------------------------------- gram G[b,c,d] = sum_l q[b,l,c] k[b,l,d]
__global__ __launch_bounds__(256) void k_gram(const float* __restrict__ q, const float* __restrict__ k,
                                              float* __restrict__ G)
{
    __shared__ float qt[64][36], kt[64][36];
    int ls = blockIdx.x;
    int ct = blockIdx.y >> 2, dt = blockIdx.y & 3;
    int b = blockIdx.z;
    int c0 = ct*32, d0 = dt*32;
    int t = threadIdx.x;
    int di = t & 31, cb = (t >> 5)*4;
    float acc[4] = {};
    for (int sub = 0; sub < 32; ++sub) {
        int l0 = ls*2048 + sub*64;
        #pragma unroll
        for (int i = 0; i < 8; ++i) {
            int lin = t + i*256;
            int r = lin >> 5, col = lin & 31;
            size_t rowb = ((size_t)b*NN + l0 + r)*128;
            qt[r][col] = q[rowb + c0 + col];
            kt[r][col] = k[rowb + d0 + col];
        }
        __syncthreads();
        #pragma unroll 8
        for (int l = 0; l < 64; ++l) {
            float kvl = kt[l][di];
            float4 qv = *reinterpret_cast<const float4*>(&qt[l][cb]);
            acc[0] += qv.x*kvl; acc[1] += qv.y*kvl; acc[2] += qv.z*kvl; acc[3] += qv.w*kvl;
        }
        __syncthreads();
    }
    #pragma unroll
    for (int j = 0; j < 4; ++j)
        atomicAdd(&G[((size_t)b*128 + c0 + cb + j)*128 + d0 + di], acc[j]);
}

// ---------------------------------------------------------------- channel attention softmax
__global__ __launch_bounds__(128) void k_attnsm(const float* __restrict__ G, const float* __restrict__ qn2,
    const float* __restrict__ kn2, const float* __restrict__ temp, float* __restrict__ attn)
{
    __shared__ float red[128];
    int row = blockIdx.x;            // b*128 + c
    int b = row >> 7, c = row & 127;
    int t = threadIdx.x;             // d
    float qn = fmaxf(sqrtf(qn2[b*128 + c]), 1e-12f);
    float kn = fmaxf(sqrtf(kn2[b*128 + t]), 1e-12f);
    float val = G[(size_t)row*128 + t] / (qn*kn) * temp[c];
    red[t] = val; __syncthreads();
    for (int s = 64; s > 0; s >>= 1) { if (t < s) red[t] = fmaxf(red[t], red[t+s]); __syncthreads(); }
    float mm = red[0]; __syncthreads();
    float ev = expf(val - mm);
    red[t] = ev; __syncthreads();
    for (int s = 64; s > 0; s >>= 1) { if (t < s) red[t] += red[t+s]; __syncthreads(); }
    attn[(size_t)row*128 + t] = ev / red[0];
}

// ---------------------------------------------------------------- build per-batch B matrix: [Wp_left^T ; M2]
__global__ __launch_bounds__(256) void k_bmat(const float* __restrict__ attn, const float* __restrict__ Wp,
                                              float* __restrict__ Bmat)
{
    int b = blockIdx.y, kk = blockIdx.x, o = threadIdx.x;
    if (kk < 128) {
        Bmat[((size_t)b*256 + kk)*256 + o] = Wp[(size_t)o*256 + kk];
    } else {
        int d = kk - 128;
        __shared__ float a[128];
        if (o < 128) a[o] = attn[((size_t)b*128 + o)*128 + d];
        __syncthreads();
        float acc = 0.f;
        for (int c = 0; c < 128; ++c) acc += a[c] * Wp[(size_t)o*256 + 128 + c];
        Bmat[((size_t)b*256 + kk)*256 + o] = acc;
    }
}

// ---------------------------------------------------------------- final GEMM: out = [xsp | v] @ Bmat_b + bp
__global__ __launch_bounds__(256) void k_out(const float* __restrict__ xsp, const float* __restrict__ v,
    const float* __restrict__ Bmat, const float* __restrict__ bp, float* __restrict__ out)
{
    __shared__ float As[32][68];
    __shared__ float Bs[32][68];
    int b = blockIdx.z;
    int m0 = blockIdx.x*64, col0 = blockIdx.y*64;
    int t = threadIdx.x, tx = t & 15, ty = t >> 4;
    const float* Bb = Bmat + (size_t)b*65536;
    float acc[4][4] = {};
    for (int k0 = 0; k0 < 256; k0 += 32) {
        const float* Asrc = (k0 < 128) ? xsp : v;
        int kk0 = k0 & 127;
        #pragma unroll
        for (int i = 0; i < 8; ++i) {
            int lin = t + i*256;
            int r = lin >> 5, c = lin & 31;
            As[c][r] = Asrc[((size_t)b*NN + m0 + r)*128 + kk0 + c];
        }
        #pragma unroll
        for (int i = 0; i < 8; ++i) {
            int lin = t + i*256;
            int r = lin >> 6, col = lin & 63;
            Bs[r][col] = Bb[(size_t)(k0 + r)*256 + col0 + col];
        }
        __syncthreads();
        #pragma unroll
        for (int kk = 0; kk < 32; ++kk) {
            float4 av = *reinterpret_cast<const float4*>(&As[kk][ty*4]);
            float4 bv4 = *reinterpret_cast<const float4*>(&Bs[kk][tx*4]);
            float a[4] = {av.x, av.y, av.z, av.w};
            float bb[4] = {bv4.x, bv4.y, bv4.z, bv4.w};
            #pragma unroll
            for (int i = 0; i < 4; ++i)
                #pragma unroll
                for (int j = 0; j < 4; ++j) acc[i][j] += a[i]*bb[j];
        }
        __syncthreads();
    }
    #pragma unroll
    for (int i = 0; i < 4; ++i) {
        size_t m = (size_t)b*NN + m0 + ty*4 + i;
        #pragma unroll
        for (int j = 0; j < 4; ++j) {
            int g = col0 + tx*4 + j;
            out[m*256 + g] = acc[i][j] + bp[g];
        }
    }
}

extern "C" void kernel_launch(void* const* d_in, const int* in_sizes, int n_in,
                              void* d_out, int out_size, void* d_ws, size_t ws_size,
                              hipStream_t stream)
{
    (void)in_sizes; (void)n_in; (void)out_size; (void)ws_size;
    const float* x    = (const float*)d_in[0];
    const float* Wq   = (const float*)d_in[1];
    const float* bq   = (const float*)d_in[2];
    const float* Wk   = (const float*)d_in[3];
    const float* bk   = (const float*)d_in[4];
    const float* Wv   = (const float*)d_in[5];
    const float* bv   = (const float*)d_in[6];
    const float* Whq  = (const float*)d_in[7];
    const float* bhq  = (const float*)d_in[8];
    const float* Whk  = (const float*)d_in[9];
    const float* bhk  = (const float*)d_in[10];
    const float* sinc = (const float*)d_in[11];
    const float* cosc = (const float*)d_in[12];
    const float* lw   = (const float*)d_in[13];
    const float* lb   = (const float*)d_in[14];
    const float* temp = (const float*)d_in[15];
    const float* Wp   = (const float*)d_in[16];
    const float* bp   = (const float*)d_in[17];

    float* out = (float*)d_out;
    float* q   = out + 33554432;   // (8,16384,128)
    float* k   = out + 50331648;   // (8,16384,128)
    float* ws  = (float*)d_ws;

    float* v      = ws + WS_V;
    float* xsp    = ws + WS_XSP;
    float* fs     = ws + WS_FS;
    float* fc     = ws + WS_FC;
    float* inv    = ws + WS_INV;
    float* cs     = ws + WS_CS;
    float* cc     = ws + WS_CC;
    float* kvpart = ws + WS_KVPART;
    float* kmpart = ws + WS_KMPART;
    float* kv     = ws + WS_KV;
    float* kmean  = ws + WS_KMEAN;
    float* qn2    = ws + WS_QN2;
    float* kn2    = ws + WS_KN2;
    float* G      = ws + WS_G;
    float* attn   = ws + WS_ATTN;
    float* Bmat   = ws + WS_BMAT;

    // zero atomic targets (qn2 and kn2 are contiguous)
    hipMemsetAsync(qn2, 0, 2048*sizeof(float), stream);
    hipMemsetAsync(G, 0, 131072*sizeof(float), stream);

    k_setup<<<1, 64, 0, stream>>>(sinc, cosc, inv, cs, cc);
    k_tables<<<16384, 64, 0, stream>>>(inv, cs, cc, fs, fc);
    k_qkv<<<dim3(2048, 6), 256, 0, stream>>>(x, Wq, Wk, Wv, bq, bk, bv, q, k, v);
    k_conv<<<dim3(64, 128, 8), 256, 0, stream>>>(v, lw, lb, xsp);
    k_featkv<<<dim3(32, 32), 256, 0, stream>>>(k, v, Whk, bhk, fs, fc, kvpart, kmpart);
    k_kvred2<<<256, 256, 0, stream>>>(kvpart, kv);
    k_kmred<<<32, 64, 0, stream>>>(kmpart, kmean);
    k_featxs<<<dim3(128, 32), 256, 0, stream>>>(q, Whq, bhq, fs, fc, kv, kmean, xsp);
    k_norms<<<dim3(64, 8), 256, 0, stream>>>(q, k, qn2, kn2);
    k_gram<<<dim3(8, 16, 8), 256, 0, stream>>>(q, k, G);
    k_attnsm<<<1024, 128, 0, stream>>>(G, qn2, kn2, temp, attn);
    k_bmat<<<dim3(256, 8), 256, 0, stream>>>(attn, Wp, Bmat);
    k_out<<<dim3(256, 4, 8), 256, 0, stream>>>(xsp, v, Bmat, bp, out);
}

// Round 3
// 932.505 us; speedup vs baseline: 2.5109x; 1.4879x over previous
//
#include <hip/hip_runtime.h>
#include <cmath>

#define NB 8
#define NN 16384
#define NDIM 256
#define NHEAD 4
#define HDH 32
#define NCH 128
#define DIN 23
#define DOUT 16

typedef short bf16x8 __attribute__((ext_vector_type(8)));
typedef float f32x4 __attribute__((ext_vector_type(4)));

__device__ __forceinline__ unsigned short f2bf(float f) {
    unsigned int u = __float_as_uint(f);
    u += 0x7FFFu + ((u >> 16) & 1u);
    return (unsigned short)(u >> 16);
}
__device__ __forceinline__ float bf2f(unsigned short s) {
    return __uint_as_float(((unsigned int)s) << 16);
}

// workspace offsets in floats (total ~38.5M floats = 154 MB)
#define WS_XSP    ((size_t)0)          // 16,777,216 f32 (conv out, xs base)
#define WS_VB     ((size_t)16777216)   // 8,388,608 f32-slots = 16,777,216 bf16 (v)
#define WS_XSB    ((size_t)25165824)   // 8,388,608 f32-slots (xs final, bf16)
#define WS_FS     ((size_t)33554432)   // 1,048,576
#define WS_FC     ((size_t)34603008)   // 1,048,576
#define WS_INV    ((size_t)35651584)   // 64
#define WS_CS     ((size_t)35651648)   // 1536
#define WS_CC     ((size_t)35653184)   // 1536
#define WS_WCAT   ((size_t)35654720)   // 49,152 f32-slots = 98,304 bf16 (W qkv)
#define WS_BCAT   ((size_t)35703872)   // 384
#define WS_KVPART ((size_t)35704256)   // 2,097,152
#define WS_KMPART ((size_t)37801408)   // 65,536
#define WS_KV     ((size_t)37866944)   // 65,536
#define WS_KMEAN  ((size_t)37932480)   // 2,048
#define WS_QN2    ((size_t)37934528)   // 1,024
#define WS_KN2    ((size_t)37935552)   // 1,024
#define WS_G      ((size_t)37936576)   // 131,072
#define WS_ATTN   ((size_t)38067648)   // 131,072
#define WS_BMATT  ((size_t)38198720)   // 262,144 f32-slots = 524,288 bf16

// ---------------------------------------------------------------- setup
__global__ void k_setup(const float* __restrict__ sc, const float* __restrict__ ccin,
                        float* __restrict__ inv, float* __restrict__ cs, float* __restrict__ cc)
{
    int t = threadIdx.x; // 64 threads
    if (t < DIN) inv[t] = (float)pow(10000.0, -((double)(2 * t)) / 64.0);
    int h = t >> 4, d = t & 15;
    float ss = 0.f, s2 = 0.f;
    for (int D = 0; D < DIN; ++D) { ss += sc[(h*DIN + D)*DOUT + d]; s2 += ccin[(h*DIN + D)*DOUT + d]; }
    float rs = 1.f / ss, r2 = 1.f / s2;
    for (int D = 0; D < DIN; ++D) {
        cs[(h*DIN + D)*DOUT + d] = sc[(h*DIN + D)*DOUT + d] * rs;
        cc[(h*DIN + D)*DOUT + d] = ccin[(h*DIN + D)*DOUT + d] * r2;
    }
}

// ---------------------------------------------------------------- FoPE tables fs/fc: [h][t][16]
__global__ __launch_bounds__(64) void k_tables(const float* __restrict__ inv, const float* __restrict__ cs,
                                               const float* __restrict__ cc,
                                               float* __restrict__ fs, float* __restrict__ fc)
{
    int tpos = blockIdx.x;
    int t = threadIdx.x;
    __shared__ float ssin[DIN], scos[DIN];
    if (t < DIN) { float fr = (float)tpos * inv[t]; ssin[t] = sinf(fr); scos[t] = cosf(fr); }
    __syncthreads();
    int h = t >> 4, d = t & 15;
    float as = 0.f, ac = 0.f;
    for (int D = 0; D < DIN; ++D) { as += ssin[D]*cs[(h*DIN + D)*DOUT + d]; ac += scos[D]*cc[(h*DIN + D)*DOUT + d]; }
    size_t base = ((size_t)h*NN + tpos)*16;
    fs[base + d] = as;      fc[base + d] = ac;
}

// ---------------------------------------------------------------- weights -> bf16 concat [384][256] + bias concat
__global__ __launch_bounds__(256) void k_wprep(
    const float* __restrict__ Wq, const float* __restrict__ Wk, const float* __restrict__ Wv,
    const float* __restrict__ bq, const float* __restrict__ bk, const float* __restrict__ bv,
    unsigned short* __restrict__ Wc, float* __restrict__ bcat)
{
    int row = blockIdx.x, t = threadIdx.x;
    const float* W = (row < 128) ? Wq : (row < 256) ? Wk : Wv;
    const float* bb = (row < 128) ? bq : (row < 256) ? bk : bv;
    int r = row & 127;
    Wc[(size_t)row*256 + t] = f2bf(W[(size_t)r*256 + t]);
    if (t == 0) bcat[row] = bb[r];
}

// ---------------------------------------------------------------- QKV MFMA GEMM: [q|k|v] = x @ Wc^T + b
// BM=128, BN=128, BK=64; 4 waves (2x2); grid (3 ntiles, 1024 mtiles) remapped.
__global__ __launch_bounds__(256) void k_qkv_mfma(const float* __restrict__ x,
    const unsigned short* __restrict__ Wc, const float* __restrict__ bcat,
    float* __restrict__ q, float* __restrict__ k, unsigned short* __restrict__ vb)
{
    __shared__ unsigned short Asm[128*64];
    __shared__ unsigned short Bsm[128*64];
    int t = threadIdx.x;
    int lin = blockIdx.y*3 + blockIdx.x;
    int logical = (lin & 7)*384 + (lin >> 3);       // XCD-contiguous remap (3072 % 8 == 0)
    int ntile = logical % 3;
    int mtile = logical / 3;
    int m0 = mtile * 128;
    int n0 = ntile * 128;
    int wave = t >> 6, lane = t & 63;
    int wm = wave >> 1, wn = wave & 1;
    int lrow = lane & 15, lk = lane >> 4;
    f32x4 acc[4][4];
    #pragma unroll
    for (int i = 0; i < 4; ++i)
        #pragma unroll
        for (int j = 0; j < 4; ++j) acc[i][j] = (f32x4){0.f,0.f,0.f,0.f};

    for (int kt = 0; kt < 4; ++kt) {
        int k0 = kt * 64;
        if (kt) __syncthreads();
        // stage A (f32 -> bf16, swizzled)
        {
            int m = t >> 4, k4 = t & 15;
            #pragma unroll
            for (int p = 0; p < 8; ++p, m += 16) {
                float4 v4 = *reinterpret_cast<const float4*>(&x[(size_t)(m0 + m)*256 + k0 + k4*4]);
                ushort4 b4;
                b4.x = f2bf(v4.x); b4.y = f2bf(v4.y); b4.z = f2bf(v4.z); b4.w = f2bf(v4.w);
                int byte = m*128 + ((k4*8) ^ ((m & 7) << 4));
                *reinterpret_cast<ushort4*>(reinterpret_cast<char*>(Asm) + byte) = b4;
            }
        }
        // stage B (bf16, swizzled)
        {
            int n = t >> 3, k8 = t & 7;
            #pragma unroll
            for (int p = 0; p < 4; ++p, n += 32) {
                uint4 u4 = *reinterpret_cast<const uint4*>(&Wc[(size_t)(n0 + n)*256 + k0 + k8*8]);
                int byte = n*128 + ((k8 ^ (n & 7)) << 4);
                *reinterpret_cast<uint4*>(reinterpret_cast<char*>(Bsm) + byte) = u4;
            }
        }
        __syncthreads();
        #pragma unroll
        for (int ks = 0; ks < 2; ++ks) {
            bf16x8 af[4], bfv[4];
            #pragma unroll
            for (int mi = 0; mi < 4; ++mi) {
                int m = wm*64 + mi*16 + lrow;
                int u = (ks*4 + lk) ^ (m & 7);
                af[mi] = *reinterpret_cast<const bf16x8*>(reinterpret_cast<const char*>(Asm) + m*128 + u*16);
            }
            #pragma unroll
            for (int ni = 0; ni < 4; ++ni) {
                int n = wn*64 + ni*16 + lrow;
                int u = (ks*4 + lk) ^ (n & 7);
                bfv[ni] = *reinterpret_cast<const bf16x8*>(reinterpret_cast<const char*>(Bsm) + n*128 + u*16);
            }
            #pragma unroll
            for (int mi = 0; mi < 4; ++mi)
                #pragma unroll
                for (int ni = 0; ni < 4; ++ni)
                    acc[mi][ni] = __builtin_amdgcn_mfma_f32_16x16x32_bf16(af[mi], bfv[ni], acc[mi][ni], 0, 0, 0);
        }
    }
    // epilogue: ntile decides destination tensor (wave-uniform)
    #pragma unroll
    for (int mi = 0; mi < 4; ++mi) {
        #pragma unroll
        for (int ni = 0; ni < 4; ++ni) {
            int gcol = n0 + wn*64 + ni*16 + lrow;
            int c = gcol & 127;
            float bias = bcat[gcol];
            #pragma unroll
            for (int r = 0; r < 4; ++r) {
                size_t grow = (size_t)m0 + wm*64 + mi*16 + lk*4 + r;
                float val = acc[mi][ni][r] + bias;
                if (ntile == 0)      q[grow*128 + c] = val;
                else if (ntile == 1) k[grow*128 + c] = val;
                else                 vb[grow*128 + c] = f2bf(val);
            }
        }
    }
}

// ---------------------------------------------------------------- depthwise 3x3 LEPE conv (bf16 v) -> xsp f32
__global__ __launch_bounds__(256) void k_conv(const unsigned short* __restrict__ vb, const float* __restrict__ w,
                                              const float* __restrict__ bias, float* __restrict__ xsp)
{
    __shared__ float wsm[NCH*9];
    __shared__ float bsm[NCH];
    int t = threadIdx.x;
    for (int i = t; i < NCH*9; i += 256) wsm[i] = w[i];
    if (t < NCH) bsm[t] = bias[t];
    __syncthreads();
    int c = t & 127, jj = t >> 7;
    int j = blockIdx.x*2 + jj;
    int i = blockIdx.y;
    int b = blockIdx.z;
    float acc = bsm[c];
    #pragma unroll
    for (int ki = 0; ki < 3; ++ki) {
        int ii = i + ki - 1;
        if (ii < 0 || ii >= 128) continue;
        #pragma unroll
        for (int kj = 0; kj < 3; ++kj) {
            int jx = j + kj - 1;
            if (jx < 0 || jx >= 128) continue;
            acc += wsm[c*9 + ki*3 + kj] * bf2f(vb[((size_t)b*NN + ii*128 + jx)*128 + c]);
        }
    }
    xsp[((size_t)b*NN + i*128 + j)*128 + c] = acc;
}

// ---------------------------------------------------------------- fused k-features + kv partial accumulation
__global__ __launch_bounds__(256) void k_featkv(
    const float* __restrict__ kin, const unsigned short* __restrict__ vb,
    const float* __restrict__ W, const float* __restrict__ bvec,
    const float* __restrict__ fs, const float* __restrict__ fc,
    float* __restrict__ kvpart, float* __restrict__ kmpart)
{
    __shared__ float th[128][32];    // k tile, then v tile
    __shared__ float kfs[128][68];   // k_fope features [pos][64]
    __shared__ float kms[8][64];
    int bh = blockIdx.y, b = bh >> 2, h = bh & 3;
    int chunk = blockIdx.x;
    int t = threadIdx.x;
    int e = t & 31, g = t >> 5;
    float Wr[32];
    #pragma unroll
    for (int dd = 0; dd < 32; ++dd) Wr[dd] = W[e*32 + dd];
    float bias = bvec[e];
    float km_lo = 0.f, km_hi = 0.f;
    float acc[8] = {};
    for (int sub = 0; sub < 4; ++sub) {
        int n0 = chunk*512 + sub*128;
        __syncthreads();
        for (int i = t; i < 4096; i += 256) {
            int pos = i >> 5, dd = i & 31;
            th[pos][dd] = kin[((size_t)(b*NN + n0 + pos))*128 + h*32 + dd];
        }
        __syncthreads();
        for (int p = 0; p < 16; ++p) {
            int pos = g*16 + p;
            float y = bias;
            #pragma unroll
            for (int q4 = 0; q4 < 8; ++q4) {
                float4 tv = *reinterpret_cast<const float4*>(&th[pos][q4*4]);
                y += Wr[q4*4]*tv.x + Wr[q4*4+1]*tv.y + Wr[q4*4+2]*tv.z + Wr[q4*4+3]*tv.w;
            }
            float y2 = 2.f*y;
            float m = fmaxf(y2, -y2);
            #pragma unroll
            for (int off = 16; off >= 1; off >>= 1) m = fmaxf(m, __shfl_xor(m, off));
            float elo = __expf(y2 - m), ehi = __expf(-y2 - m);
            float s = elo + ehi;
            #pragma unroll
            for (int off = 16; off >= 1; off >>= 1) s += __shfl_xor(s, off);
            float rs = 1.f / s;
            float klo = elo*rs, khi = ehi*rs;
            km_lo += klo; km_hi += khi;
            size_t fbase = ((size_t)h*NN + n0 + pos)*16 + e;
            float fsv = (e < 16) ? fs[fbase] : 1.0f;
            float fcv = (e < 16) ? fc[fbase] : 1.0f;
            kfs[pos][e]      = klo*fcv + khi*fsv;
            kfs[pos][32 + e] = khi*fcv - klo*fsv;
        }
        __syncthreads();
        for (int i = t; i < 4096; i += 256) {
            int pos = i >> 5, dd = i & 31;
            th[pos][dd] = bf2f(vb[((size_t)(b*NN + n0 + pos))*128 + h*32 + dd]);
        }
        __syncthreads();
        for (int n = 0; n < 128; ++n) {
            float vv = th[n][e];
            float4 ka = *reinterpret_cast<const float4*>(&kfs[n][g*8]);
            float4 kb = *reinterpret_cast<const float4*>(&kfs[n][g*8+4]);
            acc[0] += ka.x*vv; acc[1] += ka.y*vv; acc[2] += ka.z*vv; acc[3] += ka.w*vv;
            acc[4] += kb.x*vv; acc[5] += kb.y*vv; acc[6] += kb.z*vv; acc[7] += kb.w*vv;
        }
    }
    size_t pb = ((size_t)(bh*32 + chunk))*2048 + (size_t)(g*8)*32 + e;
    #pragma unroll
    for (int j = 0; j < 8; ++j) kvpart[pb + (size_t)j*32] = acc[j];
    kms[g][e] = km_lo; kms[g][32 + e] = km_hi;
    __syncthreads();
    if (t < 64) {
        float s = 0.f;
        #pragma unroll
        for (int gg = 0; gg < 8; ++gg) s += kms[gg][t];
        kmpart[(size_t)(bh*32 + chunk)*64 + t] = s;
    }
}

// ---------------------------------------------------------------- reduce kv partials (x 1/N)
__global__ __launch_bounds__(256) void k_kvred2(const float* __restrict__ kvpart, float* __restrict__ kv)
{
    int bh = blockIdx.x >> 3, part = blockIdx.x & 7;
    int idx = part*256 + threadIdx.x;
    float s = 0.f;
    for (int c = 0; c < 32; ++c) s += kvpart[((size_t)(bh*32 + c))*2048 + idx];
    kv[(size_t)bh*2048 + idx] = s * (1.f/16384.f);
}

__global__ __launch_bounds__(64) void k_kmred(const float* __restrict__ kmpart, float* __restrict__ kmean)
{
    int bh = blockIdx.x, t = threadIdx.x;
    float s = 0.f;
    for (int c = 0; c < 32; ++c) s += kmpart[(size_t)(bh*32 + c)*64 + t];
    kmean[bh*64 + t] = s * (1.f/16384.f);
}

// ---------------------------------------------------------------- fused q-features + xs GEMM -> xsb (bf16)
__global__ __launch_bounds__(256) void k_featxs(
    const float* __restrict__ qin, const float* __restrict__ W, const float* __restrict__ bvec,
    const float* __restrict__ fs, const float* __restrict__ fc,
    const float* __restrict__ kv, const float* __restrict__ kmean,
    const float* __restrict__ xsp, unsigned short* __restrict__ xsb)
{
    __shared__ float th[128][32];
    __shared__ float qfs[128][68];
    __shared__ float kvs[64][32];
    int bh = blockIdx.y, b = bh >> 2, h = bh & 3;
    int n0 = blockIdx.x * 128;
    int t = threadIdx.x;
    int e = t & 31, g = t >> 5;
    float Wr[32];
    #pragma unroll
    for (int dd = 0; dd < 32; ++dd) Wr[dd] = W[e*32 + dd];
    float bias = bvec[e];
    float km_lo = kmean[bh*64 + e], km_hi = kmean[bh*64 + 32 + e];
    for (int i = t; i < 2048; i += 256) kvs[i>>5][i&31] = kv[(size_t)bh*2048 + i];
    for (int i = t; i < 4096; i += 256) {
        int pos = i >> 5, dd = i & 31;
        th[pos][dd] = qin[((size_t)(b*NN + n0 + pos))*128 + h*32 + dd];
    }
    __syncthreads();
    for (int p = 0; p < 16; ++p) {
        int pos = g*16 + p;
        float y = bias;
        #pragma unroll
        for (int q4 = 0; q4 < 8; ++q4) {
            float4 tv = *reinterpret_cast<const float4*>(&th[pos][q4*4]);
            y += Wr[q4*4]*tv.x + Wr[q4*4+1]*tv.y + Wr[q4*4+2]*tv.z + Wr[q4*4+3]*tv.w;
        }
        float y2 = 2.f*y;
        float m = fmaxf(y2, -y2);
        #pragma unroll
        for (int off = 16; off >= 1; off >>= 1) m = fmaxf(m, __shfl_xor(m, off));
        float elo = __expf(y2 - m), ehi = __expf(-y2 - m);
        float s = elo + ehi;
        #pragma unroll
        for (int off = 16; off >= 1; off >>= 1) s += __shfl_xor(s, off);
        float rs = 1.f / s;
        float qlo = elo*rs, qhi = ehi*rs;
        float zd = qlo*km_lo + qhi*km_hi;
        #pragma unroll
        for (int off = 16; off >= 1; off >>= 1) zd += __shfl_xor(zd, off);
        float z = 1.f / (zd + 1e-6f);
        size_t fbase = ((size_t)h*NN + n0 + pos)*16 + e;
        float fsv = (e < 16) ? fs[fbase] : 1.0f;
        float fcv = (e < 16) ? fc[fbase] : 1.0f;
        qfs[pos][e]      = z*(qlo*fcv + qhi*fsv);
        qfs[pos][32 + e] = z*(qhi*fcv - qlo*fsv);
    }
    __syncthreads();
    float acc[16] = {};
    #pragma unroll
    for (int c = 0; c < 4; ++c) {
        float kreg[16];
        #pragma unroll
        for (int j = 0; j < 16; ++j) kreg[j] = kvs[c*16 + j][e];
        #pragma unroll
        for (int r = 0; r < 16; ++r) {
            int row = g*16 + r;
            float4 qa = *reinterpret_cast<const float4*>(&qfs[row][c*16]);
            float4 qb = *reinterpret_cast<const float4*>(&qfs[row][c*16+4]);
            float4 qc2 = *reinterpret_cast<const float4*>(&qfs[row][c*16+8]);
            float4 qd = *reinterpret_cast<const float4*>(&qfs[row][c*16+12]);
            acc[r] += qa.x*kreg[0] + qa.y*kreg[1] + qa.z*kreg[2] + qa.w*kreg[3]
                    + qb.x*kreg[4] + qb.y*kreg[5] + qb.z*kreg[6] + qb.w*kreg[7]
                    + qc2.x*kreg[8] + qc2.y*kreg[9] + qc2.z*kreg[10] + qc2.w*kreg[11]
                    + qd.x*kreg[12] + qd.y*kreg[13] + qd.z*kreg[14] + qd.w*kreg[15];
        }
    }
    #pragma unroll
    for (int r = 0; r < 16; ++r) {
        size_t off = ((size_t)(b*NN + n0 + g*16 + r))*128 + h*32 + e;
        xsb[off] = f2bf(xsp[off] + acc[r]);
    }
}

// ---------------------------------------------------------------- channel norms
__global__ __launch_bounds__(256) void k_norms(const float* __restrict__ q, const float* __restrict__ k,
                                               float* __restrict__ qn2, float* __restrict__ kn2)
{
    __shared__ float sq[256], sk[256];
    int b = blockIdx.y, chunk = blockIdx.x;
    int t = threadIdx.x, c = t & 127, half = t >> 7;
    float qa = 0.f, ka = 0.f;
    size_t base = ((size_t)b*NN + chunk*256 + half)*128 + c;
    for (int r = 0; r < 128; ++r) {
        float xq = q[base], xk = k[base];
        qa += xq*xq; ka += xk*xk;
        base += 256;
    }
    sq[t] = qa; sk[t] = ka;
    __syncthreads();
    if (t < 128) {
        atomicAdd(&qn2[b*128 + c], sq[t] + sq[t+128]);
        atomicAdd(&kn2[b*128 + c], sk[t] + sk[t+128]);
    }
}

// ---------------------------------------------------------------- gram G[b,c,d] = sum_l q[b,l,c] k[b,l,d]
__global__ __launch_bounds__(256) void k_gram(const float* __restrict__ q, const float* __restrict__ k,
                                              float* __restrict__ G)
{
    __shared__ float qt[64][36], kt[64][36];
    int ls = blockIdx.x;
    int ct = blockIdx.y >> 2, dt = blockIdx.y & 3;
    int b = blockIdx.z;
    int c0 = ct*32, d0 = dt*32;
    int t = threadIdx.x;
    int di = t & 31, cb = (t >> 5)*4;
    float acc[4] = {};
    for (int sub = 0; sub < 32; ++sub) {
        int l0 = ls*2048 + sub*64;
        #pragma unroll
        for (int i = 0; i < 8; ++i) {
            int lin = t + i*256;
            int r = lin >> 5, col = lin & 31;
            size_t rowb = ((size_t)b*NN + l0 + r)*128;
            qt[r][col] = q[rowb + c0 + col];
            kt[r][col] = k[rowb + d0 + col];
        }
        __syncthreads();
        #pragma unroll 8
        for (int l = 0; l < 64; ++l) {
            float kvl = kt[l][di];
            float4 qv = *reinterpret_cast<const float4*>(&qt[l][cb]);
            acc[0] += qv.x*kvl; acc[1] += qv.y*kvl; acc[2] += qv.z*kvl; acc[3] += qv.w*kvl;
        }
        __syncthreads();
    }
    #pragma unroll
    for (int j = 0; j < 4; ++j)
        atomicAdd(&G[((size_t)b*128 + c0 + cb + j)*128 + d0 + di], acc[j]);
}

// ---------------------------------------------------------------- channel attention softmax
__global__ __launch_bounds__(128) void k_attnsm(const float* __restrict__ G, const float* __restrict__ qn2,
    const float* __restrict__ kn2, const float* __restrict__ temp, float* __restrict__ attn)
{
    __shared__ float red[128];
    int row = blockIdx.x;
    int b = row >> 7, c = row & 127;
    int t = threadIdx.x;
    float qn = fmaxf(sqrtf(qn2[b*128 + c]), 1e-12f);
    float kn = fmaxf(sqrtf(kn2[b*128 + t]), 1e-12f);
    float val = G[(size_t)row*128 + t] / (qn*kn) * temp[c];
    red[t] = val; __syncthreads();
    for (int s = 64; s > 0; s >>= 1) { if (t < s) red[t] = fmaxf(red[t], red[t+s]); __syncthreads(); }
    float mm = red[0]; __syncthreads();
    float ev = expf(val - mm);
    red[t] = ev; __syncthreads();
    for (int s = 64; s > 0; s >>= 1) { if (t < s) red[t] += red[t+s]; __syncthreads(); }
    attn[(size_t)row*128 + t] = ev / red[0];
}

// ---------------------------------------------------------------- per-batch B matrix, transposed bf16: BmatT[b][o][kk]
__global__ __launch_bounds__(256) void k_bmat(const float* __restrict__ attn, const float* __restrict__ Wp,
                                              unsigned short* __restrict__ BmatT)
{
    int b = blockIdx.y, kk = blockIdx.x, o = threadIdx.x;
    float val;
    if (kk < 128) {
        val = Wp[(size_t)o*256 + kk];
    } else {
        int d = kk - 128;
        __shared__ float a[128];
        if (o < 128) a[o] = attn[((size_t)b*128 + o)*128 + d];
        __syncthreads();
        float acc = 0.f;
        for (int c = 0; c < 128; ++c) acc += a[c] * Wp[(size_t)o*256 + 128 + c];
        val = acc;
    }
    BmatT[((size_t)b*256 + o)*256 + kk] = f2bf(val);
}

// ---------------------------------------------------------------- final MFMA GEMM: out = [xsb | vb] @ BmatT_b^T + bp
__global__ __launch_bounds__(256) void k_out_mfma(const unsigned short* __restrict__ xsb,
    const unsigned short* __restrict__ vb, const unsigned short* __restrict__ BmatT,
    const float* __restrict__ bp, float* __restrict__ out)
{
    __shared__ unsigned short Asm[128*64];
    __shared__ unsigned short Bsm[128*64];
    int t = threadIdx.x;
    int lin = blockIdx.y*2 + blockIdx.x;
    int logical = (lin & 7)*256 + (lin >> 3);       // 2048 % 8 == 0
    int ntile = logical & 1;
    int mtile = logical >> 1;
    int m0 = mtile * 128;
    int n0 = ntile * 128;
    int b = mtile >> 7;
    int wave = t >> 6, lane = t & 63;
    int wm = wave >> 1, wn = wave & 1;
    int lrow = lane & 15, lk = lane >> 4;
    f32x4 acc[4][4];
    #pragma unroll
    for (int i = 0; i < 4; ++i)
        #pragma unroll
        for (int j = 0; j < 4; ++j) acc[i][j] = (f32x4){0.f,0.f,0.f,0.f};

    for (int kt = 0; kt < 4; ++kt) {
        const unsigned short* Asrc = (kt < 2) ? xsb : vb;
        int ka0 = (kt & 1) * 64;
        if (kt) __syncthreads();
        // stage A (bf16, swizzled): rows 128 bf16 wide
        {
            int m = t >> 3, k8 = t & 7;
            #pragma unroll
            for (int p = 0; p < 4; ++p, m += 32) {
                uint4 u4 = *reinterpret_cast<const uint4*>(&Asrc[(size_t)(m0 + m)*128 + ka0 + k8*8]);
                int byte = m*128 + ((k8 ^ (m & 7)) << 4);
                *reinterpret_cast<uint4*>(reinterpret_cast<char*>(Asm) + byte) = u4;
            }
        }
        // stage B (bf16, swizzled): BmatT rows 256 bf16 wide
        {
            int n = t >> 3, k8 = t & 7;
            #pragma unroll
            for (int p = 0; p < 4; ++p, n += 32) {
                uint4 u4 = *reinterpret_cast<const uint4*>(&BmatT[((size_t)b*256 + n0 + n)*256 + kt*64 + k8*8]);
                int byte = n*128 + ((k8 ^ (n & 7)) << 4);
                *reinterpret_cast<uint4*>(reinterpret_cast<char*>(Bsm) + byte) = u4;
            }
        }
        __syncthreads();
        #pragma unroll
        for (int ks = 0; ks < 2; ++ks) {
            bf16x8 af[4], bfv[4];
            #pragma unroll
            for (int mi = 0; mi < 4; ++mi) {
                int m = wm*64 + mi*16 + lrow;
                int u = (ks*4 + lk) ^ (m & 7);
                af[mi] = *reinterpret_cast<const bf16x8*>(reinterpret_cast<const char*>(Asm) + m*128 + u*16);
            }
            #pragma unroll
            for (int ni = 0; ni < 4; ++ni) {
                int n = wn*64 + ni*16 + lrow;
                int u = (ks*4 + lk) ^ (n & 7);
                bfv[ni] = *reinterpret_cast<const bf16x8*>(reinterpret_cast<const char*>(Bsm) + n*128 + u*16);
            }
            #pragma unroll
            for (int mi = 0; mi < 4; ++mi)
                #pragma unroll
                for (int ni = 0; ni < 4; ++ni)
                    acc[mi][ni] = __builtin_amdgcn_mfma_f32_16x16x32_bf16(af[mi], bfv[ni], acc[mi][ni], 0, 0, 0);
        }
    }
    #pragma unroll
    for (int mi = 0; mi < 4; ++mi) {
        #pragma unroll
        for (int ni = 0; ni < 4; ++ni) {
            int gcol = n0 + wn*64 + ni*16 + lrow;
            float bias = bp[gcol];
            #pragma unroll
            for (int r = 0; r < 4; ++r) {
                size_t grow = (size_t)m0 + wm*64 + mi*16 + lk*4 + r;
                out[grow*256 + gcol] = acc[mi][ni][r] + bias;
            }
        }
    }
}

extern "C" void kernel_launch(void* const* d_in, const int* in_sizes, int n_in,
                              void* d_out, int out_size, void* d_ws, size_t ws_size,
                              hipStream_t stream)
{
    (void)in_sizes; (void)n_in; (void)out_size; (void)ws_size;
    const float* x    = (const float*)d_in[0];
    const float* Wq   = (const float*)d_in[1];
    const float* bq   = (const float*)d_in[2];
    const float* Wk   = (const float*)d_in[3];
    const float* bk   = (const float*)d_in[4];
    const float* Wv   = (const float*)d_in[5];
    const float* bv   = (const float*)d_in[6];
    const float* Whq  = (const float*)d_in[7];
    const float* bhq  = (const float*)d_in[8];
    const float* Whk  = (const float*)d_in[9];
    const float* bhk  = (const float*)d_in[10];
    const float* sinc = (const float*)d_in[11];
    const float* cosc = (const float*)d_in[12];
    const float* lw   = (const float*)d_in[13];
    const float* lb   = (const float*)d_in[14];
    const float* temp = (const float*)d_in[15];
    const float* Wp   = (const float*)d_in[16];
    const float* bp   = (const float*)d_in[17];

    float* out = (float*)d_out;
    float* q   = out + 33554432;   // (8,16384,128)
    float* k   = out + 50331648;   // (8,16384,128)
    float* ws  = (float*)d_ws;

    float* xsp    = ws + WS_XSP;
    unsigned short* vbuf = (unsigned short*)(ws + WS_VB);
    unsigned short* xsb  = (unsigned short*)(ws + WS_XSB);
    float* fs     = ws + WS_FS;
    float* fc     = ws + WS_FC;
    float* inv    = ws + WS_INV;
    float* cs     = ws + WS_CS;
    float* cc     = ws + WS_CC;
    unsigned short* Wc = (unsigned short*)(ws + WS_WCAT);
    float* bcat   = ws + WS_BCAT;
    float* kvpart = ws + WS_KVPART;
    float* kmpart = ws + WS_KMPART;
    float* kv     = ws + WS_KV;
    float* kmean  = ws + WS_KMEAN;
    float* qn2    = ws + WS_QN2;
    float* kn2    = ws + WS_KN2;
    float* G      = ws + WS_G;
    float* attn   = ws + WS_ATTN;
    unsigned short* BmatT = (unsigned short*)(ws + WS_BMATT);

    hipMemsetAsync(qn2, 0, 2048*sizeof(float), stream);
    hipMemsetAsync(G, 0, 131072*sizeof(float), stream);

    k_setup<<<1, 64, 0, stream>>>(sinc, cosc, inv, cs, cc);
    k_tables<<<16384, 64, 0, stream>>>(inv, cs, cc, fs, fc);
    k_wprep<<<384, 256, 0, stream>>>(Wq, Wk, Wv, bq, bk, bv, Wc, bcat);
    k_qkv_mfma<<<dim3(3, 1024), 256, 0, stream>>>(x, Wc, bcat, q, k, vbuf);
    k_conv<<<dim3(64, 128, 8), 256, 0, stream>>>(vbuf, lw, lb, xsp);
    k_featkv<<<dim3(32, 32), 256, 0, stream>>>(k, vbuf, Whk, bhk, fs, fc, kvpart, kmpart);
    k_kvred2<<<256, 256, 0, stream>>>(kvpart, kv);
    k_kmred<<<32, 64, 0, stream>>>(kmpart, kmean);
    k_featxs<<<dim3(128, 32), 256, 0, stream>>>(q, Whq, bhq, fs, fc, kv, kmean, xsp, xsb);
    k_norms<<<dim3(64, 8), 256, 0, stream>>>(q, k, qn2, kn2);
    k_gram<<<dim3(8, 16, 8), 256, 0, stream>>>(q, k, G);
    k_attnsm<<<1024, 128, 0, stream>>>(G, qn2, kn2, temp, attn);
    k_bmat<<<dim3(256, 8), 256, 0, stream>>>(attn, Wp, BmatT);
    k_out_mfma<<<dim3(2, 1024), 256, 0, stream>>>(xsb, vbuf, BmatT, bp, out);
}

// Round 4
// 671.325 us; speedup vs baseline: 3.4878x; 1.3891x over previous
//
#include <hip/hip_runtime.h>
#include <cmath>

#define NB 8
#define NN 16384
#define DIN 23
#define DOUT 16

typedef short bf16x8 __attribute__((ext_vector_type(8)));
typedef float f32x4 __attribute__((ext_vector_type(4)));

__device__ __forceinline__ unsigned short f2bf(float f) {
    unsigned int u = __float_as_uint(f);
    u += 0x7FFFu + ((u >> 16) & 1u);
    return (unsigned short)(u >> 16);
}
__device__ __forceinline__ float bf2f(unsigned short s) {
    return __uint_as_float(((unsigned int)s) << 16);
}

// workspace offsets in floats (identical budget to round 3: ~154 MB)
#define WS_XSP    ((size_t)0)          // 16,777,216 f32 (conv out; later reused as Gpart)
#define WS_VB     ((size_t)16777216)   // 8,388,608 slots = 16,777,216 bf16 (v)
#define WS_XSB    ((size_t)25165824)   // 8,388,608 slots (xs final, bf16)
#define WS_FS     ((size_t)33554432)   // 1,048,576
#define WS_FC     ((size_t)34603008)   // 1,048,576
#define WS_INV    ((size_t)35651584)   // 64
#define WS_CS     ((size_t)35651648)   // 1536
#define WS_CC     ((size_t)35653184)   // 1536
#define WS_WCAT   ((size_t)35654720)   // 49,152 slots = 98,304 bf16
#define WS_BCAT   ((size_t)35703872)   // 384
#define WS_KVPART ((size_t)35704256)   // 2,097,152 (32 bh x 32 chunks x 2048)
#define WS_KMPART ((size_t)37801408)   // 65,536
#define WS_KV     ((size_t)37866944)   // 65,536
#define WS_KMEAN  ((size_t)37932480)   // 2,048
#define WS_QN2    ((size_t)37934528)   // 1,024
#define WS_KN2    ((size_t)37935552)   // 1,024
#define WS_G      ((size_t)37936576)   // 131,072
#define WS_ATTN   ((size_t)38067648)   // 131,072
#define WS_BMATT  ((size_t)38198720)   // 262,144 slots = 524,288 bf16

// ---------------------------------------------------------------- setup
__global__ void k_setup(const float* __restrict__ sc, const float* __restrict__ ccin,
                        float* __restrict__ inv, float* __restrict__ cs, float* __restrict__ cc)
{
    int t = threadIdx.x; // 64 threads
    if (t < DIN) inv[t] = (float)pow(10000.0, -((double)(2 * t)) / 64.0);
    int h = t >> 4, d = t & 15;
    float ss = 0.f, s2 = 0.f;
    for (int D = 0; D < DIN; ++D) { ss += sc[(h*DIN + D)*DOUT + d]; s2 += ccin[(h*DIN + D)*DOUT + d]; }
    float rs = 1.f / ss, r2 = 1.f / s2;
    for (int D = 0; D < DIN; ++D) {
        cs[(h*DIN + D)*DOUT + d] = sc[(h*DIN + D)*DOUT + d] * rs;
        cc[(h*DIN + D)*DOUT + d] = ccin[(h*DIN + D)*DOUT + d] * r2;
    }
}

// ---------------------------------------------------------------- FoPE tables fs/fc: [h][t][16]
__global__ __launch_bounds__(256) void k_tables(const float* __restrict__ inv, const float* __restrict__ cs,
                                               const float* __restrict__ cc,
                                               float* __restrict__ fs, float* __restrict__ fc)
{
    int t = threadIdx.x;
    int sub = t >> 6, lane = t & 63;
    int tpos = blockIdx.x*4 + sub;
    __shared__ float ssin[4][DIN], scos[4][DIN];
    if (lane < DIN) { float fr = (float)tpos * inv[lane]; ssin[sub][lane] = sinf(fr); scos[sub][lane] = cosf(fr); }
    __syncthreads();
    int h = lane >> 4, d = lane & 15;
    float as = 0.f, ac = 0.f;
    for (int D = 0; D < DIN; ++D) { as += ssin[sub][D]*cs[(h*DIN + D)*DOUT + d]; ac += scos[sub][D]*cc[(h*DIN + D)*DOUT + d]; }
    size_t base = ((size_t)h*NN + tpos)*16;
    fs[base + d] = as;      fc[base + d] = ac;
}

// ---------------------------------------------------------------- weights -> bf16 concat [384][256] + bias concat
__global__ __launch_bounds__(256) void k_wprep(
    const float* __restrict__ Wq, const float* __restrict__ Wk, const float* __restrict__ Wv,
    const float* __restrict__ bq, const float* __restrict__ bk, const float* __restrict__ bv,
    unsigned short* __restrict__ Wc, float* __restrict__ bcat)
{
    int row = blockIdx.x, t = threadIdx.x;
    const float* W = (row < 128) ? Wq : (row < 256) ? Wk : Wv;
    const float* bb = (row < 128) ? bq : (row < 256) ? bk : bv;
    int r = row & 127;
    Wc[(size_t)row*256 + t] = f2bf(W[(size_t)r*256 + t]);
    if (t == 0) bcat[row] = bb[r];
}

// ---------------------------------------------------------------- QKV MFMA GEMM: [q|k|v] = x @ Wc^T + b
__global__ __launch_bounds__(256) void k_qkv_mfma(const float* __restrict__ x,
    const unsigned short* __restrict__ Wc, const float* __restrict__ bcat,
    float* __restrict__ q, float* __restrict__ k, unsigned short* __restrict__ vb)
{
    __shared__ unsigned short Asm[128*64];
    __shared__ unsigned short Bsm[128*64];
    int t = threadIdx.x;
    int lin = blockIdx.y*3 + blockIdx.x;
    int logical = (lin & 7)*384 + (lin >> 3);
    int ntile = logical % 3;
    int mtile = logical / 3;
    int m0 = mtile * 128;
    int n0 = ntile * 128;
    int wave = t >> 6, lane = t & 63;
    int wm = wave >> 1, wn = wave & 1;
    int lrow = lane & 15, lk = lane >> 4;
    f32x4 acc[4][4];
    #pragma unroll
    for (int i = 0; i < 4; ++i)
        #pragma unroll
        for (int j = 0; j < 4; ++j) acc[i][j] = (f32x4){0.f,0.f,0.f,0.f};

    for (int kt = 0; kt < 4; ++kt) {
        int k0 = kt * 64;
        if (kt) __syncthreads();
        {
            int m = t >> 4, k4 = t & 15;
            #pragma unroll
            for (int p = 0; p < 8; ++p, m += 16) {
                float4 v4 = *reinterpret_cast<const float4*>(&x[(size_t)(m0 + m)*256 + k0 + k4*4]);
                ushort4 b4;
                b4.x = f2bf(v4.x); b4.y = f2bf(v4.y); b4.z = f2bf(v4.z); b4.w = f2bf(v4.w);
                int byte = m*128 + ((k4*8) ^ ((m & 7) << 4));
                *reinterpret_cast<ushort4*>(reinterpret_cast<char*>(Asm) + byte) = b4;
            }
        }
        {
            int n = t >> 3, k8 = t & 7;
            #pragma unroll
            for (int p = 0; p < 4; ++p, n += 32) {
                uint4 u4 = *reinterpret_cast<const uint4*>(&Wc[(size_t)(n0 + n)*256 + k0 + k8*8]);
                int byte = n*128 + ((k8 ^ (n & 7)) << 4);
                *reinterpret_cast<uint4*>(reinterpret_cast<char*>(Bsm) + byte) = u4;
            }
        }
        __syncthreads();
        #pragma unroll
        for (int ks = 0; ks < 2; ++ks) {
            bf16x8 af[4], bfv[4];
            #pragma unroll
            for (int mi = 0; mi < 4; ++mi) {
                int m = wm*64 + mi*16 + lrow;
                int u = (ks*4 + lk) ^ (m & 7);
                af[mi] = *reinterpret_cast<const bf16x8*>(reinterpret_cast<const char*>(Asm) + m*128 + u*16);
            }
            #pragma unroll
            for (int ni = 0; ni < 4; ++ni) {
                int n = wn*64 + ni*16 + lrow;
                int u = (ks*4 + lk) ^ (n & 7);
                bfv[ni] = *reinterpret_cast<const bf16x8*>(reinterpret_cast<const char*>(Bsm) + n*128 + u*16);
            }
            #pragma unroll
            for (int mi = 0; mi < 4; ++mi)
                #pragma unroll
                for (int ni = 0; ni < 4; ++ni)
                    acc[mi][ni] = __builtin_amdgcn_mfma_f32_16x16x32_bf16(af[mi], bfv[ni], acc[mi][ni], 0, 0, 0);
        }
    }
    #pragma unroll
    for (int mi = 0; mi < 4; ++mi) {
        #pragma unroll
        for (int ni = 0; ni < 4; ++ni) {
            int gcol = n0 + wn*64 + ni*16 + lrow;
            int c = gcol & 127;
            float bias = bcat[gcol];
            #pragma unroll
            for (int r = 0; r < 4; ++r) {
                size_t grow = (size_t)m0 + wm*64 + mi*16 + lk*4 + r;
                float val = acc[mi][ni][r] + bias;
                if (ntile == 0)      q[grow*128 + c] = val;
                else if (ntile == 1) k[grow*128 + c] = val;
                else                 vb[grow*128 + c] = f2bf(val);
            }
        }
    }
}

// ---------------------------------------------------------------- depthwise 3x3 LEPE conv (bf16 v, 2ch/lane) -> xsp f32
__global__ __launch_bounds__(256) void k_conv(const unsigned short* __restrict__ vb, const float* __restrict__ w,
                                              const float* __restrict__ bias, float* __restrict__ xsp)
{
    __shared__ float wsm[128*9];
    __shared__ float bsm[128];
    int t = threadIdx.x;
    for (int i = t; i < 128*9; i += 256) wsm[i] = w[i];
    if (t < 128) bsm[t] = bias[t];
    __syncthreads();
    int c0 = (t & 63)*2, jj = t >> 6;
    int j = blockIdx.x*4 + jj;
    int i = blockIdx.y;
    int b = blockIdx.z;
    float a0 = bsm[c0], a1 = bsm[c0+1];
    #pragma unroll
    for (int ki = 0; ki < 3; ++ki) {
        int ii = i + ki - 1;
        if (ii < 0 || ii >= 128) continue;
        #pragma unroll
        for (int kj = 0; kj < 3; ++kj) {
            int jx = j + kj - 1;
            if (jx < 0 || jx >= 128) continue;
            ushort2 uv = *reinterpret_cast<const ushort2*>(&vb[((size_t)b*NN + ii*128 + jx)*128 + c0]);
            a0 += wsm[c0*9 + ki*3 + kj] * bf2f(uv.x);
            a1 += wsm[(c0+1)*9 + ki*3 + kj] * bf2f(uv.y);
        }
    }
    float2 r; r.x = a0; r.y = a1;
    *reinterpret_cast<float2*>(&xsp[((size_t)b*NN + i*128 + j)*128 + c0]) = r;
}

// ---------------------------------------------------------------- fused k-features + kv partials via MFMA
// grid (32 chunks, 32 bh), block 256; 512 positions per block as 2 halves of 256.
__global__ __launch_bounds__(256) void k_featkv(
    const float* __restrict__ kin, const unsigned short* __restrict__ vb,
    const float* __restrict__ W, const float* __restrict__ bvec,
    const float* __restrict__ fs, const float* __restrict__ fc,
    float* __restrict__ kvpart, float* __restrict__ kmpart)
{
    __shared__ unsigned short kfsT[64][264];   // [feature e][pos]
    __shared__ unsigned short vT[32][264];     // [dim d][pos]
    __shared__ float kms[8][64];
    int bh = blockIdx.y, b = bh >> 2, h = bh & 3;
    int chunk = blockIdx.x;
    int t = threadIdx.x, lane = t & 63;
    int e = t & 31, g = t >> 5;
    int wave = t >> 6, wm = wave >> 1, wn = wave & 1;
    float Wr[32];
    #pragma unroll
    for (int dd = 0; dd < 32; ++dd) Wr[dd] = W[e*32 + dd];
    float bias = bvec[e];
    float km_lo = 0.f, km_hi = 0.f;
    f32x4 acc[2];
    acc[0] = (f32x4){0.f,0.f,0.f,0.f};
    acc[1] = (f32x4){0.f,0.f,0.f,0.f};

    for (int half = 0; half < 2; ++half) {
        int n0 = chunk*512 + half*256;
        __syncthreads();   // protect LDS reuse (prev half MFMA reads done)
        // stage vT (bf16, transposed): thread -> d = e, pos = g*32 + i
        {
            int posb = g*32;
            for (int i = 0; i < 32; ++i) {
                int pos = posb + i;
                vT[e][pos] = vb[((size_t)(b*NN + n0 + pos))*128 + h*32 + e];
            }
        }
        // phase 1: features for 32 positions per group
        for (int p = 0; p < 32; ++p) {
            int pos = g*32 + p;
            const float* krow = &kin[((size_t)(b*NN + n0 + pos))*128 + h*32];
            float y = bias;
            #pragma unroll
            for (int q4 = 0; q4 < 8; ++q4) {
                float4 tv = *reinterpret_cast<const float4*>(&krow[q4*4]);
                y += Wr[q4*4]*tv.x + Wr[q4*4+1]*tv.y + Wr[q4*4+2]*tv.z + Wr[q4*4+3]*tv.w;
            }
            float y2 = 2.f*y;
            float elo = __expf(y2), ehi = __expf(-y2);
            float s = elo + ehi;
            #pragma unroll
            for (int off = 16; off >= 1; off >>= 1) s += __shfl_xor(s, off);
            float rs = 1.f / s;
            float klo = elo*rs, khi = ehi*rs;
            km_lo += klo; km_hi += khi;
            size_t fbase = ((size_t)h*NN + n0 + pos)*16 + e;
            float fsv = (e < 16) ? fs[fbase] : 1.0f;
            float fcv = (e < 16) ? fc[fbase] : 1.0f;
            kfsT[e][pos]      = f2bf(klo*fcv + khi*fsv);
            kfsT[e + 32][pos] = f2bf(khi*fcv - klo*fsv);
        }
        __syncthreads();
        // MFMA: kv[e][d] partial += kfsT(64 x 256) x vT^T(256 x 32)
        #pragma unroll
        for (int ks = 0; ks < 8; ++ks) {
            bf16x8 bfr = *reinterpret_cast<const bf16x8*>(&vT[wn*16 + (lane & 15)][ks*32 + (lane >> 4)*8]);
            #pragma unroll
            for (int mi = 0; mi < 2; ++mi) {
                bf16x8 af = *reinterpret_cast<const bf16x8*>(&kfsT[(wm*2+mi)*16 + (lane & 15)][ks*32 + (lane >> 4)*8]);
                acc[mi] = __builtin_amdgcn_mfma_f32_16x16x32_bf16(af, bfr, acc[mi], 0, 0, 0);
            }
        }
    }
    // write kv partials
    {
        int d = wn*16 + (lane & 15);
        #pragma unroll
        for (int mi = 0; mi < 2; ++mi) {
            #pragma unroll
            for (int r = 0; r < 4; ++r) {
                int eo = (wm*2+mi)*16 + (lane >> 4)*4 + r;
                kvpart[((size_t)(bh*32 + chunk))*2048 + eo*32 + d] = acc[mi][r];
            }
        }
    }
    kms[g][e] = km_lo; kms[g][32 + e] = km_hi;
    __syncthreads();
    if (t < 64) {
        float s = 0.f;
        #pragma unroll
        for (int gg = 0; gg < 8; ++gg) s += kms[gg][t];
        kmpart[(size_t)(bh*32 + chunk)*64 + t] = s;
    }
}

// ---------------------------------------------------------------- reduce kv partials (x 1/N)
__global__ __launch_bounds__(256) void k_kvred2(const float* __restrict__ kvpart, float* __restrict__ kv)
{
    int bh = blockIdx.x >> 3, part = blockIdx.x & 7;
    int idx = part*256 + threadIdx.x;
    float s = 0.f;
    for (int c = 0; c < 32; ++c) s += kvpart[((size_t)(bh*32 + c))*2048 + idx];
    kv[(size_t)bh*2048 + idx] = s * (1.f/16384.f);
}

__global__ __launch_bounds__(64) void k_kmred(const float* __restrict__ kmpart, float* __restrict__ kmean)
{
    int bh = blockIdx.x, t = threadIdx.x;
    float s = 0.f;
    for (int c = 0; c < 32; ++c) s += kmpart[(size_t)(bh*32 + c)*64 + t];
    kmean[bh*64 + t] = s * (1.f/16384.f);
}

// ---------------------------------------------------------------- fused q-features + xs MFMA -> xsb (bf16)
// grid (128 chunks, 32 bh), block 256; 128 positions per block.
__global__ __launch_bounds__(256) void k_featxs(
    const float* __restrict__ qin, const float* __restrict__ W, const float* __restrict__ bvec,
    const float* __restrict__ fs, const float* __restrict__ fc,
    const float* __restrict__ kv, const float* __restrict__ kmean,
    const float* __restrict__ xsp, unsigned short* __restrict__ xsb)
{
    __shared__ unsigned short qfs[128][64];  // swizzled bf16 [pos][feature]
    int bh = blockIdx.y, b = bh >> 2, h = bh & 3;
    int n0 = blockIdx.x * 128;
    int t = threadIdx.x, lane = t & 63;
    int e = t & 31, g = t >> 5;
    int wave = t >> 6;
    float Wr[32];
    #pragma unroll
    for (int dd = 0; dd < 32; ++dd) Wr[dd] = W[e*32 + dd];
    float bias = bvec[e];
    float km_lo = kmean[bh*64 + e], km_hi = kmean[bh*64 + 32 + e];
    // preload B fragments (kv) once: bfr[nt][ks]
    bf16x8 bfr[2][2];
    #pragma unroll
    for (int nt = 0; nt < 2; ++nt)
        #pragma unroll
        for (int ks = 0; ks < 2; ++ks) {
            bf16x8 tmp;
            #pragma unroll
            for (int j = 0; j < 8; ++j)
                tmp[j] = (short)f2bf(kv[(size_t)bh*2048 + (ks*32 + (lane>>4)*8 + j)*32 + nt*16 + (lane & 15)]);
            bfr[nt][ks] = tmp;
        }
    // phase 1: features, z folded in; 16 positions per group
    for (int p = 0; p < 16; ++p) {
        int pos = g*16 + p;
        const float* qrow = &qin[((size_t)(b*NN + n0 + pos))*128 + h*32];
        float y = bias;
        #pragma unroll
        for (int q4 = 0; q4 < 8; ++q4) {
            float4 tv = *reinterpret_cast<const float4*>(&qrow[q4*4]);
            y += Wr[q4*4]*tv.x + Wr[q4*4+1]*tv.y + Wr[q4*4+2]*tv.z + Wr[q4*4+3]*tv.w;
        }
        float y2 = 2.f*y;
        float elo = __expf(y2), ehi = __expf(-y2);
        float s = elo + ehi;
        float w = elo*km_lo + ehi*km_hi;
        #pragma unroll
        for (int off = 16; off >= 1; off >>= 1) { s += __shfl_xor(s, off); w += __shfl_xor(w, off); }
        float rs = 1.f / s;
        float z = 1.f / (w*rs + 1e-6f);
        float qlo = elo*rs, qhi = ehi*rs;
        size_t fbase = ((size_t)h*NN + n0 + pos)*16 + e;
        float fsv = (e < 16) ? fs[fbase] : 1.0f;
        float fcv = (e < 16) ? fc[fbase] : 1.0f;
        float a1 = z*(qlo*fcv + qhi*fsv);
        float a2 = z*(qhi*fcv - qlo*fsv);
        char* base = reinterpret_cast<char*>(qfs) + pos*128;
        int u1 = (e >> 3) ^ (pos & 7);
        int u2 = (4 + (e >> 3)) ^ (pos & 7);
        *reinterpret_cast<unsigned short*>(base + u1*16 + (e & 7)*2) = f2bf(a1);
        *reinterpret_cast<unsigned short*>(base + u2*16 + (e & 7)*2) = f2bf(a2);
    }
    __syncthreads();
    // phase 2: xs = qfs(128x64) @ kv(64x32) via MFMA
    f32x4 acc[2][2];
    #pragma unroll
    for (int mi = 0; mi < 2; ++mi)
        #pragma unroll
        for (int nt = 0; nt < 2; ++nt) acc[mi][nt] = (f32x4){0.f,0.f,0.f,0.f};
    #pragma unroll
    for (int ks = 0; ks < 2; ++ks) {
        #pragma unroll
        for (int mi = 0; mi < 2; ++mi) {
            int prow = (wave*2 + mi)*16 + (lane & 15);
            int unit = (ks*4 + (lane >> 4)) ^ (prow & 7);
            bf16x8 af = *reinterpret_cast<const bf16x8*>(reinterpret_cast<const char*>(qfs) + prow*128 + unit*16);
            #pragma unroll
            for (int nt = 0; nt < 2; ++nt)
                acc[mi][nt] = __builtin_amdgcn_mfma_f32_16x16x32_bf16(af, bfr[nt][ks], acc[mi][nt], 0, 0, 0);
        }
    }
    // epilogue: xsb = bf16(xsp + xs)
    #pragma unroll
    for (int mi = 0; mi < 2; ++mi) {
        #pragma unroll
        for (int nt = 0; nt < 2; ++nt) {
            int d = nt*16 + (lane & 15);
            #pragma unroll
            for (int r = 0; r < 4; ++r) {
                int pos = (wave*2 + mi)*16 + (lane >> 4)*4 + r;
                size_t off = ((size_t)(b*NN + n0 + pos))*128 + h*32 + d;
                xsb[off] = f2bf(xsp[off] + acc[mi][nt][r]);
            }
        }
    }
}

// ---------------------------------------------------------------- gram via MFMA + fused norms
// grid (32 kc, 8 b); per block: full 128x128 tile, K=512; writes Gpart[b][kc]
__global__ __launch_bounds__(256) void k_gram(const float* __restrict__ q, const float* __restrict__ k,
                                              float* __restrict__ Gpart,
                                              float* __restrict__ qn2, float* __restrict__ kn2)
{
    __shared__ unsigned short qTs[128][40];
    __shared__ unsigned short kTs[128][40];
    int kc = blockIdx.x, bb = blockIdx.y;
    int t = threadIdx.x, lane = t & 63;
    int wave = t >> 6, wm = wave >> 1, wn = wave & 1;
    int c = t & 127, lh = t >> 7;
    float qa = 0.f, ka = 0.f;
    f32x4 acc[4][4];
    #pragma unroll
    for (int i = 0; i < 4; ++i)
        #pragma unroll
        for (int j = 0; j < 4; ++j) acc[i][j] = (f32x4){0.f,0.f,0.f,0.f};

    for (int kt = 0; kt < 16; ++kt) {
        __syncthreads();
        #pragma unroll
        for (int i = 0; i < 16; ++i) {
            int l = lh*16 + i;
            size_t pos = (size_t)bb*NN + kc*512 + kt*32 + l;
            float qv = q[pos*128 + c];
            float kvv = k[pos*128 + c];
            qa += qv*qv; ka += kvv*kvv;
            qTs[c][l] = f2bf(qv);
            kTs[c][l] = f2bf(kvv);
        }
        __syncthreads();
        bf16x8 af[4];
        #pragma unroll
        for (int mi = 0; mi < 4; ++mi)
            af[mi] = *reinterpret_cast<const bf16x8*>(&qTs[wm*64 + mi*16 + (lane & 15)][(lane >> 4)*8]);
        #pragma unroll
        for (int ni = 0; ni < 4; ++ni) {
            bf16x8 bfr = *reinterpret_cast<const bf16x8*>(&kTs[wn*64 + ni*16 + (lane & 15)][(lane >> 4)*8]);
            #pragma unroll
            for (int mi = 0; mi < 4; ++mi)
                acc[mi][ni] = __builtin_amdgcn_mfma_f32_16x16x32_bf16(af[mi], bfr, acc[mi][ni], 0, 0, 0);
        }
    }
    // write partial tile
    size_t gb = ((size_t)(bb*32 + kc))*16384;
    #pragma unroll
    for (int mi = 0; mi < 4; ++mi) {
        #pragma unroll
        for (int ni = 0; ni < 4; ++ni) {
            int d = wn*64 + ni*16 + (lane & 15);
            #pragma unroll
            for (int r = 0; r < 4; ++r) {
                int cc = wm*64 + mi*16 + (lane >> 4)*4 + r;
                Gpart[gb + (size_t)cc*128 + d] = acc[mi][ni][r];
            }
        }
    }
    atomicAdd(&qn2[bb*128 + c], qa);
    atomicAdd(&kn2[bb*128 + c], ka);
}

// ---------------------------------------------------------------- reduce Gpart -> G
__global__ __launch_bounds__(256) void k_gramred(const float* __restrict__ Gpart, float* __restrict__ G)
{
    int bb = blockIdx.y;
    int idx = blockIdx.x*256 + threadIdx.x;   // 64 x 256 = 16384
    float s = 0.f;
    for (int kc = 0; kc < 32; ++kc) s += Gpart[((size_t)(bb*32 + kc))*16384 + idx];
    G[(size_t)bb*16384 + idx] = s;
}

// ---------------------------------------------------------------- channel attention softmax
__global__ __launch_bounds__(128) void k_attnsm(const float* __restrict__ G, const float* __restrict__ qn2,
    const float* __restrict__ kn2, const float* __restrict__ temp, float* __restrict__ attn)
{
    __shared__ float red[128];
    int row = blockIdx.x;
    int b = row >> 7, c = row & 127;
    int t = threadIdx.x;
    float qn = fmaxf(sqrtf(qn2[b*128 + c]), 1e-12f);
    float kn = fmaxf(sqrtf(kn2[b*128 + t]), 1e-12f);
    float val = G[(size_t)row*128 + t] / (qn*kn) * temp[c];
    red[t] = val; __syncthreads();
    for (int s = 64; s > 0; s >>= 1) { if (t < s) red[t] = fmaxf(red[t], red[t+s]); __syncthreads(); }
    float mm = red[0]; __syncthreads();
    float ev = expf(val - mm);
    red[t] = ev; __syncthreads();
    for (int s = 64; s > 0; s >>= 1) { if (t < s) red[t] += red[t+s]; __syncthreads(); }
    attn[(size_t)row*128 + t] = ev / red[0];
}

// ---------------------------------------------------------------- per-batch B matrix, transposed bf16
__global__ __launch_bounds__(256) void k_bmat(const float* __restrict__ attn, const float* __restrict__ Wp,
                                              unsigned short* __restrict__ BmatT)
{
    int b = blockIdx.y, kk = blockIdx.x, o = threadIdx.x;
    float val;
    if (kk < 128) {
        val = Wp[(size_t)o*256 + kk];
    } else {
        int d = kk - 128;
        __shared__ float a[128];
        if (o < 128) a[o] = attn[((size_t)b*128 + o)*128 + d];
        __syncthreads();
        float acc = 0.f;
        for (int c = 0; c < 128; ++c) acc += a[c] * Wp[(size_t)o*256 + 128 + c];
        val = acc;
    }
    BmatT[((size_t)b*256 + o)*256 + kk] = f2bf(val);
}

// ---------------------------------------------------------------- final MFMA GEMM: out = [xsb | vb] @ BmatT_b^T + bp
__global__ __launch_bounds__(256) void k_out_mfma(const unsigned short* __restrict__ xsb,
    const unsigned short* __restrict__ vb, const unsigned short* __restrict__ BmatT,
    const float* __restrict__ bp, float* __restrict__ out)
{
    __shared__ unsigned short Asm[128*64];
    __shared__ unsigned short Bsm[128*64];
    int t = threadIdx.x;
    int lin = blockIdx.y*2 + blockIdx.x;
    int logical = (lin & 7)*256 + (lin >> 3);
    int ntile = logical & 1;
    int mtile = logical >> 1;
    int m0 = mtile * 128;
    int n0 = ntile * 128;
    int b = mtile >> 7;
    int wave = t >> 6, lane = t & 63;
    int wm = wave >> 1, wn = wave & 1;
    int lrow = lane & 15, lk = lane >> 4;
    f32x4 acc[4][4];
    #pragma unroll
    for (int i = 0; i < 4; ++i)
        #pragma unroll
        for (int j = 0; j < 4; ++j) acc[i][j] = (f32x4){0.f,0.f,0.f,0.f};

    for (int kt = 0; kt < 4; ++kt) {
        const unsigned short* Asrc = (kt < 2) ? xsb : vb;
        int ka0 = (kt & 1) * 64;
        if (kt) __syncthreads();
        {
            int m = t >> 3, k8 = t & 7;
            #pragma unroll
            for (int p = 0; p < 4; ++p, m += 32) {
                uint4 u4 = *reinterpret_cast<const uint4*>(&Asrc[(size_t)(m0 + m)*128 + ka0 + k8*8]);
                int byte = m*128 + ((k8 ^ (m & 7)) << 4);
                *reinterpret_cast<uint4*>(reinterpret_cast<char*>(Asm) + byte) = u4;
            }
        }
        {
            int n = t >> 3, k8 = t & 7;
            #pragma unroll
            for (int p = 0; p < 4; ++p, n += 32) {
                uint4 u4 = *reinterpret_cast<const uint4*>(&BmatT[((size_t)b*256 + n0 + n)*256 + kt*64 + k8*8]);
                int byte = n*128 + ((k8 ^ (n & 7)) << 4);
                *reinterpret_cast<uint4*>(reinterpret_cast<char*>(Bsm) + byte) = u4;
            }
        }
        __syncthreads();
        #pragma unroll
        for (int ks = 0; ks < 2; ++ks) {
            bf16x8 af[4], bfv[4];
            #pragma unroll
            for (int mi = 0; mi < 4; ++mi) {
                int m = wm*64 + mi*16 + lrow;
                int u = (ks*4 + lk) ^ (m & 7);
                af[mi] = *reinterpret_cast<const bf16x8*>(reinterpret_cast<const char*>(Asm) + m*128 + u*16);
            }
            #pragma unroll
            for (int ni = 0; ni < 4; ++ni) {
                int n = wn*64 + ni*16 + lrow;
                int u = (ks*4 + lk) ^ (n & 7);
                bfv[ni] = *reinterpret_cast<const bf16x8*>(reinterpret_cast<const char*>(Bsm) + n*128 + u*16);
            }
            #pragma unroll
            for (int mi = 0; mi < 4; ++mi)
                #pragma unroll
                for (int ni = 0; ni < 4; ++ni)
                    acc[mi][ni] = __builtin_amdgcn_mfma_f32_16x16x32_bf16(af[mi], bfv[ni], acc[mi][ni], 0, 0, 0);
        }
    }
    #pragma unroll
    for (int mi = 0; mi < 4; ++mi) {
        #pragma unroll
        for (int ni = 0; ni < 4; ++ni) {
            int gcol = n0 + wn*64 + ni*16 + lrow;
            float bias = bp[gcol];
            #pragma unroll
            for (int r = 0; r < 4; ++r) {
                size_t grow = (size_t)m0 + wm*64 + mi*16 + lk*4 + r;
                out[grow*256 + gcol] = acc[mi][ni][r] + bias;
            }
        }
    }
}

extern "C" void kernel_launch(void* const* d_in, const int* in_sizes, int n_in,
                              void* d_out, int out_size, void* d_ws, size_t ws_size,
                              hipStream_t stream)
{
    (void)in_sizes; (void)n_in; (void)out_size; (void)ws_size;
    const float* x    = (const float*)d_in[0];
    const float* Wq   = (const float*)d_in[1];
    const float* bq   = (const float*)d_in[2];
    const float* Wk   = (const float*)d_in[3];
    const float* bk   = (const float*)d_in[4];
    const float* Wv   = (const float*)d_in[5];
    const float* bv   = (const float*)d_in[6];
    const float* Whq  = (const float*)d_in[7];
    const float* bhq  = (const float*)d_in[8];
    const float* Whk  = (const float*)d_in[9];
    const float* bhk  = (const float*)d_in[10];
    const float* sinc = (const float*)d_in[11];
    const float* cosc = (const float*)d_in[12];
    const float* lw   = (const float*)d_in[13];
    const float* lb   = (const float*)d_in[14];
    const float* temp = (const float*)d_in[15];
    const float* Wp   = (const float*)d_in[16];
    const float* bp   = (const float*)d_in[17];

    float* out = (float*)d_out;
    float* q   = out + 33554432;
    float* k   = out + 50331648;
    float* ws  = (float*)d_ws;

    float* xsp    = ws + WS_XSP;
    float* Gpart  = ws + WS_XSP;     // reuses xsp after featxs consumed it
    unsigned short* vbuf = (unsigned short*)(ws + WS_VB);
    unsigned short* xsb  = (unsigned short*)(ws + WS_XSB);
    float* fs     = ws + WS_FS;
    float* fc     = ws + WS_FC;
    float* inv    = ws + WS_INV;
    float* cs     = ws + WS_CS;
    float* cc     = ws + WS_CC;
    unsigned short* Wc = (unsigned short*)(ws + WS_WCAT);
    float* bcat   = ws + WS_BCAT;
    float* kvpart = ws + WS_KVPART;
    float* kmpart = ws + WS_KMPART;
    float* kv     = ws + WS_KV;
    float* kmean  = ws + WS_KMEAN;
    float* qn2    = ws + WS_QN2;
    float* kn2    = ws + WS_KN2;
    float* G      = ws + WS_G;
    float* attn   = ws + WS_ATTN;
    unsigned short* BmatT = (unsigned short*)(ws + WS_BMATT);

    hipMemsetAsync(qn2, 0, 2048*sizeof(float), stream);

    k_setup<<<1, 64, 0, stream>>>(sinc, cosc, inv, cs, cc);
    k_tables<<<4096, 256, 0, stream>>>(inv, cs, cc, fs, fc);
    k_wprep<<<384, 256, 0, stream>>>(Wq, Wk, Wv, bq, bk, bv, Wc, bcat);
    k_qkv_mfma<<<dim3(3, 1024), 256, 0, stream>>>(x, Wc, bcat, q, k, vbuf);
    k_conv<<<dim3(32, 128, 8), 256, 0, stream>>>(vbuf, lw, lb, xsp);
    k_featkv<<<dim3(32, 32), 256, 0, stream>>>(k, vbuf, Whk, bhk, fs, fc, kvpart, kmpart);
    k_kvred2<<<256, 256, 0, stream>>>(kvpart, kv);
    k_kmred<<<32, 64, 0, stream>>>(kmpart, kmean);
    k_featxs<<<dim3(128, 32), 256, 0, stream>>>(q, Whq, bhq, fs, fc, kv, kmean, xsp, xsb);
    k_gram<<<dim3(32, 8), 256, 0, stream>>>(q, k, Gpart, qn2, kn2);
    k_gramred<<<dim3(64, 8), 256, 0, stream>>>(Gpart, G);
    k_attnsm<<<1024, 128, 0, stream>>>(G, qn2, kn2, temp, attn);
    k_bmat<<<dim3(256, 8), 256, 0, stream>>>(attn, Wp, BmatT);
    k_out_mfma<<<dim3(2, 1024), 256, 0, stream>>>(xsb, vbuf, BmatT, bp, out);
}

// Round 5
// 467.529 us; speedup vs baseline: 5.0081x; 1.4359x over previous
//
#include <hip/hip_runtime.h>
#include <cmath>

#define NB 8
#define NN 16384
#define DIN 23
#define DOUT 16

typedef short bf16x8 __attribute__((ext_vector_type(8)));
typedef float f32x4 __attribute__((ext_vector_type(4)));

__device__ __forceinline__ unsigned short f2bf(float f) {
    unsigned int u = __float_as_uint(f);
    u += 0x7FFFu + ((u >> 16) & 1u);
    return (unsigned short)(u >> 16);
}
__device__ __forceinline__ float bf2f(unsigned short s) {
    return __uint_as_float(((unsigned int)s) << 16);
}
__device__ __forceinline__ float rcpf(float x) { return __builtin_amdgcn_rcpf(x); }

__device__ __forceinline__ bf16x8 cvt8(float4 a, float4 b) {
    bf16x8 r;
    r[0]=(short)f2bf(a.x); r[1]=(short)f2bf(a.y); r[2]=(short)f2bf(a.z); r[3]=(short)f2bf(a.w);
    r[4]=(short)f2bf(b.x); r[5]=(short)f2bf(b.y); r[6]=(short)f2bf(b.z); r[7]=(short)f2bf(b.w);
    return r;
}
__device__ __forceinline__ void red16(f32x4& s) {
    #pragma unroll
    for (int off = 1; off < 16; off <<= 1) {
        s[0] += __shfl_xor(s[0], off); s[1] += __shfl_xor(s[1], off);
        s[2] += __shfl_xor(s[2], off); s[3] += __shfl_xor(s[3], off);
    }
}
__device__ __forceinline__ void red16x2(f32x4& s, f32x4& w) {
    #pragma unroll
    for (int off = 1; off < 16; off <<= 1) {
        s[0] += __shfl_xor(s[0], off); s[1] += __shfl_xor(s[1], off);
        s[2] += __shfl_xor(s[2], off); s[3] += __shfl_xor(s[3], off);
        w[0] += __shfl_xor(w[0], off); w[1] += __shfl_xor(w[1], off);
        w[2] += __shfl_xor(w[2], off); w[3] += __shfl_xor(w[3], off);
    }
}

// workspace offsets in floats (unchanged budget ~154 MB)
#define WS_XSP    ((size_t)0)          // 16,777,216 f32 (conv out; later reused as Gpart)
#define WS_VB     ((size_t)16777216)   // v bf16
#define WS_XSB    ((size_t)25165824)   // xs bf16
#define WS_FS     ((size_t)33554432)   // fsc packed u32 [4][NN][16]
#define WS_FC     ((size_t)34603008)   // (free)
#define WS_INV    ((size_t)35651584)
#define WS_CS     ((size_t)35651648)
#define WS_CC     ((size_t)35653184)
#define WS_WCAT   ((size_t)35654720)
#define WS_BCAT   ((size_t)35703872)
#define WS_KVPART ((size_t)35704256)   // 32bh x 32chunk x 2048
#define WS_KMPART ((size_t)37801408)   // 32 x 32 x 64
#define WS_KV     ((size_t)37866944)   // kvT bf16 [32][32][64]
#define WS_KMEAN  ((size_t)37932480)
#define WS_QN2    ((size_t)37934528)
#define WS_KN2    ((size_t)37935552)
#define WS_G      ((size_t)37936576)
#define WS_ATTN   ((size_t)38067648)
#define WS_BMATT  ((size_t)38198720)

// ---------------------------------------------------------------- setup
__global__ void k_setup(const float* __restrict__ sc, const float* __restrict__ ccin,
                        float* __restrict__ inv, float* __restrict__ cs, float* __restrict__ cc)
{
    int t = threadIdx.x; // 64 threads
    if (t < DIN) inv[t] = (float)pow(10000.0, -((double)(2 * t)) / 64.0);
    int h = t >> 4, d = t & 15;
    float ss = 0.f, s2 = 0.f;
    for (int D = 0; D < DIN; ++D) { ss += sc[(h*DIN + D)*DOUT + d]; s2 += ccin[(h*DIN + D)*DOUT + d]; }
    float rs = 1.f / ss, r2 = 1.f / s2;
    for (int D = 0; D < DIN; ++D) {
        cs[(h*DIN + D)*DOUT + d] = sc[(h*DIN + D)*DOUT + d] * rs;
        cc[(h*DIN + D)*DOUT + d] = ccin[(h*DIN + D)*DOUT + d] * r2;
    }
}

// ---------------------------------------------------------------- FoPE table fsc: [h][t][16] packed (fs lo16, fc hi16) bf16
__global__ __launch_bounds__(256) void k_tables(const float* __restrict__ inv, const float* __restrict__ cs,
                                                const float* __restrict__ cc,
                                                unsigned int* __restrict__ fsc)
{
    int t = threadIdx.x;
    int sub = t >> 6, lane = t & 63;
    int tpos = blockIdx.x*4 + sub;
    __shared__ float ssin[4][DIN], scos[4][DIN];
    if (lane < DIN) { float fr = (float)tpos * inv[lane]; ssin[sub][lane] = sinf(fr); scos[sub][lane] = cosf(fr); }
    __syncthreads();
    int h = lane >> 4, d = lane & 15;
    float as = 0.f, ac = 0.f;
    for (int D = 0; D < DIN; ++D) { as += ssin[sub][D]*cs[(h*DIN + D)*DOUT + d]; ac += scos[sub][D]*cc[(h*DIN + D)*DOUT + d]; }
    fsc[((size_t)h*NN + tpos)*16 + d] = ((unsigned int)f2bf(ac) << 16) | (unsigned int)f2bf(as);
}

// ---------------------------------------------------------------- weights -> bf16 concat [384][256] + bias concat
__global__ __launch_bounds__(256) void k_wprep(
    const float* __restrict__ Wq, const float* __restrict__ Wk, const float* __restrict__ Wv,
    const float* __restrict__ bq, const float* __restrict__ bk, const float* __restrict__ bv,
    unsigned short* __restrict__ Wc, float* __restrict__ bcat)
{
    int row = blockIdx.x, t = threadIdx.x;
    const float* W = (row < 128) ? Wq : (row < 256) ? Wk : Wv;
    const float* bb = (row < 128) ? bq : (row < 256) ? bk : bv;
    int r = row & 127;
    Wc[(size_t)row*256 + t] = f2bf(W[(size_t)r*256 + t]);
    if (t == 0) bcat[row] = bb[r];
}

// ---------------------------------------------------------------- QKV MFMA GEMM: [q|k|v] = x @ Wc^T + b
__global__ __launch_bounds__(256) void k_qkv_mfma(const float* __restrict__ x,
    const unsigned short* __restrict__ Wc, const float* __restrict__ bcat,
    float* __restrict__ q, float* __restrict__ k, unsigned short* __restrict__ vb)
{
    __shared__ unsigned short Asm[128*64];
    __shared__ unsigned short Bsm[128*64];
    int t = threadIdx.x;
    int lin = blockIdx.y*3 + blockIdx.x;
    int logical = (lin & 7)*384 + (lin >> 3);
    int ntile = logical % 3;
    int mtile = logical / 3;
    int m0 = mtile * 128;
    int n0 = ntile * 128;
    int wave = t >> 6, lane = t & 63;
    int wm = wave >> 1, wn = wave & 1;
    int lrow = lane & 15, lk = lane >> 4;
    f32x4 acc[4][4];
    #pragma unroll
    for (int i = 0; i < 4; ++i)
        #pragma unroll
        for (int j = 0; j < 4; ++j) acc[i][j] = (f32x4){0.f,0.f,0.f,0.f};

    for (int kt = 0; kt < 4; ++kt) {
        int k0 = kt * 64;
        if (kt) __syncthreads();
        {
            int m = t >> 4, k4 = t & 15;
            #pragma unroll
            for (int p = 0; p < 8; ++p, m += 16) {
                float4 v4 = *reinterpret_cast<const float4*>(&x[(size_t)(m0 + m)*256 + k0 + k4*4]);
                ushort4 b4;
                b4.x = f2bf(v4.x); b4.y = f2bf(v4.y); b4.z = f2bf(v4.z); b4.w = f2bf(v4.w);
                int byte = m*128 + ((k4*8) ^ ((m & 7) << 4));
                *reinterpret_cast<ushort4*>(reinterpret_cast<char*>(Asm) + byte) = b4;
            }
        }
        {
            int n = t >> 3, k8 = t & 7;
            #pragma unroll
            for (int p = 0; p < 4; ++p, n += 32) {
                uint4 u4 = *reinterpret_cast<const uint4*>(&Wc[(size_t)(n0 + n)*256 + k0 + k8*8]);
                int byte = n*128 + ((k8 ^ (n & 7)) << 4);
                *reinterpret_cast<uint4*>(reinterpret_cast<char*>(Bsm) + byte) = u4;
            }
        }
        __syncthreads();
        #pragma unroll
        for (int ks = 0; ks < 2; ++ks) {
            bf16x8 af[4], bfv[4];
            #pragma unroll
            for (int mi = 0; mi < 4; ++mi) {
                int m = wm*64 + mi*16 + lrow;
                int u = (ks*4 + lk) ^ (m & 7);
                af[mi] = *reinterpret_cast<const bf16x8*>(reinterpret_cast<const char*>(Asm) + m*128 + u*16);
            }
            #pragma unroll
            for (int ni = 0; ni < 4; ++ni) {
                int n = wn*64 + ni*16 + lrow;
                int u = (ks*4 + lk) ^ (n & 7);
                bfv[ni] = *reinterpret_cast<const bf16x8*>(reinterpret_cast<const char*>(Bsm) + n*128 + u*16);
            }
            #pragma unroll
            for (int mi = 0; mi < 4; ++mi)
                #pragma unroll
                for (int ni = 0; ni < 4; ++ni)
                    acc[mi][ni] = __builtin_amdgcn_mfma_f32_16x16x32_bf16(af[mi], bfv[ni], acc[mi][ni], 0, 0, 0);
        }
    }
    #pragma unroll
    for (int mi = 0; mi < 4; ++mi) {
        #pragma unroll
        for (int ni = 0; ni < 4; ++ni) {
            int gcol = n0 + wn*64 + ni*16 + lrow;
            int c = gcol & 127;
            float bias = bcat[gcol];
            #pragma unroll
            for (int r = 0; r < 4; ++r) {
                size_t grow = (size_t)m0 + wm*64 + mi*16 + lk*4 + r;
                float val = acc[mi][ni][r] + bias;
                if (ntile == 0)      q[grow*128 + c] = val;
                else if (ntile == 1) k[grow*128 + c] = val;
                else                 vb[grow*128 + c] = f2bf(val);
            }
        }
    }
}

// ---------------------------------------------------------------- depthwise 3x3 LEPE conv, 8 ch/lane
__global__ __launch_bounds__(256) void k_conv(const unsigned short* __restrict__ vb, const float* __restrict__ w,
                                              const float* __restrict__ bias, float* __restrict__ xsp)
{
    __shared__ float wsmT[9][128];
    __shared__ float bsm[128];
    int t = threadIdx.x;
    for (int i = t; i < 1152; i += 256) wsmT[i % 9][i / 9] = w[i];
    if (t < 128) bsm[t] = bias[t];
    __syncthreads();
    int jj = t >> 4, c8 = (t & 15) * 8;
    int j = blockIdx.x * 16 + jj;
    int i = blockIdx.y, b = blockIdx.z;
    float acc[8];
    #pragma unroll
    for (int l = 0; l < 8; ++l) acc[l] = bsm[c8 + l];
    #pragma unroll
    for (int di = 0; di < 3; ++di) {
        int ii = i + di - 1;
        if (ii < 0 || ii >= 128) continue;
        #pragma unroll
        for (int dj = 0; dj < 3; ++dj) {
            int jx = j + dj - 1;
            if (jx < 0 || jx >= 128) continue;
            uint4 u = *reinterpret_cast<const uint4*>(&vb[((size_t)b*NN + ii*128 + jx)*128 + c8]);
            const unsigned short* us = (const unsigned short*)&u;
            int kk = di*3 + dj;
            #pragma unroll
            for (int l = 0; l < 8; ++l)
                acc[l] += wsmT[kk][c8 + l] * bf2f(us[l]);
        }
    }
    float4 r0 = {acc[0],acc[1],acc[2],acc[3]}, r1 = {acc[4],acc[5],acc[6],acc[7]};
    size_t ob = ((size_t)b*NN + i*128 + j)*128 + c8;
    *reinterpret_cast<float4*>(&xsp[ob]) = r0;
    *reinterpret_cast<float4*>(&xsp[ob+4]) = r1;
}

// ---------------------------------------------------------------- fused k-features (MFMA) + kv partials (MFMA)
// grid (32 chunks, 32 bh), block 256; each wave owns 128 pos (2 rounds x 64).
__global__ __launch_bounds__(256) void k_featkv(
    const float* __restrict__ kin, const unsigned short* __restrict__ vb,
    const float* __restrict__ W, const float* __restrict__ bvec,
    const unsigned int* __restrict__ fsc,
    float* __restrict__ kvpart, float* __restrict__ kmpart)
{
    __shared__ __align__(16) unsigned short kfsT[4][64][72];  // [wave][f][pos]
    __shared__ __align__(16) unsigned short vT[4][32][72];    // [wave][d][pos]
    __shared__ float kms[4][64];
    int bh = blockIdx.y, b = bh >> 2, h = bh & 3;
    int chunk = blockIdx.x;
    int t = threadIdx.x, w = t >> 6, lane = t & 63;
    int c = lane & 15, g = lane >> 4;
    // y-GEMM B frags: W[e][d], e=c(+16), d=g*8+j
    bf16x8 wb[2];
    #pragma unroll
    for (int et = 0; et < 2; ++et) {
        float4 wa = *reinterpret_cast<const float4*>(&W[(c + et*16)*32 + g*8]);
        float4 wb2 = *reinterpret_cast<const float4*>(&W[(c + et*16)*32 + g*8 + 4]);
        wb[et] = cvt8(wa, wb2);
    }
    float bias0 = bvec[c], bias1 = bvec[c + 16];
    f32x4 acc[4][2];
    #pragma unroll
    for (int i = 0; i < 4; ++i) { acc[i][0] = (f32x4){0.f,0.f,0.f,0.f}; acc[i][1] = (f32x4){0.f,0.f,0.f,0.f}; }
    f32x4 km0 = {0.f,0.f,0.f,0.f}, km1 = km0, km2 = km0, km3 = km0;

    for (int rnd = 0; rnd < 2; ++rnd) {
        int p0 = chunk*512 + w*128 + rnd*64;
        // stage vT (coalesced global, b64 transposed writes)
        {
            uint4 vr[4];
            size_t vbase = ((size_t)(b*NN + p0 + c*4))*128 + h*32 + g*8;
            #pragma unroll
            for (int i = 0; i < 4; ++i) vr[i] = *reinterpret_cast<const uint4*>(&vb[vbase + (size_t)i*128]);
            #pragma unroll
            for (int j = 0; j < 8; ++j) {
                ushort4 pk;
                pk.x = ((const unsigned short*)&vr[0])[j];
                pk.y = ((const unsigned short*)&vr[1])[j];
                pk.z = ((const unsigned short*)&vr[2])[j];
                pk.w = ((const unsigned short*)&vr[3])[j];
                *reinterpret_cast<ushort4*>(&vT[w][g*8 + j][c*4]) = pk;
            }
        }
        // phase 1: y = k @ W^T via MFMA, softmax in C-regs, fope, b64 writes
        #pragma unroll
        for (int mt = 0; mt < 4; ++mt) {
            int posA = p0 + mt*16 + c;
            const float* krow = &kin[((size_t)(b*NN + posA))*128 + h*32 + g*8];
            float4 ka = *reinterpret_cast<const float4*>(krow);
            float4 kb2 = *reinterpret_cast<const float4*>(krow + 4);
            bf16x8 af = cvt8(ka, kb2);
            f32x4 z4 = {0.f,0.f,0.f,0.f};
            f32x4 y0 = __builtin_amdgcn_mfma_f32_16x16x32_bf16(af, wb[0], z4, 0, 0, 0);
            f32x4 y1 = __builtin_amdgcn_mfma_f32_16x16x32_bf16(af, wb[1], z4, 0, 0, 0);
            f32x4 el0, eh0, el1, eh1;
            #pragma unroll
            for (int r = 0; r < 4; ++r) {
                float a0 = 2.f*(y0[r] + bias0);
                float a1 = 2.f*(y1[r] + bias1);
                el0[r] = __expf(a0); eh0[r] = __expf(-a0);
                el1[r] = __expf(a1); eh1[r] = __expf(-a1);
            }
            f32x4 s = el0 + eh0 + el1 + eh1;
            red16(s);
            f32x4 rs;
            #pragma unroll
            for (int r = 0; r < 4; ++r) rs[r] = rcpf(s[r]);
            f32x4 klo0 = el0*rs, khi0 = eh0*rs, klo1 = el1*rs, khi1 = eh1*rs;
            km0 += klo0; km1 += khi0; km2 += klo1; km3 += khi1;
            int posC = p0 + mt*16 + g*4;
            ushort4 wlo0, whi0, wlo1, whi1;
            #pragma unroll
            for (int r = 0; r < 4; ++r) {
                unsigned int u = fsc[((size_t)h*NN + posC + r)*16 + c];
                float fsv = bf2f((unsigned short)(u & 0xffffu));
                float fcv = bf2f((unsigned short)(u >> 16));
                ((unsigned short*)&wlo0)[r] = f2bf(klo0[r]*fcv + khi0[r]*fsv);
                ((unsigned short*)&whi0)[r] = f2bf(khi0[r]*fcv - klo0[r]*fsv);
                ((unsigned short*)&wlo1)[r] = f2bf(klo1[r] + khi1[r]);
                ((unsigned short*)&whi1)[r] = f2bf(khi1[r] - klo1[r]);
            }
            int po = mt*16 + g*4;
            *reinterpret_cast<ushort4*>(&kfsT[w][c][po])      = wlo0;
            *reinterpret_cast<ushort4*>(&kfsT[w][32 + c][po]) = whi0;
            *reinterpret_cast<ushort4*>(&kfsT[w][16 + c][po]) = wlo1;
            *reinterpret_cast<ushort4*>(&kfsT[w][48 + c][po]) = whi1;
        }
        // phase 2: kv[f][d] += kfope^T x v (K = this wave's 64 pos)
        #pragma unroll
        for (int ks = 0; ks < 2; ++ks) {
            bf16x8 bf0 = *reinterpret_cast<const bf16x8*>(&vT[w][c][ks*32 + g*8]);
            bf16x8 bf1 = *reinterpret_cast<const bf16x8*>(&vT[w][16 + c][ks*32 + g*8]);
            #pragma unroll
            for (int mt = 0; mt < 4; ++mt) {
                bf16x8 af2 = *reinterpret_cast<const bf16x8*>(&kfsT[w][mt*16 + c][ks*32 + g*8]);
                acc[mt][0] = __builtin_amdgcn_mfma_f32_16x16x32_bf16(af2, bf0, acc[mt][0], 0, 0, 0);
                acc[mt][1] = __builtin_amdgcn_mfma_f32_16x16x32_bf16(af2, bf1, acc[mt][1], 0, 0, 0);
            }
        }
    }
    // kmean partials
    float kv0 = km0[0]+km0[1]+km0[2]+km0[3];
    float kv1 = km1[0]+km1[1]+km1[2]+km1[3];
    float kv2 = km2[0]+km2[1]+km2[2]+km2[3];
    float kv3 = km3[0]+km3[1]+km3[2]+km3[3];
    kv0 += __shfl_xor(kv0, 16); kv0 += __shfl_xor(kv0, 32);
    kv1 += __shfl_xor(kv1, 16); kv1 += __shfl_xor(kv1, 32);
    kv2 += __shfl_xor(kv2, 16); kv2 += __shfl_xor(kv2, 32);
    kv3 += __shfl_xor(kv3, 16); kv3 += __shfl_xor(kv3, 32);
    if (g == 0) {
        kms[w][c] = kv0; kms[w][16 + c] = kv2; kms[w][32 + c] = kv1; kms[w][48 + c] = kv3;
    }
    // write per-wave kv to LDS (aliases own kfsT region), then block reduce
    float* kvred = reinterpret_cast<float*>(&kfsT[0][0][0]);   // [(w*32+d)*72 + f]
    #pragma unroll
    for (int mt = 0; mt < 4; ++mt)
        #pragma unroll
        for (int nt = 0; nt < 2; ++nt) {
            int d = nt*16 + c;
            *reinterpret_cast<f32x4*>(&kvred[(size_t)(w*32 + d)*72 + mt*16 + g*4]) = acc[mt][nt];
        }
    __syncthreads();
    #pragma unroll
    for (int i = 0; i < 8; ++i) {
        int idx = t*8 + i;   // f*32 + d
        int f = idx >> 5, d = idx & 31;
        float s2 = kvred[(0*32 + d)*72 + f] + kvred[(1*32 + d)*72 + f]
                 + kvred[(2*32 + d)*72 + f] + kvred[(3*32 + d)*72 + f];
        kvpart[((size_t)(bh*32 + chunk))*2048 + idx] = s2;
    }
    if (t < 64) {
        float s2 = kms[0][t] + kms[1][t] + kms[2][t] + kms[3][t];
        kmpart[(size_t)(bh*32 + chunk)*64 + t] = s2;
    }
}

// ---------------------------------------------------------------- reduce kv partials -> kvT bf16 [bh][d][f] (x 1/N)
__global__ __launch_bounds__(256) void k_kvred2(const float* __restrict__ kvpart, unsigned short* __restrict__ kvT)
{
    int bh = blockIdx.x >> 3, part = blockIdx.x & 7;
    int idx = part*256 + threadIdx.x;   // f*32 + d
    float s = 0.f;
    for (int cidx = 0; cidx < 32; ++cidx) s += kvpart[((size_t)(bh*32 + cidx))*2048 + idx];
    int f = idx >> 5, d = idx & 31;
    kvT[(size_t)bh*2048 + d*64 + f] = f2bf(s * (1.f/16384.f));
}

__global__ __launch_bounds__(64) void k_kmred(const float* __restrict__ kmpart, float* __restrict__ kmean)
{
    int bh = blockIdx.x, t = threadIdx.x;
    float s = 0.f;
    for (int cidx = 0; cidx < 32; ++cidx) s += kmpart[(size_t)(bh*32 + cidx)*64 + t];
    kmean[bh*64 + t] = s * (1.f/16384.f);
}

// ---------------------------------------------------------------- fused q-features (MFMA) + xs (MFMA) -> xsb bf16
// grid (32 chunks, 32 bh); each wave owns 128 pos (2 rounds x 64).
__global__ __launch_bounds__(256) void k_featxs(
    const float* __restrict__ qin, const float* __restrict__ W, const float* __restrict__ bvec,
    const unsigned int* __restrict__ fsc, const unsigned short* __restrict__ kvT,
    const float* __restrict__ kmean, const float* __restrict__ xsp, unsigned short* __restrict__ xsb)
{
    __shared__ __align__(16) unsigned short qfs[4][64][72];   // [wave][pos][f]
    int bh = blockIdx.y, b = bh >> 2, h = bh & 3;
    int chunk = blockIdx.x;
    int t = threadIdx.x, w = t >> 6, lane = t & 63;
    int c = lane & 15, g = lane >> 4;
    bf16x8 wb[2];
    #pragma unroll
    for (int et = 0; et < 2; ++et) {
        float4 wa = *reinterpret_cast<const float4*>(&W[(c + et*16)*32 + g*8]);
        float4 wb2 = *reinterpret_cast<const float4*>(&W[(c + et*16)*32 + g*8 + 4]);
        wb[et] = cvt8(wa, wb2);
    }
    float bias0 = bvec[c], bias1 = bvec[c + 16];
    float kml0 = kmean[bh*64 + c],      kml1 = kmean[bh*64 + 16 + c];
    float kmh0 = kmean[bh*64 + 32 + c], kmh1 = kmean[bh*64 + 48 + c];
    bf16x8 bkv[2][2];
    #pragma unroll
    for (int nt = 0; nt < 2; ++nt)
        #pragma unroll
        for (int ks = 0; ks < 2; ++ks)
            bkv[nt][ks] = *reinterpret_cast<const bf16x8*>(&kvT[(size_t)bh*2048 + (nt*16 + c)*64 + ks*32 + g*8]);

    for (int rnd = 0; rnd < 2; ++rnd) {
        int p0 = chunk*512 + w*128 + rnd*64;
        // phase 1
        #pragma unroll
        for (int mt = 0; mt < 4; ++mt) {
            int posA = p0 + mt*16 + c;
            const float* qrow = &qin[((size_t)(b*NN + posA))*128 + h*32 + g*8];
            float4 qa = *reinterpret_cast<const float4*>(qrow);
            float4 qb2 = *reinterpret_cast<const float4*>(qrow + 4);
            bf16x8 af = cvt8(qa, qb2);
            f32x4 z4 = {0.f,0.f,0.f,0.f};
            f32x4 y0 = __builtin_amdgcn_mfma_f32_16x16x32_bf16(af, wb[0], z4, 0, 0, 0);
            f32x4 y1 = __builtin_amdgcn_mfma_f32_16x16x32_bf16(af, wb[1], z4, 0, 0, 0);
            f32x4 el0, eh0, el1, eh1;
            #pragma unroll
            for (int r = 0; r < 4; ++r) {
                float a0 = 2.f*(y0[r] + bias0);
                float a1 = 2.f*(y1[r] + bias1);
                el0[r] = __expf(a0); eh0[r] = __expf(-a0);
                el1[r] = __expf(a1); eh1[r] = __expf(-a1);
            }
            f32x4 s = el0 + eh0 + el1 + eh1;
            f32x4 wv = el0*kml0 + eh0*kmh0 + el1*kml1 + eh1*kmh1;
            red16x2(s, wv);
            f32x4 zr;
            #pragma unroll
            for (int r = 0; r < 4; ++r) {
                float rs = rcpf(s[r]);
                float z = rcpf(wv[r]*rs + 1e-6f);
                zr[r] = z*rs;
            }
            int posC = mt*16 + g*4;   // local row within wave tile
            #pragma unroll
            for (int r = 0; r < 4; ++r) {
                unsigned int u = fsc[((size_t)h*NN + p0 + posC + r)*16 + c];
                float fsv = bf2f((unsigned short)(u & 0xffffu));
                float fcv = bf2f((unsigned short)(u >> 16));
                qfs[w][posC + r][c]      = f2bf(zr[r]*(el0[r]*fcv + eh0[r]*fsv));
                qfs[w][posC + r][32 + c] = f2bf(zr[r]*(eh0[r]*fcv - el0[r]*fsv));
                qfs[w][posC + r][16 + c] = f2bf(zr[r]*(el1[r] + eh1[r]));
                qfs[w][posC + r][48 + c] = f2bf(zr[r]*(eh1[r] - el1[r]));
            }
        }
        // phase 2: xs = qfs(64x64) @ kv(64x32)
        f32x4 acc[4][2];
        #pragma unroll
        for (int i = 0; i < 4; ++i) { acc[i][0] = (f32x4){0.f,0.f,0.f,0.f}; acc[i][1] = (f32x4){0.f,0.f,0.f,0.f}; }
        #pragma unroll
        for (int ks = 0; ks < 2; ++ks)
            #pragma unroll
            for (int mt = 0; mt < 4; ++mt) {
                bf16x8 af2 = *reinterpret_cast<const bf16x8*>(&qfs[w][mt*16 + c][ks*32 + g*8]);
                acc[mt][0] = __builtin_amdgcn_mfma_f32_16x16x32_bf16(af2, bkv[0][ks], acc[mt][0], 0, 0, 0);
                acc[mt][1] = __builtin_amdgcn_mfma_f32_16x16x32_bf16(af2, bkv[1][ks], acc[mt][1], 0, 0, 0);
            }
        // epilogue: xsb = bf16(xsp + xs)
        #pragma unroll
        for (int mt = 0; mt < 4; ++mt)
            #pragma unroll
            for (int nt = 0; nt < 2; ++nt) {
                int d = nt*16 + c;
                #pragma unroll
                for (int r = 0; r < 4; ++r) {
                    int pos = p0 + mt*16 + g*4 + r;
                    size_t off = ((size_t)(b*NN + pos))*128 + h*32 + d;
                    xsb[off] = f2bf(xsp[off] + acc[mt][nt][r]);
                }
            }
    }
}

// ---------------------------------------------------------------- gram via MFMA + fused norms (64 K-chunks)
__global__ __launch_bounds__(256) void k_gram(const float* __restrict__ q, const float* __restrict__ k,
                                              float* __restrict__ Gpart,
                                              float* __restrict__ qn2, float* __restrict__ kn2)
{
    __shared__ unsigned short qTs[128][40];
    __shared__ unsigned short kTs[128][40];
    int kc = blockIdx.x, bb = blockIdx.y;
    int t = threadIdx.x, lane = t & 63;
    int wave = t >> 6, wm = wave >> 1, wn = wave & 1;
    int c = t & 127, lh = t >> 7;
    float qa = 0.f, ka = 0.f;
    f32x4 acc[4][4];
    #pragma unroll
    for (int i = 0; i < 4; ++i)
        #pragma unroll
        for (int j = 0; j < 4; ++j) acc[i][j] = (f32x4){0.f,0.f,0.f,0.f};

    for (int kt = 0; kt < 8; ++kt) {
        __syncthreads();
        #pragma unroll
        for (int i = 0; i < 16; ++i) {
            int l = lh*16 + i;
            size_t pos = (size_t)bb*NN + kc*256 + kt*32 + l;
            float qv = q[pos*128 + c];
            float kvv = k[pos*128 + c];
            qa += qv*qv; ka += kvv*kvv;
            qTs[c][l] = f2bf(qv);
            kTs[c][l] = f2bf(kvv);
        }
        __syncthreads();
        bf16x8 af[4];
        #pragma unroll
        for (int mi = 0; mi < 4; ++mi)
            af[mi] = *reinterpret_cast<const bf16x8*>(&qTs[wm*64 + mi*16 + (lane & 15)][(lane >> 4)*8]);
        #pragma unroll
        for (int ni = 0; ni < 4; ++ni) {
            bf16x8 bfr = *reinterpret_cast<const bf16x8*>(&kTs[wn*64 + ni*16 + (lane & 15)][(lane >> 4)*8]);
            #pragma unroll
            for (int mi = 0; mi < 4; ++mi)
                acc[mi][ni] = __builtin_amdgcn_mfma_f32_16x16x32_bf16(af[mi], bfr, acc[mi][ni], 0, 0, 0);
        }
    }
    size_t gb = ((size_t)(bb*64 + kc))*16384;
    #pragma unroll
    for (int mi = 0; mi < 4; ++mi) {
        #pragma unroll
        for (int ni = 0; ni < 4; ++ni) {
            int d = wn*64 + ni*16 + (lane & 15);
            #pragma unroll
            for (int r = 0; r < 4; ++r) {
                int cc = wm*64 + mi*16 + (lane >> 4)*4 + r;
                Gpart[gb + (size_t)cc*128 + d] = acc[mi][ni][r];
            }
        }
    }
    atomicAdd(&qn2[bb*128 + c], qa);
    atomicAdd(&kn2[bb*128 + c], ka);
}

// ---------------------------------------------------------------- reduce Gpart -> G
__global__ __launch_bounds__(256) void k_gramred(const float* __restrict__ Gpart, float* __restrict__ G)
{
    int bb = blockIdx.y;
    int idx = blockIdx.x*256 + threadIdx.x;
    float s = 0.f;
    for (int kc = 0; kc < 64; ++kc) s += Gpart[((size_t)(bb*64 + kc))*16384 + idx];
    G[(size_t)bb*16384 + idx] = s;
}

// ---------------------------------------------------------------- channel attention softmax
__global__ __launch_bounds__(128) void k_attnsm(const float* __restrict__ G, const float* __restrict__ qn2,
    const float* __restrict__ kn2, const float* __restrict__ temp, float* __restrict__ attn)
{
    __shared__ float red[128];
    int row = blockIdx.x;
    int b = row >> 7, c = row & 127;
    int t = threadIdx.x;
    float qn = fmaxf(sqrtf(qn2[b*128 + c]), 1e-12f);
    float kn = fmaxf(sqrtf(kn2[b*128 + t]), 1e-12f);
    float val = G[(size_t)row*128 + t] / (qn*kn) * temp[c];
    red[t] = val; __syncthreads();
    for (int s = 64; s > 0; s >>= 1) { if (t < s) red[t] = fmaxf(red[t], red[t+s]); __syncthreads(); }
    float mm = red[0]; __syncthreads();
    float ev = expf(val - mm);
    red[t] = ev; __syncthreads();
    for (int s = 64; s > 0; s >>= 1) { if (t < s) red[t] += red[t+s]; __syncthreads(); }
    attn[(size_t)row*128 + t] = ev / red[0];
}

// ---------------------------------------------------------------- per-batch B matrix, transposed bf16
__global__ __launch_bounds__(256) void k_bmat(const float* __restrict__ attn, const float* __restrict__ Wp,
                                              unsigned short* __restrict__ BmatT)
{
    int b = blockIdx.y, kk = blockIdx.x, o = threadIdx.x;
    float val;
    if (kk < 128) {
        val = Wp[(size_t)o*256 + kk];
    } else {
        int d = kk - 128;
        __shared__ float a[128];
        if (o < 128) a[o] = attn[((size_t)b*128 + o)*128 + d];
        __syncthreads();
        float acc = 0.f;
        for (int c = 0; c < 128; ++c) acc += a[c] * Wp[(size_t)o*256 + 128 + c];
        val = acc;
    }
    BmatT[((size_t)b*256 + o)*256 + kk] = f2bf(val);
}

// ---------------------------------------------------------------- final MFMA GEMM: out = [xsb | vb] @ BmatT_b^T + bp
__global__ __launch_bounds__(256) void k_out_mfma(const unsigned short* __restrict__ xsb,
    const unsigned short* __restrict__ vb, const unsigned short* __restrict__ BmatT,
    const float* __restrict__ bp, float* __restrict__ out)
{
    __shared__ unsigned short Asm[128*64];
    __shared__ unsigned short Bsm[128*64];
    int t = threadIdx.x;
    int lin = blockIdx.y*2 + blockIdx.x;
    int logical = (lin & 7)*256 + (lin >> 3);
    int ntile = logical & 1;
    int mtile = logical >> 1;
    int m0 = mtile * 128;
    int n0 = ntile * 128;
    int b = mtile >> 7;
    int wave = t >> 6, lane = t & 63;
    int wm = wave >> 1, wn = wave & 1;
    int lrow = lane & 15, lk = lane >> 4;
    f32x4 acc[4][4];
    #pragma unroll
    for (int i = 0; i < 4; ++i)
        #pragma unroll
        for (int j = 0; j < 4; ++j) acc[i][j] = (f32x4){0.f,0.f,0.f,0.f};

    for (int kt = 0; kt < 4; ++kt) {
        const unsigned short* Asrc = (kt < 2) ? xsb : vb;
        int ka0 = (kt & 1) * 64;
        if (kt) __syncthreads();
        {
            int m = t >> 3, k8 = t & 7;
            #pragma unroll
            for (int p = 0; p < 4; ++p, m += 32) {
                uint4 u4 = *reinterpret_cast<const uint4*>(&Asrc[(size_t)(m0 + m)*128 + ka0 + k8*8]);
                int byte = m*128 + ((k8 ^ (m & 7)) << 4);
                *reinterpret_cast<uint4*>(reinterpret_cast<char*>(Asm) + byte) = u4;
            }
        }
        {
            int n = t >> 3, k8 = t & 7;
            #pragma unroll
            for (int p = 0; p < 4; ++p, n += 32) {
                uint4 u4 = *reinterpret_cast<const uint4*>(&BmatT[((size_t)b*256 + n0 + n)*256 + kt*64 + k8*8]);
                int byte = n*128 + ((k8 ^ (n & 7)) << 4);
                *reinterpret_cast<uint4*>(reinterpret_cast<char*>(Bsm) + byte) = u4;
            }
        }
        __syncthreads();
        #pragma unroll
        for (int ks = 0; ks < 2; ++ks) {
            bf16x8 af[4], bfv[4];
            #pragma unroll
            for (int mi = 0; mi < 4; ++mi) {
                int m = wm*64 + mi*16 + lrow;
                int u = (ks*4 + lk) ^ (m & 7);
                af[mi] = *reinterpret_cast<const bf16x8*>(reinterpret_cast<const char*>(Asm) + m*128 + u*16);
            }
            #pragma unroll
            for (int ni = 0; ni < 4; ++ni) {
                int n = wn*64 + ni*16 + lrow;
                int u = (ks*4 + lk) ^ (n & 7);
                bfv[ni] = *reinterpret_cast<const bf16x8*>(reinterpret_cast<const char*>(Bsm) + n*128 + u*16);
            }
            #pragma unroll
            for (int mi = 0; mi < 4; ++mi)
                #pragma unroll
                for (int ni = 0; ni < 4; ++ni)
                    acc[mi][ni] = __builtin_amdgcn_mfma_f32_16x16x32_bf16(af[mi], bfv[ni], acc[mi][ni], 0, 0, 0);
        }
    }
    #pragma unroll
    for (int mi = 0; mi < 4; ++mi) {
        #pragma unroll
        for (int ni = 0; ni < 4; ++ni) {
            int gcol = n0 + wn*64 + ni*16 + lrow;
            float bias = bp[gcol];
            #pragma unroll
            for (int r = 0; r < 4; ++r) {
                size_t grow = (size_t)m0 + wm*64 + mi*16 + lk*4 + r;
                out[grow*256 + gcol] = acc[mi][ni][r] + bias;
            }
        }
    }
}

extern "C" void kernel_launch(void* const* d_in, const int* in_sizes, int n_in,
                              void* d_out, int out_size, void* d_ws, size_t ws_size,
                              hipStream_t stream)
{
    (void)in_sizes; (void)n_in; (void)out_size; (void)ws_size;
    const float* x    = (const float*)d_in[0];
    const float* Wq   = (const float*)d_in[1];
    const float* bq   = (const float*)d_in[2];
    const float* Wk   = (const float*)d_in[3];
    const float* bk   = (const float*)d_in[4];
    const float* Wv   = (const float*)d_in[5];
    const float* bv   = (const float*)d_in[6];
    const float* Whq  = (const float*)d_in[7];
    const float* bhq  = (const float*)d_in[8];
    const float* Whk  = (const float*)d_in[9];
    const float* bhk  = (const float*)d_in[10];
    const float* sinc = (const float*)d_in[11];
    const float* cosc = (const float*)d_in[12];
    const float* lw   = (const float*)d_in[13];
    const float* lb   = (const float*)d_in[14];
    const float* temp = (const float*)d_in[15];
    const float* Wp   = (const float*)d_in[16];
    const float* bp   = (const float*)d_in[17];

    float* out = (float*)d_out;
    float* q   = out + 33554432;
    float* k   = out + 50331648;
    float* ws  = (float*)d_ws;

    float* xsp    = ws + WS_XSP;
    float* Gpart  = ws + WS_XSP;     // reused after featxs consumed xsp
    unsigned short* vbuf = (unsigned short*)(ws + WS_VB);
    unsigned short* xsb  = (unsigned short*)(ws + WS_XSB);
    unsigned int* fsc = (unsigned int*)(ws + WS_FS);
    float* inv    = ws + WS_INV;
    float* cs     = ws + WS_CS;
    float* cc     = ws + WS_CC;
    unsigned short* Wc = (unsigned short*)(ws + WS_WCAT);
    float* bcat   = ws + WS_BCAT;
    float* kvpart = ws + WS_KVPART;
    float* kmpart = ws + WS_KMPART;
    unsigned short* kvT = (unsigned short*)(ws + WS_KV);
    float* kmean  = ws + WS_KMEAN;
    float* qn2    = ws + WS_QN2;
    float* kn2    = ws + WS_KN2;
    float* G      = ws + WS_G;
    float* attn   = ws + WS_ATTN;
    unsigned short* BmatT = (unsigned short*)(ws + WS_BMATT);

    hipMemsetAsync(qn2, 0, 2048*sizeof(float), stream);

    k_setup<<<1, 64, 0, stream>>>(sinc, cosc, inv, cs, cc);
    k_tables<<<4096, 256, 0, stream>>>(inv, cs, cc, fsc);
    k_wprep<<<384, 256, 0, stream>>>(Wq, Wk, Wv, bq, bk, bv, Wc, bcat);
    k_qkv_mfma<<<dim3(3, 1024), 256, 0, stream>>>(x, Wc, bcat, q, k, vbuf);
    k_conv<<<dim3(8, 128, 8), 256, 0, stream>>>(vbuf, lw, lb, xsp);
    k_featkv<<<dim3(32, 32), 256, 0, stream>>>(k, vbuf, Whk, bhk, fsc, kvpart, kmpart);
    k_kvred2<<<256, 256, 0, stream>>>(kvpart, kvT);
    k_kmred<<<32, 64, 0, stream>>>(kmpart, kmean);
    k_featxs<<<dim3(32, 32), 256, 0, stream>>>(q, Whq, bhq, fsc, kvT, kmean, xsp, xsb);
    k_gram<<<dim3(64, 8), 256, 0, stream>>>(q, k, Gpart, qn2, kn2);
    k_gramred<<<dim3(64, 8), 256, 0, stream>>>(Gpart, G);
    k_attnsm<<<1024, 128, 0, stream>>>(G, qn2, kn2, temp, attn);
    k_bmat<<<dim3(256, 8), 256, 0, stream>>>(attn, Wp, BmatT);
    k_out_mfma<<<dim3(2, 1024), 256, 0, stream>>>(xsb, vbuf, BmatT, bp, out);
}

// Round 6
// 440.189 us; speedup vs baseline: 5.3191x; 1.0621x over previous
//
#include <hip/hip_runtime.h>
#include <cmath>

#define NB 8
#define NN 16384
#define DIN 23
#define DOUT 16

typedef short bf16x8 __attribute__((ext_vector_type(8)));
typedef float f32x4 __attribute__((ext_vector_type(4)));

__device__ __forceinline__ unsigned short f2bf(float f) {
    unsigned int u = __float_as_uint(f);
    u += 0x7FFFu + ((u >> 16) & 1u);
    return (unsigned short)(u >> 16);
}
__device__ __forceinline__ float bf2f(unsigned short s) {
    return __uint_as_float(((unsigned int)s) << 16);
}
__device__ __forceinline__ float rcpf(float x) { return __builtin_amdgcn_rcpf(x); }

__device__ __forceinline__ bf16x8 cvt8(float4 a, float4 b) {
    bf16x8 r;
    r[0]=(short)f2bf(a.x); r[1]=(short)f2bf(a.y); r[2]=(short)f2bf(a.z); r[3]=(short)f2bf(a.w);
    r[4]=(short)f2bf(b.x); r[5]=(short)f2bf(b.y); r[6]=(short)f2bf(b.z); r[7]=(short)f2bf(b.w);
    return r;
}
__device__ __forceinline__ void red16(f32x4& s) {
    #pragma unroll
    for (int off = 1; off < 16; off <<= 1) {
        s[0] += __shfl_xor(s[0], off); s[1] += __shfl_xor(s[1], off);
        s[2] += __shfl_xor(s[2], off); s[3] += __shfl_xor(s[3], off);
    }
}
__device__ __forceinline__ void red16x2(f32x4& s, f32x4& w) {
    #pragma unroll
    for (int off = 1; off < 16; off <<= 1) {
        s[0] += __shfl_xor(s[0], off); s[1] += __shfl_xor(s[1], off);
        s[2] += __shfl_xor(s[2], off); s[3] += __shfl_xor(s[3], off);
        w[0] += __shfl_xor(w[0], off); w[1] += __shfl_xor(w[1], off);
        w[2] += __shfl_xor(w[2], off); w[3] += __shfl_xor(w[3], off);
    }
}

// workspace offsets in floats (ws_size = 1 GiB per harness fill; we use ~221 MB)
#define WS_XSP    ((size_t)0)          // 16,777,216 f32 (conv out; later reused as Gpart)
#define WS_VB     ((size_t)16777216)   // v bf16
#define WS_XSB    ((size_t)25165824)   // xs bf16
#define WS_FS     ((size_t)33554432)   // fsc packed u32 [4][NN][16]
#define WS_INV    ((size_t)35651584)
#define WS_CS     ((size_t)35651648)
#define WS_CC     ((size_t)35653184)
#define WS_WCAT   ((size_t)35654720)
#define WS_BCAT   ((size_t)35703872)
#define WS_KVPART ((size_t)35704256)   // 32bh x 32chunk x 2048
#define WS_KMPART ((size_t)37801408)
#define WS_KV     ((size_t)37866944)   // kvT bf16 [32][32][64]
#define WS_KMEAN  ((size_t)37932480)
#define WS_QN2    ((size_t)37934528)
#define WS_KN2    ((size_t)37935552)
#define WS_G      ((size_t)37936576)
#define WS_ATTN   ((size_t)38067648)
#define WS_BMATT  ((size_t)38198720)   // 262,144 slots
#define WS_QB     ((size_t)38460864)   // 8,388,608 slots = q bf16
#define WS_KB     ((size_t)46849472)   // 8,388,608 slots = k bf16

// ---------------------------------------------------------------- setup
__global__ void k_setup(const float* __restrict__ sc, const float* __restrict__ ccin,
                        float* __restrict__ inv, float* __restrict__ cs, float* __restrict__ cc)
{
    int t = threadIdx.x; // 64 threads
    if (t < DIN) inv[t] = (float)pow(10000.0, -((double)(2 * t)) / 64.0);
    int h = t >> 4, d = t & 15;
    float ss = 0.f, s2 = 0.f;
    for (int D = 0; D < DIN; ++D) { ss += sc[(h*DIN + D)*DOUT + d]; s2 += ccin[(h*DIN + D)*DOUT + d]; }
    float rs = 1.f / ss, r2 = 1.f / s2;
    for (int D = 0; D < DIN; ++D) {
        cs[(h*DIN + D)*DOUT + d] = sc[(h*DIN + D)*DOUT + d] * rs;
        cc[(h*DIN + D)*DOUT + d] = ccin[(h*DIN + D)*DOUT + d] * r2;
    }
}

// ---------------------------------------------------------------- FoPE table fsc: [h][t][16] packed (fs lo16, fc hi16) bf16
__global__ __launch_bounds__(256) void k_tables(const float* __restrict__ inv, const float* __restrict__ cs,
                                                const float* __restrict__ cc,
                                                unsigned int* __restrict__ fsc)
{
    int t = threadIdx.x;
    int sub = t >> 6, lane = t & 63;
    int tpos = blockIdx.x*4 + sub;
    __shared__ float ssin[4][DIN], scos[4][DIN];
    if (lane < DIN) { float fr = (float)tpos * inv[lane]; ssin[sub][lane] = sinf(fr); scos[sub][lane] = cosf(fr); }
    __syncthreads();
    int h = lane >> 4, d = lane & 15;
    float as = 0.f, ac = 0.f;
    for (int D = 0; D < DIN; ++D) { as += ssin[sub][D]*cs[(h*DIN + D)*DOUT + d]; ac += scos[sub][D]*cc[(h*DIN + D)*DOUT + d]; }
    fsc[((size_t)h*NN + tpos)*16 + d] = ((unsigned int)f2bf(ac) << 16) | (unsigned int)f2bf(as);
}

// ---------------------------------------------------------------- weights -> bf16 concat [384][256] + bias concat
__global__ __launch_bounds__(256) void k_wprep(
    const float* __restrict__ Wq, const float* __restrict__ Wk, const float* __restrict__ Wv,
    const float* __restrict__ bq, const float* __restrict__ bk, const float* __restrict__ bv,
    unsigned short* __restrict__ Wc, float* __restrict__ bcat)
{
    int row = blockIdx.x, t = threadIdx.x;
    const float* W = (row < 128) ? Wq : (row < 256) ? Wk : Wv;
    const float* bb = (row < 128) ? bq : (row < 256) ? bk : bv;
    int r = row & 127;
    Wc[(size_t)row*256 + t] = f2bf(W[(size_t)r*256 + t]);
    if (t == 0) bcat[row] = bb[r];
}

// ---------------------------------------------------------------- QKV MFMA GEMM with T14 prefetch: [q|k|v] = x @ Wc^T + b
__global__ __launch_bounds__(256) void k_qkv_mfma(const float* __restrict__ x,
    const unsigned short* __restrict__ Wc, const float* __restrict__ bcat,
    float* __restrict__ q, float* __restrict__ k,
    unsigned short* __restrict__ qb, unsigned short* __restrict__ kb,
    unsigned short* __restrict__ vb)
{
    __shared__ unsigned short Asm[128*64];
    __shared__ unsigned short Bsm[128*64];
    int t = threadIdx.x;
    int lin = blockIdx.y*3 + blockIdx.x;
    int logical = (lin & 7)*384 + (lin >> 3);
    int ntile = logical % 3;
    int mtile = logical / 3;
    int m0 = mtile * 128;
    int n0 = ntile * 128;
    int wave = t >> 6, lane = t & 63;
    int wm = wave >> 1, wn = wave & 1;
    int lrow = lane & 15, lk = lane >> 4;
    f32x4 acc[4][4];
    #pragma unroll
    for (int i = 0; i < 4; ++i)
        #pragma unroll
        for (int j = 0; j < 4; ++j) acc[i][j] = (f32x4){0.f,0.f,0.f,0.f};

    int am = t >> 4, ak4 = t & 15;
    size_t arow = (size_t)(m0 + am);
    float4 pa[8];
    // prologue: issue kt=0 A-loads
    #pragma unroll
    for (int p = 0; p < 8; ++p)
        pa[p] = *reinterpret_cast<const float4*>(&x[(arow + p*16)*256 + ak4*4]);

    #pragma unroll
    for (int kt = 0; kt < 4; ++kt) {
        int k0 = kt * 64;
        if (kt) __syncthreads();
        // ds_write A from prefetched regs (cvt f32->bf16, swizzled)
        #pragma unroll
        for (int p = 0; p < 8; ++p) {
            int m = am + p*16;
            ushort4 b4;
            b4.x = f2bf(pa[p].x); b4.y = f2bf(pa[p].y); b4.z = f2bf(pa[p].z); b4.w = f2bf(pa[p].w);
            int byte = m*128 + ((ak4*8) ^ ((m & 7) << 4));
            *reinterpret_cast<ushort4*>(reinterpret_cast<char*>(Asm) + byte) = b4;
        }
        // B stage (synchronous; Wc is L2-hot)
        {
            int n = t >> 3, k8 = t & 7;
            #pragma unroll
            for (int p = 0; p < 4; ++p, n += 32) {
                uint4 u4 = *reinterpret_cast<const uint4*>(&Wc[(size_t)(n0 + n)*256 + k0 + k8*8]);
                int byte = n*128 + ((k8 ^ (n & 7)) << 4);
                *reinterpret_cast<uint4*>(reinterpret_cast<char*>(Bsm) + byte) = u4;
            }
        }
        // issue kt+1 A-loads (in flight across barrier + MFMA)
        if (kt < 3) {
            #pragma unroll
            for (int p = 0; p < 8; ++p)
                pa[p] = *reinterpret_cast<const float4*>(&x[(arow + p*16)*256 + (kt+1)*64 + ak4*4]);
        }
        __syncthreads();
        #pragma unroll
        for (int ks = 0; ks < 2; ++ks) {
            bf16x8 af[4], bfv[4];
            #pragma unroll
            for (int mi = 0; mi < 4; ++mi) {
                int m = wm*64 + mi*16 + lrow;
                int u = (ks*4 + lk) ^ (m & 7);
                af[mi] = *reinterpret_cast<const bf16x8*>(reinterpret_cast<const char*>(Asm) + m*128 + u*16);
            }
            #pragma unroll
            for (int ni = 0; ni < 4; ++ni) {
                int n = wn*64 + ni*16 + lrow;
                int u = (ks*4 + lk) ^ (n & 7);
                bfv[ni] = *reinterpret_cast<const bf16x8*>(reinterpret_cast<const char*>(Bsm) + n*128 + u*16);
            }
            #pragma unroll
            for (int mi = 0; mi < 4; ++mi)
                #pragma unroll
                for (int ni = 0; ni < 4; ++ni)
                    acc[mi][ni] = __builtin_amdgcn_mfma_f32_16x16x32_bf16(af[mi], bfv[ni], acc[mi][ni], 0, 0, 0);
        }
    }
    #pragma unroll
    for (int mi = 0; mi < 4; ++mi) {
        #pragma unroll
        for (int ni = 0; ni < 4; ++ni) {
            int gcol = n0 + wn*64 + ni*16 + lrow;
            int c = gcol & 127;
            float bias = bcat[gcol];
            #pragma unroll
            for (int r = 0; r < 4; ++r) {
                size_t grow = (size_t)m0 + wm*64 + mi*16 + lk*4 + r;
                float val = acc[mi][ni][r] + bias;
                if (ntile == 0)      { q[grow*128 + c] = val; qb[grow*128 + c] = f2bf(val); }
                else if (ntile == 1) { k[grow*128 + c] = val; kb[grow*128 + c] = f2bf(val); }
                else                 vb[grow*128 + c] = f2bf(val);
            }
        }
    }
}

// ---------------------------------------------------------------- depthwise 3x3 LEPE conv, 8 ch/lane
__global__ __launch_bounds__(256) void k_conv(const unsigned short* __restrict__ vb, const float* __restrict__ w,
                                              const float* __restrict__ bias, float* __restrict__ xsp)
{
    __shared__ float wsmT[9][128];
    __shared__ float bsm[128];
    int t = threadIdx.x;
    for (int i = t; i < 1152; i += 256) wsmT[i % 9][i / 9] = w[i];
    if (t < 128) bsm[t] = bias[t];
    __syncthreads();
    int jj = t >> 4, c8 = (t & 15) * 8;
    int j = blockIdx.x * 16 + jj;
    int i = blockIdx.y, b = blockIdx.z;
    float acc[8];
    #pragma unroll
    for (int l = 0; l < 8; ++l) acc[l] = bsm[c8 + l];
    #pragma unroll
    for (int di = 0; di < 3; ++di) {
        int ii = i + di - 1;
        if (ii < 0 || ii >= 128) continue;
        #pragma unroll
        for (int dj = 0; dj < 3; ++dj) {
            int jx = j + dj - 1;
            if (jx < 0 || jx >= 128) continue;
            uint4 u = *reinterpret_cast<const uint4*>(&vb[((size_t)b*NN + ii*128 + jx)*128 + c8]);
            const unsigned short* us = (const unsigned short*)&u;
            int kk = di*3 + dj;
            #pragma unroll
            for (int l = 0; l < 8; ++l)
                acc[l] += wsmT[kk][c8 + l] * bf2f(us[l]);
        }
    }
    float4 r0 = {acc[0],acc[1],acc[2],acc[3]}, r1 = {acc[4],acc[5],acc[6],acc[7]};
    size_t ob = ((size_t)b*NN + i*128 + j)*128 + c8;
    *reinterpret_cast<float4*>(&xsp[ob]) = r0;
    *reinterpret_cast<float4*>(&xsp[ob+4]) = r1;
}

// ---------------------------------------------------------------- fused k-features (MFMA) + kv partials (MFMA), bf16 k input
__global__ __launch_bounds__(256) void k_featkv(
    const unsigned short* __restrict__ kb, const unsigned short* __restrict__ vb,
    const float* __restrict__ W, const float* __restrict__ bvec,
    const unsigned int* __restrict__ fsc,
    float* __restrict__ kvpart, float* __restrict__ kmpart)
{
    __shared__ __align__(16) unsigned short kfsT[4][64][72];  // [wave][f][pos]
    __shared__ __align__(16) unsigned short vT[4][32][72];    // [wave][d][pos]
    __shared__ float kms[4][64];
    int bh = blockIdx.y, b = bh >> 2, h = bh & 3;
    int chunk = blockIdx.x;
    int t = threadIdx.x, w = t >> 6, lane = t & 63;
    int c = lane & 15, g = lane >> 4;
    bf16x8 wb[2];
    #pragma unroll
    for (int et = 0; et < 2; ++et) {
        float4 wa = *reinterpret_cast<const float4*>(&W[(c + et*16)*32 + g*8]);
        float4 wb2 = *reinterpret_cast<const float4*>(&W[(c + et*16)*32 + g*8 + 4]);
        wb[et] = cvt8(wa, wb2);
    }
    float bias0 = bvec[c], bias1 = bvec[c + 16];
    f32x4 acc[4][2];
    #pragma unroll
    for (int i = 0; i < 4; ++i) { acc[i][0] = (f32x4){0.f,0.f,0.f,0.f}; acc[i][1] = (f32x4){0.f,0.f,0.f,0.f}; }
    f32x4 km0 = {0.f,0.f,0.f,0.f}, km1 = km0, km2 = km0, km3 = km0;

    for (int rnd = 0; rnd < 2; ++rnd) {
        int p0 = chunk*512 + w*128 + rnd*64;
        // stage vT (coalesced global, b64 transposed writes)
        {
            uint4 vr[4];
            size_t vbase = ((size_t)(b*NN + p0 + c*4))*128 + h*32 + g*8;
            #pragma unroll
            for (int i = 0; i < 4; ++i) vr[i] = *reinterpret_cast<const uint4*>(&vb[vbase + (size_t)i*128]);
            #pragma unroll
            for (int j = 0; j < 8; ++j) {
                ushort4 pk;
                pk.x = ((const unsigned short*)&vr[0])[j];
                pk.y = ((const unsigned short*)&vr[1])[j];
                pk.z = ((const unsigned short*)&vr[2])[j];
                pk.w = ((const unsigned short*)&vr[3])[j];
                *reinterpret_cast<ushort4*>(&vT[w][g*8 + j][c*4]) = pk;
            }
        }
        // phase 1: y = k @ W^T via MFMA, softmax in C-regs, fope
        #pragma unroll
        for (int mt = 0; mt < 4; ++mt) {
            int posA = p0 + mt*16 + c;
            bf16x8 af = *reinterpret_cast<const bf16x8*>(&kb[((size_t)(b*NN + posA))*128 + h*32 + g*8]);
            f32x4 z4 = {0.f,0.f,0.f,0.f};
            f32x4 y0 = __builtin_amdgcn_mfma_f32_16x16x32_bf16(af, wb[0], z4, 0, 0, 0);
            f32x4 y1 = __builtin_amdgcn_mfma_f32_16x16x32_bf16(af, wb[1], z4, 0, 0, 0);
            f32x4 el0, eh0, el1, eh1;
            #pragma unroll
            for (int r = 0; r < 4; ++r) {
                float a0 = 2.f*(y0[r] + bias0);
                float a1 = 2.f*(y1[r] + bias1);
                el0[r] = __expf(a0); eh0[r] = __expf(-a0);
                el1[r] = __expf(a1); eh1[r] = __expf(-a1);
            }
            f32x4 s = el0 + eh0 + el1 + eh1;
            red16(s);
            f32x4 rs;
            #pragma unroll
            for (int r = 0; r < 4; ++r) rs[r] = rcpf(s[r]);
            f32x4 klo0 = el0*rs, khi0 = eh0*rs, klo1 = el1*rs, khi1 = eh1*rs;
            km0 += klo0; km1 += khi0; km2 += klo1; km3 += khi1;
            int posC = p0 + mt*16 + g*4;
            ushort4 wlo0, whi0, wlo1, whi1;
            #pragma unroll
            for (int r = 0; r < 4; ++r) {
                unsigned int u = fsc[((size_t)h*NN + posC + r)*16 + c];
                float fsv = bf2f((unsigned short)(u & 0xffffu));
                float fcv = bf2f((unsigned short)(u >> 16));
                ((unsigned short*)&wlo0)[r] = f2bf(klo0[r]*fcv + khi0[r]*fsv);
                ((unsigned short*)&whi0)[r] = f2bf(khi0[r]*fcv - klo0[r]*fsv);
                ((unsigned short*)&wlo1)[r] = f2bf(klo1[r] + khi1[r]);
                ((unsigned short*)&whi1)[r] = f2bf(khi1[r] - klo1[r]);
            }
            int po = mt*16 + g*4;
            *reinterpret_cast<ushort4*>(&kfsT[w][c][po])      = wlo0;
            *reinterpret_cast<ushort4*>(&kfsT[w][32 + c][po]) = whi0;
            *reinterpret_cast<ushort4*>(&kfsT[w][16 + c][po]) = wlo1;
            *reinterpret_cast<ushort4*>(&kfsT[w][48 + c][po]) = whi1;
        }
        // phase 2: kv[f][d] += kfope^T x v
        #pragma unroll
        for (int ks = 0; ks < 2; ++ks) {
            bf16x8 bf0 = *reinterpret_cast<const bf16x8*>(&vT[w][c][ks*32 + g*8]);
            bf16x8 bf1 = *reinterpret_cast<const bf16x8*>(&vT[w][16 + c][ks*32 + g*8]);
            #pragma unroll
            for (int mt = 0; mt < 4; ++mt) {
                bf16x8 af2 = *reinterpret_cast<const bf16x8*>(&kfsT[w][mt*16 + c][ks*32 + g*8]);
                acc[mt][0] = __builtin_amdgcn_mfma_f32_16x16x32_bf16(af2, bf0, acc[mt][0], 0, 0, 0);
                acc[mt][1] = __builtin_amdgcn_mfma_f32_16x16x32_bf16(af2, bf1, acc[mt][1], 0, 0, 0);
            }
        }
    }
    float kv0 = km0[0]+km0[1]+km0[2]+km0[3];
    float kv1 = km1[0]+km1[1]+km1[2]+km1[3];
    float kv2 = km2[0]+km2[1]+km2[2]+km2[3];
    float kv3 = km3[0]+km3[1]+km3[2]+km3[3];
    kv0 += __shfl_xor(kv0, 16); kv0 += __shfl_xor(kv0, 32);
    kv1 += __shfl_xor(kv1, 16); kv1 += __shfl_xor(kv1, 32);
    kv2 += __shfl_xor(kv2, 16); kv2 += __shfl_xor(kv2, 32);
    kv3 += __shfl_xor(kv3, 16); kv3 += __shfl_xor(kv3, 32);
    if (g == 0) {
        kms[w][c] = kv0; kms[w][16 + c] = kv2; kms[w][32 + c] = kv1; kms[w][48 + c] = kv3;
    }
    float* kvred = reinterpret_cast<float*>(&kfsT[0][0][0]);   // [(w*32+d)*72 + f]
    #pragma unroll
    for (int mt = 0; mt < 4; ++mt)
        #pragma unroll
        for (int nt = 0; nt < 2; ++nt) {
            int d = nt*16 + c;
            *reinterpret_cast<f32x4*>(&kvred[(size_t)(w*32 + d)*72 + mt*16 + g*4]) = acc[mt][nt];
        }
    __syncthreads();
    #pragma unroll
    for (int i = 0; i < 8; ++i) {
        int idx = t*8 + i;   // f*32 + d
        int f = idx >> 5, d = idx & 31;
        float s2 = kvred[(0*32 + d)*72 + f] + kvred[(1*32 + d)*72 + f]
                 + kvred[(2*32 + d)*72 + f] + kvred[(3*32 + d)*72 + f];
        kvpart[((size_t)(bh*32 + chunk))*2048 + idx] = s2;
    }
    if (t < 64) {
        float s2 = kms[0][t] + kms[1][t] + kms[2][t] + kms[3][t];
        kmpart[(size_t)(bh*32 + chunk)*64 + t] = s2;
    }
}

// ---------------------------------------------------------------- reduce kv partials -> kvT bf16 [bh][d][f] (x 1/N)
__global__ __launch_bounds__(256) void k_kvred2(const float* __restrict__ kvpart, unsigned short* __restrict__ kvT)
{
    int bh = blockIdx.x >> 3, part = blockIdx.x & 7;
    int idx = part*256 + threadIdx.x;   // f*32 + d
    float s = 0.f;
    for (int cidx = 0; cidx < 32; ++cidx) s += kvpart[((size_t)(bh*32 + cidx))*2048 + idx];
    int f = idx >> 5, d = idx & 31;
    kvT[(size_t)bh*2048 + d*64 + f] = f2bf(s * (1.f/16384.f));
}

__global__ __launch_bounds__(64) void k_kmred(const float* __restrict__ kmpart, float* __restrict__ kmean)
{
    int bh = blockIdx.x, t = threadIdx.x;
    float s = 0.f;
    for (int cidx = 0; cidx < 32; ++cidx) s += kmpart[(size_t)(bh*32 + cidx)*64 + t];
    kmean[bh*64 + t] = s * (1.f/16384.f);
}

// ---------------------------------------------------------------- fused q-features (MFMA) + xs (MFMA) -> xsb bf16, bf16 q input
__global__ __launch_bounds__(256) void k_featxs(
    const unsigned short* __restrict__ qb, const float* __restrict__ W, const float* __restrict__ bvec,
    const unsigned int* __restrict__ fsc, const unsigned short* __restrict__ kvT,
    const float* __restrict__ kmean, const float* __restrict__ xsp, unsigned short* __restrict__ xsb)
{
    __shared__ __align__(16) unsigned short qfs[4][64][72];   // [wave][pos][f]
    int bh = blockIdx.y, b = bh >> 2, h = bh & 3;
    int chunk = blockIdx.x;
    int t = threadIdx.x, w = t >> 6, lane = t & 63;
    int c = lane & 15, g = lane >> 4;
    bf16x8 wb[2];
    #pragma unroll
    for (int et = 0; et < 2; ++et) {
        float4 wa = *reinterpret_cast<const float4*>(&W[(c + et*16)*32 + g*8]);
        float4 wb2 = *reinterpret_cast<const float4*>(&W[(c + et*16)*32 + g*8 + 4]);
        wb[et] = cvt8(wa, wb2);
    }
    float bias0 = bvec[c], bias1 = bvec[c + 16];
    float kml0 = kmean[bh*64 + c],      kml1 = kmean[bh*64 + 16 + c];
    float kmh0 = kmean[bh*64 + 32 + c], kmh1 = kmean[bh*64 + 48 + c];
    bf16x8 bkv[2][2];
    #pragma unroll
    for (int nt = 0; nt < 2; ++nt)
        #pragma unroll
        for (int ks = 0; ks < 2; ++ks)
            bkv[nt][ks] = *reinterpret_cast<const bf16x8*>(&kvT[(size_t)bh*2048 + (nt*16 + c)*64 + ks*32 + g*8]);

    for (int rnd = 0; rnd < 2; ++rnd) {
        int p0 = chunk*512 + w*128 + rnd*64;
        #pragma unroll
        for (int mt = 0; mt < 4; ++mt) {
            int posA = p0 + mt*16 + c;
            bf16x8 af = *reinterpret_cast<const bf16x8*>(&qb[((size_t)(b*NN + posA))*128 + h*32 + g*8]);
            f32x4 z4 = {0.f,0.f,0.f,0.f};
            f32x4 y0 = __builtin_amdgcn_mfma_f32_16x16x32_bf16(af, wb[0], z4, 0, 0, 0);
            f32x4 y1 = __builtin_amdgcn_mfma_f32_16x16x32_bf16(af, wb[1], z4, 0, 0, 0);
            f32x4 el0, eh0, el1, eh1;
            #pragma unroll
            for (int r = 0; r < 4; ++r) {
                float a0 = 2.f*(y0[r] + bias0);
                float a1 = 2.f*(y1[r] + bias1);
                el0[r] = __expf(a0); eh0[r] = __expf(-a0);
                el1[r] = __expf(a1); eh1[r] = __expf(-a1);
            }
            f32x4 s = el0 + eh0 + el1 + eh1;
            f32x4 wv = el0*kml0 + eh0*kmh0 + el1*kml1 + eh1*kmh1;
            red16x2(s, wv);
            f32x4 zr;
            #pragma unroll
            for (int r = 0; r < 4; ++r) {
                float rs = rcpf(s[r]);
                float z = rcpf(wv[r]*rs + 1e-6f);
                zr[r] = z*rs;
            }
            int posC = mt*16 + g*4;
            #pragma unroll
            for (int r = 0; r < 4; ++r) {
                unsigned int u = fsc[((size_t)h*NN + p0 + posC + r)*16 + c];
                float fsv = bf2f((unsigned short)(u & 0xffffu));
                float fcv = bf2f((unsigned short)(u >> 16));
                qfs[w][posC + r][c]      = f2bf(zr[r]*(el0[r]*fcv + eh0[r]*fsv));
                qfs[w][posC + r][32 + c] = f2bf(zr[r]*(eh0[r]*fcv - el0[r]*fsv));
                qfs[w][posC + r][16 + c] = f2bf(zr[r]*(el1[r] + eh1[r]));
                qfs[w][posC + r][48 + c] = f2bf(zr[r]*(eh1[r] - el1[r]));
            }
        }
        f32x4 acc[4][2];
        #pragma unroll
        for (int i = 0; i < 4; ++i) { acc[i][0] = (f32x4){0.f,0.f,0.f,0.f}; acc[i][1] = (f32x4){0.f,0.f,0.f,0.f}; }
        #pragma unroll
        for (int ks = 0; ks < 2; ++ks)
            #pragma unroll
            for (int mt = 0; mt < 4; ++mt) {
                bf16x8 af2 = *reinterpret_cast<const bf16x8*>(&qfs[w][mt*16 + c][ks*32 + g*8]);
                acc[mt][0] = __builtin_amdgcn_mfma_f32_16x16x32_bf16(af2, bkv[0][ks], acc[mt][0], 0, 0, 0);
                acc[mt][1] = __builtin_amdgcn_mfma_f32_16x16x32_bf16(af2, bkv[1][ks], acc[mt][1], 0, 0, 0);
            }
        #pragma unroll
        for (int mt = 0; mt < 4; ++mt)
            #pragma unroll
            for (int nt = 0; nt < 2; ++nt) {
                int d = nt*16 + c;
                #pragma unroll
                for (int r = 0; r < 4; ++r) {
                    int pos = p0 + mt*16 + g*4 + r;
                    size_t off = ((size_t)(b*NN + pos))*128 + h*32 + d;
                    xsb[off] = f2bf(xsp[off] + acc[mt][nt][r]);
                }
            }
    }
}

// ---------------------------------------------------------------- gram via MFMA + fused norms (bf16 inputs, 64 K-chunks)
__global__ __launch_bounds__(256) void k_gram(const unsigned short* __restrict__ qb, const unsigned short* __restrict__ kb,
                                              float* __restrict__ Gpart,
                                              float* __restrict__ qn2, float* __restrict__ kn2)
{
    __shared__ unsigned short qTs[128][40];
    __shared__ unsigned short kTs[128][40];
    int kc = blockIdx.x, bb = blockIdx.y;
    int t = threadIdx.x, lane = t & 63;
    int wave = t >> 6, wm = wave >> 1, wn = wave & 1;
    int c = t & 127, lh = t >> 7;
    float qa = 0.f, ka = 0.f;
    f32x4 acc[4][4];
    #pragma unroll
    for (int i = 0; i < 4; ++i)
        #pragma unroll
        for (int j = 0; j < 4; ++j) acc[i][j] = (f32x4){0.f,0.f,0.f,0.f};

    for (int kt = 0; kt < 8; ++kt) {
        __syncthreads();
        #pragma unroll
        for (int i = 0; i < 16; ++i) {
            int l = lh*16 + i;
            size_t pos = (size_t)bb*NN + kc*256 + kt*32 + l;
            unsigned short qu = qb[pos*128 + c];
            unsigned short ku = kb[pos*128 + c];
            float qv = bf2f(qu), kvv = bf2f(ku);
            qa += qv*qv; ka += kvv*kvv;
            qTs[c][l] = qu;
            kTs[c][l] = ku;
        }
        __syncthreads();
        bf16x8 af[4];
        #pragma unroll
        for (int mi = 0; mi < 4; ++mi)
            af[mi] = *reinterpret_cast<const bf16x8*>(&qTs[wm*64 + mi*16 + (lane & 15)][(lane >> 4)*8]);
        #pragma unroll
        for (int ni = 0; ni < 4; ++ni) {
            bf16x8 bfr = *reinterpret_cast<const bf16x8*>(&kTs[wn*64 + ni*16 + (lane & 15)][(lane >> 4)*8]);
            #pragma unroll
            for (int mi = 0; mi < 4; ++mi)
                acc[mi][ni] = __builtin_amdgcn_mfma_f32_16x16x32_bf16(af[mi], bfr, acc[mi][ni], 0, 0, 0);
        }
    }
    size_t gb = ((size_t)(bb*64 + kc))*16384;
    #pragma unroll
    for (int mi = 0; mi < 4; ++mi) {
        #pragma unroll
        for (int ni = 0; ni < 4; ++ni) {
            int d = wn*64 + ni*16 + (lane & 15);
            #pragma unroll
            for (int r = 0; r < 4; ++r) {
                int cc = wm*64 + mi*16 + (lane >> 4)*4 + r;
                Gpart[gb + (size_t)cc*128 + d] = acc[mi][ni][r];
            }
        }
    }
    atomicAdd(&qn2[bb*128 + c], qa);
    atomicAdd(&kn2[bb*128 + c], ka);
}

// ---------------------------------------------------------------- reduce Gpart -> G
__global__ __launch_bounds__(256) void k_gramred(const float* __restrict__ Gpart, float* __restrict__ G)
{
    int bb = blockIdx.y;
    int idx = blockIdx.x*256 + threadIdx.x;
    float s = 0.f;
    for (int kc = 0; kc < 64; ++kc) s += Gpart[((size_t)(bb*64 + kc))*16384 + idx];
    G[(size_t)bb*16384 + idx] = s;
}

// ---------------------------------------------------------------- channel attention softmax
__global__ __launch_bounds__(128) void k_attnsm(const float* __restrict__ G, const float* __restrict__ qn2,
    const float* __restrict__ kn2, const float* __restrict__ temp, float* __restrict__ attn)
{
    __shared__ float red[128];
    int row = blockIdx.x;
    int b = row >> 7, c = row & 127;
    int t = threadIdx.x;
    float qn = fmaxf(sqrtf(qn2[b*128 + c]), 1e-12f);
    float kn = fmaxf(sqrtf(kn2[b*128 + t]), 1e-12f);
    float val = G[(size_t)row*128 + t] / (qn*kn) * temp[c];
    red[t] = val; __syncthreads();
    for (int s = 64; s > 0; s >>= 1) { if (t < s) red[t] = fmaxf(red[t], red[t+s]); __syncthreads(); }
    float mm = red[0]; __syncthreads();
    float ev = expf(val - mm);
    red[t] = ev; __syncthreads();
    for (int s = 64; s > 0; s >>= 1) { if (t < s) red[t] += red[t+s]; __syncthreads(); }
    attn[(size_t)row*128 + t] = ev / red[0];
}

// ---------------------------------------------------------------- per-batch B matrix, transposed bf16
__global__ __launch_bounds__(256) void k_bmat(const float* __restrict__ attn, const float* __restrict__ Wp,
                                              unsigned short* __restrict__ BmatT)
{
    int b = blockIdx.y, kk = blockIdx.x, o = threadIdx.x;
    float val;
    if (kk < 128) {
        val = Wp[(size_t)o*256 + kk];
    } else {
        int d = kk - 128;
        __shared__ float a[128];
        if (o < 128) a[o] = attn[((size_t)b*128 + o)*128 + d];
        __syncthreads();
        float acc = 0.f;
        for (int c = 0; c < 128; ++c) acc += a[c] * Wp[(size_t)o*256 + 128 + c];
        val = acc;
    }
    BmatT[((size_t)b*256 + o)*256 + kk] = f2bf(val);
}

// ---------------------------------------------------------------- final MFMA GEMM with T14 prefetch: out = [xsb | vb] @ BmatT_b^T + bp
__global__ __launch_bounds__(256) void k_out_mfma(const unsigned short* __restrict__ xsb,
    const unsigned short* __restrict__ vb, const unsigned short* __restrict__ BmatT,
    const float* __restrict__ bp, float* __restrict__ out)
{
    __shared__ unsigned short Asm[128*64];
    __shared__ unsigned short Bsm[128*64];
    int t = threadIdx.x;
    int lin = blockIdx.y*2 + blockIdx.x;
    int logical = (lin & 7)*256 + (lin >> 3);
    int ntile = logical & 1;
    int mtile = logical >> 1;
    int m0 = mtile * 128;
    int n0 = ntile * 128;
    int b = mtile >> 7;
    int wave = t >> 6, lane = t & 63;
    int wm = wave >> 1, wn = wave & 1;
    int lrow = lane & 15, lk = lane >> 4;
    f32x4 acc[4][4];
    #pragma unroll
    for (int i = 0; i < 4; ++i)
        #pragma unroll
        for (int j = 0; j < 4; ++j) acc[i][j] = (f32x4){0.f,0.f,0.f,0.f};

    int am = t >> 3, ak8 = t & 7;
    uint4 pa4[4];
    // prologue: kt=0 A-loads (xsb, ka0=0)
    #pragma unroll
    for (int p = 0; p < 4; ++p)
        pa4[p] = *reinterpret_cast<const uint4*>(&xsb[(size_t)(m0 + am + p*32)*128 + ak8*8]);

    #pragma unroll
    for (int kt = 0; kt < 4; ++kt) {
        if (kt) __syncthreads();
        // ds_write A from prefetched regs
        #pragma unroll
        for (int p = 0; p < 4; ++p) {
            int m = am + p*32;
            int byte = m*128 + ((ak8 ^ (m & 7)) << 4);
            *reinterpret_cast<uint4*>(reinterpret_cast<char*>(Asm) + byte) = pa4[p];
        }
        // B stage (synchronous; BmatT L2-hot)
        {
            int n = t >> 3, k8 = t & 7;
            #pragma unroll
            for (int p = 0; p < 4; ++p, n += 32) {
                uint4 u4 = *reinterpret_cast<const uint4*>(&BmatT[((size_t)b*256 + n0 + n)*256 + kt*64 + k8*8]);
                int byte = n*128 + ((k8 ^ (n & 7)) << 4);
                *reinterpret_cast<uint4*>(reinterpret_cast<char*>(Bsm) + byte) = u4;
            }
        }
        // issue kt+1 A-loads
        if (kt < 3) {
            const unsigned short* Asrc = ((kt+1) < 2) ? xsb : vb;
            int ka0 = ((kt+1) & 1) * 64;
            #pragma unroll
            for (int p = 0; p < 4; ++p)
                pa4[p] = *reinterpret_cast<const uint4*>(&Asrc[(size_t)(m0 + am + p*32)*128 + ka0 + ak8*8]);
        }
        __syncthreads();
        #pragma unroll
        for (int ks = 0; ks < 2; ++ks) {
            bf16x8 af[4], bfv[4];
            #pragma unroll
            for (int mi = 0; mi < 4; ++mi) {
                int m = wm*64 + mi*16 + lrow;
                int u = (ks*4 + lk) ^ (m & 7);
                af[mi] = *reinterpret_cast<const bf16x8*>(reinterpret_cast<const char*>(Asm) + m*128 + u*16);
            }
            #pragma unroll
            for (int ni = 0; ni < 4; ++ni) {
                int n = wn*64 + ni*16 + lrow;
                int u = (ks*4 + lk) ^ (n & 7);
                bfv[ni] = *reinterpret_cast<const bf16x8*>(reinterpret_cast<const char*>(Bsm) + n*128 + u*16);
            }
            #pragma unroll
            for (int mi = 0; mi < 4; ++mi)
                #pragma unroll
                for (int ni = 0; ni < 4; ++ni)
                    acc[mi][ni] = __builtin_amdgcn_mfma_f32_16x16x32_bf16(af[mi], bfv[ni], acc[mi][ni], 0, 0, 0);
        }
    }
    #pragma unroll
    for (int mi = 0; mi < 4; ++mi) {
        #pragma unroll
        for (int ni = 0; ni < 4; ++ni) {
            int gcol = n0 + wn*64 + ni*16 + lrow;
            float bias = bp[gcol];
            #pragma unroll
            for (int r = 0; r < 4; ++r) {
                size_t grow = (size_t)m0 + wm*64 + mi*16 + lk*4 + r;
                out[grow*256 + gcol] = acc[mi][ni][r] + bias;
            }
        }
    }
}

extern "C" void kernel_launch(void* const* d_in, const int* in_sizes, int n_in,
                              void* d_out, int out_size, void* d_ws, size_t ws_size,
                              hipStream_t stream)
{
    (void)in_sizes; (void)n_in; (void)out_size; (void)ws_size;
    const float* x    = (const float*)d_in[0];
    const float* Wq   = (const float*)d_in[1];
    const float* bq   = (const float*)d_in[2];
    const float* Wk   = (const float*)d_in[3];
    const float* bk   = (const float*)d_in[4];
    const float* Wv   = (const float*)d_in[5];
    const float* bv   = (const float*)d_in[6];
    const float* Whq  = (const float*)d_in[7];
    const float* bhq  = (const float*)d_in[8];
    const float* Whk  = (const float*)d_in[9];
    const float* bhk  = (const float*)d_in[10];
    const float* sinc = (const float*)d_in[11];
    const float* cosc = (const float*)d_in[12];
    const float* lw   = (const float*)d_in[13];
    const float* lb   = (const float*)d_in[14];
    const float* temp = (const float*)d_in[15];
    const float* Wp   = (const float*)d_in[16];
    const float* bp   = (const float*)d_in[17];

    float* out = (float*)d_out;
    float* q   = out + 33554432;
    float* k   = out + 50331648;
    float* ws  = (float*)d_ws;

    float* xsp    = ws + WS_XSP;
    float* Gpart  = ws + WS_XSP;     // reused after featxs consumed xsp
    unsigned short* vbuf = (unsigned short*)(ws + WS_VB);
    unsigned short* xsb  = (unsigned short*)(ws + WS_XSB);
    unsigned int* fsc = (unsigned int*)(ws + WS_FS);
    float* inv    = ws + WS_INV;
    float* cs     = ws + WS_CS;
    float* cc     = ws + WS_CC;
    unsigned short* Wc = (unsigned short*)(ws + WS_WCAT);
    float* bcat   = ws + WS_BCAT;
    float* kvpart = ws + WS_KVPART;
    float* kmpart = ws + WS_KMPART;
    unsigned short* kvT = (unsigned short*)(ws + WS_KV);
    float* kmean  = ws + WS_KMEAN;
    float* qn2    = ws + WS_QN2;
    float* kn2    = ws + WS_KN2;
    float* G      = ws + WS_G;
    float* attn   = ws + WS_ATTN;
    unsigned short* BmatT = (unsigned short*)(ws + WS_BMATT);
    unsigned short* qbuf  = (unsigned short*)(ws + WS_QB);
    unsigned short* kbuf  = (unsigned short*)(ws + WS_KB);

    hipMemsetAsync(qn2, 0, 2048*sizeof(float), stream);

    k_setup<<<1, 64, 0, stream>>>(sinc, cosc, inv, cs, cc);
    k_tables<<<4096, 256, 0, stream>>>(inv, cs, cc, fsc);
    k_wprep<<<384, 256, 0, stream>>>(Wq, Wk, Wv, bq, bk, bv, Wc, bcat);
    k_qkv_mfma<<<dim3(3, 1024), 256, 0, stream>>>(x, Wc, bcat, q, k, qbuf, kbuf, vbuf);
    k_conv<<<dim3(8, 128, 8), 256, 0, stream>>>(vbuf, lw, lb, xsp);
    k_featkv<<<dim3(32, 32), 256, 0, stream>>>(kbuf, vbuf, Whk, bhk, fsc, kvpart, kmpart);
    k_kvred2<<<256, 256, 0, stream>>>(kvpart, kvT);
    k_kmred<<<32, 64, 0, stream>>>(kmpart, kmean);
    k_featxs<<<dim3(32, 32), 256, 0, stream>>>(qbuf, Whq, bhq, fsc, kvT, kmean, xsp, xsb);
    k_gram<<<dim3(64, 8), 256, 0, stream>>>(qbuf, kbuf, Gpart, qn2, kn2);
    k_gramred<<<dim3(64, 8), 256, 0, stream>>>(Gpart, G);
    k_attnsm<<<1024, 128, 0, stream>>>(G, qn2, kn2, temp, attn);
    k_bmat<<<dim3(256, 8), 256, 0, stream>>>(attn, Wp, BmatT);
    k_out_mfma<<<dim3(2, 1024), 256, 0, stream>>>(xsb, vbuf, BmatT, bp, out);
}

// Round 7
// 383.836 us; speedup vs baseline: 6.1001x; 1.1468x over previous
//
#include <hip/hip_runtime.h>
#include <cmath>

#define NB 8
#define NN 16384
#define DIN 23
#define DOUT 16

typedef short bf16x8 __attribute__((ext_vector_type(8)));
typedef float f32x4 __attribute__((ext_vector_type(4)));

__device__ __forceinline__ unsigned short f2bf(float f) {
    unsigned int u = __float_as_uint(f);
    u += 0x7FFFu + ((u >> 16) & 1u);
    return (unsigned short)(u >> 16);
}
__device__ __forceinline__ float bf2f(unsigned short s) {
    return __uint_as_float(((unsigned int)s) << 16);
}
__device__ __forceinline__ float rcpf(float x) { return __builtin_amdgcn_rcpf(x); }

__device__ __forceinline__ bf16x8 cvt8(float4 a, float4 b) {
    bf16x8 r;
    r[0]=(short)f2bf(a.x); r[1]=(short)f2bf(a.y); r[2]=(short)f2bf(a.z); r[3]=(short)f2bf(a.w);
    r[4]=(short)f2bf(b.x); r[5]=(short)f2bf(b.y); r[6]=(short)f2bf(b.z); r[7]=(short)f2bf(b.w);
    return r;
}
__device__ __forceinline__ void red16(f32x4& s) {
    #pragma unroll
    for (int off = 1; off < 16; off <<= 1) {
        s[0] += __shfl_xor(s[0], off); s[1] += __shfl_xor(s[1], off);
        s[2] += __shfl_xor(s[2], off); s[3] += __shfl_xor(s[3], off);
    }
}
__device__ __forceinline__ void red16x2(f32x4& s, f32x4& w) {
    #pragma unroll
    for (int off = 1; off < 16; off <<= 1) {
        s[0] += __shfl_xor(s[0], off); s[1] += __shfl_xor(s[1], off);
        s[2] += __shfl_xor(s[2], off); s[3] += __shfl_xor(s[3], off);
        w[0] += __shfl_xor(w[0], off); w[1] += __shfl_xor(w[1], off);
        w[2] += __shfl_xor(w[2], off); w[3] += __shfl_xor(w[3], off);
    }
}

// workspace offsets in floats
#define WS_XSPB   ((size_t)0)          // xspb bf16: 16,777,216 ushorts = 8,388,608 slots
#define WS_GPART  ((size_t)8388608)    // Gpart f32: 8,388,608 floats (8 b x 64 kc x 16384)
#define WS_VB     ((size_t)16777216)   // v bf16
#define WS_XSB    ((size_t)25165824)   // xs bf16
#define WS_FS     ((size_t)33554432)   // fsc packed u32 [4][NN][16]
#define WS_INV    ((size_t)35651584)
#define WS_CS     ((size_t)35651648)
#define WS_CC     ((size_t)35653184)
#define WS_WCAT   ((size_t)35654720)
#define WS_BCAT   ((size_t)35703872)
#define WS_KVPART ((size_t)35704256)   // 32bh x 32chunk x 2048
#define WS_KMPART ((size_t)37801408)
#define WS_KV     ((size_t)37866944)   // kvT bf16 [32][32][64]
#define WS_KMEAN  ((size_t)37932480)
#define WS_QN2    ((size_t)37934528)
#define WS_KN2    ((size_t)37935552)
#define WS_ATTN   ((size_t)38067648)
#define WS_BMATT  ((size_t)38198720)
#define WS_QB     ((size_t)38460864)   // q bf16
#define WS_KB     ((size_t)46849472)   // k bf16

// ---------------------------------------------------------------- setup
__global__ void k_setup(const float* __restrict__ sc, const float* __restrict__ ccin,
                        float* __restrict__ inv, float* __restrict__ cs, float* __restrict__ cc)
{
    int t = threadIdx.x; // 64 threads
    if (t < DIN) inv[t] = (float)pow(10000.0, -((double)(2 * t)) / 64.0);
    int h = t >> 4, d = t & 15;
    float ss = 0.f, s2 = 0.f;
    for (int D = 0; D < DIN; ++D) { ss += sc[(h*DIN + D)*DOUT + d]; s2 += ccin[(h*DIN + D)*DOUT + d]; }
    float rs = 1.f / ss, r2 = 1.f / s2;
    for (int D = 0; D < DIN; ++D) {
        cs[(h*DIN + D)*DOUT + d] = sc[(h*DIN + D)*DOUT + d] * rs;
        cc[(h*DIN + D)*DOUT + d] = ccin[(h*DIN + D)*DOUT + d] * r2;
    }
}

// ---------------------------------------------------------------- FoPE table fsc: [h][t][16] packed (fs lo16, fc hi16) bf16
__global__ __launch_bounds__(256) void k_tables(const float* __restrict__ inv, const float* __restrict__ cs,
                                                const float* __restrict__ cc,
                                                unsigned int* __restrict__ fsc)
{
    int t = threadIdx.x;
    int sub = t >> 6, lane = t & 63;
    int tpos = blockIdx.x*4 + sub;
    __shared__ float ssin[4][DIN], scos[4][DIN];
    if (lane < DIN) { float fr = (float)tpos * inv[lane]; ssin[sub][lane] = sinf(fr); scos[sub][lane] = cosf(fr); }
    __syncthreads();
    int h = lane >> 4, d = lane & 15;
    float as = 0.f, ac = 0.f;
    for (int D = 0; D < DIN; ++D) { as += ssin[sub][D]*cs[(h*DIN + D)*DOUT + d]; ac += scos[sub][D]*cc[(h*DIN + D)*DOUT + d]; }
    fsc[((size_t)h*NN + tpos)*16 + d] = ((unsigned int)f2bf(ac) << 16) | (unsigned int)f2bf(as);
}

// ---------------------------------------------------------------- weights -> bf16 concat [384][256] + bias concat
__global__ __launch_bounds__(256) void k_wprep(
    const float* __restrict__ Wq, const float* __restrict__ Wk, const float* __restrict__ Wv,
    const float* __restrict__ bq, const float* __restrict__ bk, const float* __restrict__ bv,
    unsigned short* __restrict__ Wc, float* __restrict__ bcat)
{
    int row = blockIdx.x, t = threadIdx.x;
    const float* W = (row < 128) ? Wq : (row < 256) ? Wk : Wv;
    const float* bb = (row < 128) ? bq : (row < 256) ? bk : bv;
    int r = row & 127;
    Wc[(size_t)row*256 + t] = f2bf(W[(size_t)r*256 + t]);
    if (t == 0) bcat[row] = bb[r];
}

// ---------------------------------------------------------------- QKV MFMA GEMM with T14 prefetch
__global__ __launch_bounds__(256) void k_qkv_mfma(const float* __restrict__ x,
    const unsigned short* __restrict__ Wc, const float* __restrict__ bcat,
    float* __restrict__ q, float* __restrict__ k,
    unsigned short* __restrict__ qb, unsigned short* __restrict__ kb,
    unsigned short* __restrict__ vb)
{
    __shared__ unsigned short Asm[128*64];
    __shared__ unsigned short Bsm[128*64];
    int t = threadIdx.x;
    int lin = blockIdx.y*3 + blockIdx.x;
    int logical = (lin & 7)*384 + (lin >> 3);
    int ntile = logical % 3;
    int mtile = logical / 3;
    int m0 = mtile * 128;
    int n0 = ntile * 128;
    int wave = t >> 6, lane = t & 63;
    int wm = wave >> 1, wn = wave & 1;
    int lrow = lane & 15, lk = lane >> 4;
    f32x4 acc[4][4];
    #pragma unroll
    for (int i = 0; i < 4; ++i)
        #pragma unroll
        for (int j = 0; j < 4; ++j) acc[i][j] = (f32x4){0.f,0.f,0.f,0.f};

    int am = t >> 4, ak4 = t & 15;
    size_t arow = (size_t)(m0 + am);
    float4 pa[8];
    #pragma unroll
    for (int p = 0; p < 8; ++p)
        pa[p] = *reinterpret_cast<const float4*>(&x[(arow + p*16)*256 + ak4*4]);

    #pragma unroll
    for (int kt = 0; kt < 4; ++kt) {
        int k0 = kt * 64;
        if (kt) __syncthreads();
        #pragma unroll
        for (int p = 0; p < 8; ++p) {
            int m = am + p*16;
            ushort4 b4;
            b4.x = f2bf(pa[p].x); b4.y = f2bf(pa[p].y); b4.z = f2bf(pa[p].z); b4.w = f2bf(pa[p].w);
            int byte = m*128 + ((ak4*8) ^ ((m & 7) << 4));
            *reinterpret_cast<ushort4*>(reinterpret_cast<char*>(Asm) + byte) = b4;
        }
        {
            int n = t >> 3, k8 = t & 7;
            #pragma unroll
            for (int p = 0; p < 4; ++p, n += 32) {
                uint4 u4 = *reinterpret_cast<const uint4*>(&Wc[(size_t)(n0 + n)*256 + k0 + k8*8]);
                int byte = n*128 + ((k8 ^ (n & 7)) << 4);
                *reinterpret_cast<uint4*>(reinterpret_cast<char*>(Bsm) + byte) = u4;
            }
        }
        if (kt < 3) {
            #pragma unroll
            for (int p = 0; p < 8; ++p)
                pa[p] = *reinterpret_cast<const float4*>(&x[(arow + p*16)*256 + (kt+1)*64 + ak4*4]);
        }
        __syncthreads();
        #pragma unroll
        for (int ks = 0; ks < 2; ++ks) {
            bf16x8 af[4], bfv[4];
            #pragma unroll
            for (int mi = 0; mi < 4; ++mi) {
                int m = wm*64 + mi*16 + lrow;
                int u = (ks*4 + lk) ^ (m & 7);
                af[mi] = *reinterpret_cast<const bf16x8*>(reinterpret_cast<const char*>(Asm) + m*128 + u*16);
            }
            #pragma unroll
            for (int ni = 0; ni < 4; ++ni) {
                int n = wn*64 + ni*16 + lrow;
                int u = (ks*4 + lk) ^ (n & 7);
                bfv[ni] = *reinterpret_cast<const bf16x8*>(reinterpret_cast<const char*>(Bsm) + n*128 + u*16);
            }
            #pragma unroll
            for (int mi = 0; mi < 4; ++mi)
                #pragma unroll
                for (int ni = 0; ni < 4; ++ni)
                    acc[mi][ni] = __builtin_amdgcn_mfma_f32_16x16x32_bf16(af[mi], bfv[ni], acc[mi][ni], 0, 0, 0);
        }
    }
    #pragma unroll
    for (int mi = 0; mi < 4; ++mi) {
        #pragma unroll
        for (int ni = 0; ni < 4; ++ni) {
            int gcol = n0 + wn*64 + ni*16 + lrow;
            int c = gcol & 127;
            float bias = bcat[gcol];
            #pragma unroll
            for (int r = 0; r < 4; ++r) {
                size_t grow = (size_t)m0 + wm*64 + mi*16 + lk*4 + r;
                float val = acc[mi][ni][r] + bias;
                if (ntile == 0)      { q[grow*128 + c] = val; qb[grow*128 + c] = f2bf(val); }
                else if (ntile == 1) { k[grow*128 + c] = val; kb[grow*128 + c] = f2bf(val); }
                else                 vb[grow*128 + c] = f2bf(val);
            }
        }
    }
}

// ---------------------------------------------------------------- depthwise 3x3 LEPE conv, 8 ch/lane -> xspb bf16
__global__ __launch_bounds__(256) void k_conv(const unsigned short* __restrict__ vb, const float* __restrict__ w,
                                              const float* __restrict__ bias, unsigned short* __restrict__ xspb)
{
    __shared__ float wsmT[9][128];
    __shared__ float bsm[128];
    int t = threadIdx.x;
    for (int i = t; i < 1152; i += 256) wsmT[i % 9][i / 9] = w[i];
    if (t < 128) bsm[t] = bias[t];
    __syncthreads();
    int jj = t >> 4, c8 = (t & 15) * 8;
    int j = blockIdx.x * 16 + jj;
    int i = blockIdx.y, b = blockIdx.z;
    float acc[8];
    #pragma unroll
    for (int l = 0; l < 8; ++l) acc[l] = bsm[c8 + l];
    #pragma unroll
    for (int di = 0; di < 3; ++di) {
        int ii = i + di - 1;
        if (ii < 0 || ii >= 128) continue;
        #pragma unroll
        for (int dj = 0; dj < 3; ++dj) {
            int jx = j + dj - 1;
            if (jx < 0 || jx >= 128) continue;
            uint4 u = *reinterpret_cast<const uint4*>(&vb[((size_t)b*NN + ii*128 + jx)*128 + c8]);
            const unsigned short* us = (const unsigned short*)&u;
            int kk = di*3 + dj;
            #pragma unroll
            for (int l = 0; l < 8; ++l)
                acc[l] += wsmT[kk][c8 + l] * bf2f(us[l]);
        }
    }
    ushort4 r0, r1;
    r0.x = f2bf(acc[0]); r0.y = f2bf(acc[1]); r0.z = f2bf(acc[2]); r0.w = f2bf(acc[3]);
    r1.x = f2bf(acc[4]); r1.y = f2bf(acc[5]); r1.z = f2bf(acc[6]); r1.w = f2bf(acc[7]);
    size_t ob = ((size_t)b*NN + i*128 + j)*128 + c8;
    *reinterpret_cast<ushort4*>(&xspb[ob]) = r0;
    *reinterpret_cast<ushort4*>(&xspb[ob+4]) = r1;
}

// ---------------------------------------------------------------- fused k-features (MFMA) + kv partials (MFMA)
// grid (32 chunks, 32 bh), block 256; wave owns 128 pos as 4 rounds x 32. LDS ~36KB -> 4 blocks/CU.
__global__ __launch_bounds__(256) void k_featkv(
    const unsigned short* __restrict__ kb, const unsigned short* __restrict__ vb,
    const float* __restrict__ W, const float* __restrict__ bvec,
    const unsigned int* __restrict__ fsc,
    float* __restrict__ kvpart, float* __restrict__ kmpart)
{
    // carved shared: per-wave kfsT[64][40] (5120B ea, 20480 total) + vT[32][40] (2560B ea, from 20480)
    // reduction phase reuses the whole region as float [(w*32+d)*68 + f] (34816B)
    __shared__ __align__(16) char smem[34816];
    __shared__ float kms[4][64];
    int bh = blockIdx.y, b = bh >> 2, h = bh & 3;
    int chunk = blockIdx.x;
    int t = threadIdx.x, w = t >> 6, lane = t & 63;
    int c = lane & 15, g = lane >> 4;
    unsigned short* kfsTw = reinterpret_cast<unsigned short*>(smem) + w*2560;            // [f*40 + p]
    unsigned short* vTw   = reinterpret_cast<unsigned short*>(smem + 20480) + w*1280;    // [d*40 + p]
    bf16x8 wb[2];
    #pragma unroll
    for (int et = 0; et < 2; ++et) {
        float4 wa = *reinterpret_cast<const float4*>(&W[(c + et*16)*32 + g*8]);
        float4 wb2 = *reinterpret_cast<const float4*>(&W[(c + et*16)*32 + g*8 + 4]);
        wb[et] = cvt8(wa, wb2);
    }
    float bias0 = bvec[c], bias1 = bvec[c + 16];
    f32x4 acc[4][2];
    #pragma unroll
    for (int i = 0; i < 4; ++i) { acc[i][0] = (f32x4){0.f,0.f,0.f,0.f}; acc[i][1] = (f32x4){0.f,0.f,0.f,0.f}; }
    f32x4 km0 = {0.f,0.f,0.f,0.f}, km1 = km0, km2 = km0, km3 = km0;

    for (int rnd = 0; rnd < 4; ++rnd) {
        int p0 = chunk*512 + w*128 + rnd*32;
        // stage vT: 32 pos x 32 d, coalesced reads + transposed ushort2 writes
        {
            uint4 vr0, vr1;
            size_t vbase = ((size_t)(b*NN + p0 + c*2))*128 + h*32 + g*8;
            vr0 = *reinterpret_cast<const uint4*>(&vb[vbase]);
            vr1 = *reinterpret_cast<const uint4*>(&vb[vbase + 128]);
            #pragma unroll
            for (int j = 0; j < 8; ++j) {
                ushort2 pk;
                pk.x = ((const unsigned short*)&vr0)[j];
                pk.y = ((const unsigned short*)&vr1)[j];
                *reinterpret_cast<ushort2*>(&vTw[(g*8 + j)*40 + c*2]) = pk;
            }
        }
        // phase 1: features for 32 pos (2 m-tiles)
        #pragma unroll
        for (int mt = 0; mt < 2; ++mt) {
            int posA = p0 + mt*16 + c;
            bf16x8 af = *reinterpret_cast<const bf16x8*>(&kb[((size_t)(b*NN + posA))*128 + h*32 + g*8]);
            f32x4 z4 = {0.f,0.f,0.f,0.f};
            f32x4 y0 = __builtin_amdgcn_mfma_f32_16x16x32_bf16(af, wb[0], z4, 0, 0, 0);
            f32x4 y1 = __builtin_amdgcn_mfma_f32_16x16x32_bf16(af, wb[1], z4, 0, 0, 0);
            f32x4 el0, eh0, el1, eh1;
            #pragma unroll
            for (int r = 0; r < 4; ++r) {
                float a0 = 2.f*(y0[r] + bias0);
                float a1 = 2.f*(y1[r] + bias1);
                el0[r] = __expf(a0); eh0[r] = __expf(-a0);
                el1[r] = __expf(a1); eh1[r] = __expf(-a1);
            }
            f32x4 s = el0 + eh0 + el1 + eh1;
            red16(s);
            f32x4 rs;
            #pragma unroll
            for (int r = 0; r < 4; ++r) rs[r] = rcpf(s[r]);
            f32x4 klo0 = el0*rs, khi0 = eh0*rs, klo1 = el1*rs, khi1 = eh1*rs;
            km0 += klo0; km1 += khi0; km2 += klo1; km3 += khi1;
            int posC = p0 + mt*16 + g*4;
            ushort4 wlo0, whi0, wlo1, whi1;
            #pragma unroll
            for (int r = 0; r < 4; ++r) {
                unsigned int u = fsc[((size_t)h*NN + posC + r)*16 + c];
                float fsv = bf2f((unsigned short)(u & 0xffffu));
                float fcv = bf2f((unsigned short)(u >> 16));
                ((unsigned short*)&wlo0)[r] = f2bf(klo0[r]*fcv + khi0[r]*fsv);
                ((unsigned short*)&whi0)[r] = f2bf(khi0[r]*fcv - klo0[r]*fsv);
                ((unsigned short*)&wlo1)[r] = f2bf(klo1[r] + khi1[r]);
                ((unsigned short*)&whi1)[r] = f2bf(khi1[r] - klo1[r]);
            }
            int po = mt*16 + g*4;
            *reinterpret_cast<ushort4*>(&kfsTw[(c)*40 + po])      = wlo0;
            *reinterpret_cast<ushort4*>(&kfsTw[(32 + c)*40 + po]) = whi0;
            *reinterpret_cast<ushort4*>(&kfsTw[(16 + c)*40 + po]) = wlo1;
            *reinterpret_cast<ushort4*>(&kfsTw[(48 + c)*40 + po]) = whi1;
        }
        // phase 2: kv[f][d] += kfope^T x v (K = 32 pos)
        {
            bf16x8 bf0 = *reinterpret_cast<const bf16x8*>(&vTw[(c)*40 + g*8]);
            bf16x8 bf1 = *reinterpret_cast<const bf16x8*>(&vTw[(16 + c)*40 + g*8]);
            #pragma unroll
            for (int mt = 0; mt < 4; ++mt) {
                bf16x8 af2 = *reinterpret_cast<const bf16x8*>(&kfsTw[(mt*16 + c)*40 + g*8]);
                acc[mt][0] = __builtin_amdgcn_mfma_f32_16x16x32_bf16(af2, bf0, acc[mt][0], 0, 0, 0);
                acc[mt][1] = __builtin_amdgcn_mfma_f32_16x16x32_bf16(af2, bf1, acc[mt][1], 0, 0, 0);
            }
        }
    }
    // kmean partials
    float kv0 = km0[0]+km0[1]+km0[2]+km0[3];
    float kv1 = km1[0]+km1[1]+km1[2]+km1[3];
    float kv2 = km2[0]+km2[1]+km2[2]+km2[3];
    float kv3 = km3[0]+km3[1]+km3[2]+km3[3];
    kv0 += __shfl_xor(kv0, 16); kv0 += __shfl_xor(kv0, 32);
    kv1 += __shfl_xor(kv1, 16); kv1 += __shfl_xor(kv1, 32);
    kv2 += __shfl_xor(kv2, 16); kv2 += __shfl_xor(kv2, 32);
    kv3 += __shfl_xor(kv3, 16); kv3 += __shfl_xor(kv3, 32);
    if (g == 0) {
        kms[w][c] = kv0; kms[w][16 + c] = kv2; kms[w][32 + c] = kv1; kms[w][48 + c] = kv3;
    }
    // cross-wave kv reduction: reuse smem as float [(w*32+d)*68 + f]
    __syncthreads();
    float* kvred = reinterpret_cast<float*>(smem);
    #pragma unroll
    for (int mt = 0; mt < 4; ++mt)
        #pragma unroll
        for (int nt = 0; nt < 2; ++nt) {
            int d = nt*16 + c;
            *reinterpret_cast<f32x4*>(&kvred[(size_t)(w*32 + d)*68 + mt*16 + g*4]) = acc[mt][nt];
        }
    __syncthreads();
    #pragma unroll
    for (int i = 0; i < 8; ++i) {
        int idx = t*8 + i;   // f*32 + d
        int f = idx >> 5, d = idx & 31;
        float s2 = kvred[(0*32 + d)*68 + f] + kvred[(1*32 + d)*68 + f]
                 + kvred[(2*32 + d)*68 + f] + kvred[(3*32 + d)*68 + f];
        kvpart[((size_t)(bh*32 + chunk))*2048 + idx] = s2;
    }
    if (t < 64) {
        float s2 = kms[0][t] + kms[1][t] + kms[2][t] + kms[3][t];
        kmpart[(size_t)(bh*32 + chunk)*64 + t] = s2;
    }
}

// ---------------------------------------------------------------- reduce kv partials -> kvT bf16 [bh][d][f]; + kmean
__global__ __launch_bounds__(256) void k_kvred2(const float* __restrict__ kvpart, const float* __restrict__ kmpart,
                                                unsigned short* __restrict__ kvT, float* __restrict__ kmean)
{
    int bh = blockIdx.x >> 3, part = blockIdx.x & 7;
    int idx = part*256 + threadIdx.x;   // f*32 + d
    float s = 0.f;
    for (int cidx = 0; cidx < 32; ++cidx) s += kvpart[((size_t)(bh*32 + cidx))*2048 + idx];
    int f = idx >> 5, d = idx & 31;
    kvT[(size_t)bh*2048 + d*64 + f] = f2bf(s * (1.f/16384.f));
    if (part == 0 && threadIdx.x < 64) {
        int tt = threadIdx.x;
        float sm = 0.f;
        for (int cidx = 0; cidx < 32; ++cidx) sm += kmpart[(size_t)(bh*32 + cidx)*64 + tt];
        kmean[bh*64 + tt] = sm * (1.f/16384.f);
    }
}

// ---------------------------------------------------------------- fused q-features (MFMA) + xs (MFMA) -> xsb bf16
// grid (32 chunks, 32 bh); wave owns 128 pos as 4 rounds x 32. LDS ~18KB.
__global__ __launch_bounds__(256) void k_featxs(
    const unsigned short* __restrict__ qb, const float* __restrict__ W, const float* __restrict__ bvec,
    const unsigned int* __restrict__ fsc, const unsigned short* __restrict__ kvT,
    const float* __restrict__ kmean, const unsigned short* __restrict__ xspb, unsigned short* __restrict__ xsb)
{
    __shared__ __align__(16) unsigned short qfs[4][32][72];   // [wave][pos][f]
    int bh = blockIdx.y, b = bh >> 2, h = bh & 3;
    int chunk = blockIdx.x;
    int t = threadIdx.x, w = t >> 6, lane = t & 63;
    int c = lane & 15, g = lane >> 4;
    bf16x8 wb[2];
    #pragma unroll
    for (int et = 0; et < 2; ++et) {
        float4 wa = *reinterpret_cast<const float4*>(&W[(c + et*16)*32 + g*8]);
        float4 wb2 = *reinterpret_cast<const float4*>(&W[(c + et*16)*32 + g*8 + 4]);
        wb[et] = cvt8(wa, wb2);
    }
    float bias0 = bvec[c], bias1 = bvec[c + 16];
    float kml0 = kmean[bh*64 + c],      kml1 = kmean[bh*64 + 16 + c];
    float kmh0 = kmean[bh*64 + 32 + c], kmh1 = kmean[bh*64 + 48 + c];
    bf16x8 bkv[2][2];
    #pragma unroll
    for (int nt = 0; nt < 2; ++nt)
        #pragma unroll
        for (int ks = 0; ks < 2; ++ks)
            bkv[nt][ks] = *reinterpret_cast<const bf16x8*>(&kvT[(size_t)bh*2048 + (nt*16 + c)*64 + ks*32 + g*8]);

    for (int rnd = 0; rnd < 4; ++rnd) {
        int p0 = chunk*512 + w*128 + rnd*32;
        // phase 1: 2 m-tiles of 16 pos
        #pragma unroll
        for (int mt = 0; mt < 2; ++mt) {
            int posA = p0 + mt*16 + c;
            bf16x8 af = *reinterpret_cast<const bf16x8*>(&qb[((size_t)(b*NN + posA))*128 + h*32 + g*8]);
            f32x4 z4 = {0.f,0.f,0.f,0.f};
            f32x4 y0 = __builtin_amdgcn_mfma_f32_16x16x32_bf16(af, wb[0], z4, 0, 0, 0);
            f32x4 y1 = __builtin_amdgcn_mfma_f32_16x16x32_bf16(af, wb[1], z4, 0, 0, 0);
            f32x4 el0, eh0, el1, eh1;
            #pragma unroll
            for (int r = 0; r < 4; ++r) {
                float a0 = 2.f*(y0[r] + bias0);
                float a1 = 2.f*(y1[r] + bias1);
                el0[r] = __expf(a0); eh0[r] = __expf(-a0);
                el1[r] = __expf(a1); eh1[r] = __expf(-a1);
            }
            f32x4 s = el0 + eh0 + el1 + eh1;
            f32x4 wv = el0*kml0 + eh0*kmh0 + el1*kml1 + eh1*kmh1;
            red16x2(s, wv);
            f32x4 zr;
            #pragma unroll
            for (int r = 0; r < 4; ++r) {
                float rs = rcpf(s[r]);
                float z = rcpf(wv[r]*rs + 1e-6f);
                zr[r] = z*rs;
            }
            int posC = mt*16 + g*4;
            #pragma unroll
            for (int r = 0; r < 4; ++r) {
                unsigned int u = fsc[((size_t)h*NN + p0 + posC + r)*16 + c];
                float fsv = bf2f((unsigned short)(u & 0xffffu));
                float fcv = bf2f((unsigned short)(u >> 16));
                qfs[w][posC + r][c]      = f2bf(zr[r]*(el0[r]*fcv + eh0[r]*fsv));
                qfs[w][posC + r][32 + c] = f2bf(zr[r]*(eh0[r]*fcv - el0[r]*fsv));
                qfs[w][posC + r][16 + c] = f2bf(zr[r]*(el1[r] + eh1[r]));
                qfs[w][posC + r][48 + c] = f2bf(zr[r]*(eh1[r] - el1[r]));
            }
        }
        // phase 2: xs = qfs(32x64) @ kv(64x32)
        f32x4 acc[2][2];
        #pragma unroll
        for (int i = 0; i < 2; ++i) { acc[i][0] = (f32x4){0.f,0.f,0.f,0.f}; acc[i][1] = (f32x4){0.f,0.f,0.f,0.f}; }
        #pragma unroll
        for (int ks = 0; ks < 2; ++ks)
            #pragma unroll
            for (int mt = 0; mt < 2; ++mt) {
                bf16x8 af2 = *reinterpret_cast<const bf16x8*>(&qfs[w][mt*16 + c][ks*32 + g*8]);
                acc[mt][0] = __builtin_amdgcn_mfma_f32_16x16x32_bf16(af2, bkv[0][ks], acc[mt][0], 0, 0, 0);
                acc[mt][1] = __builtin_amdgcn_mfma_f32_16x16x32_bf16(af2, bkv[1][ks], acc[mt][1], 0, 0, 0);
            }
        // epilogue: xsb = bf16(xspb + xs)
        #pragma unroll
        for (int mt = 0; mt < 2; ++mt)
            #pragma unroll
            for (int nt = 0; nt < 2; ++nt) {
                int d = nt*16 + c;
                #pragma unroll
                for (int r = 0; r < 4; ++r) {
                    int pos = p0 + mt*16 + g*4 + r;
                    size_t off = ((size_t)(b*NN + pos))*128 + h*32 + d;
                    xsb[off] = f2bf(bf2f(xspb[off]) + acc[mt][nt][r]);
                }
            }
    }
}

// ---------------------------------------------------------------- gram via MFMA + fused norms (bf16 inputs, 64 K-chunks)
__global__ __launch_bounds__(256) void k_gram(const unsigned short* __restrict__ qb, const unsigned short* __restrict__ kb,
                                              float* __restrict__ Gpart,
                                              float* __restrict__ qn2, float* __restrict__ kn2)
{
    __shared__ unsigned short qTs[128][40];
    __shared__ unsigned short kTs[128][40];
    int kc = blockIdx.x, bb = blockIdx.y;
    int t = threadIdx.x, lane = t & 63;
    int wave = t >> 6, wm = wave >> 1, wn = wave & 1;
    int c = t & 127, lh = t >> 7;
    float qa = 0.f, ka = 0.f;
    f32x4 acc[4][4];
    #pragma unroll
    for (int i = 0; i < 4; ++i)
        #pragma unroll
        for (int j = 0; j < 4; ++j) acc[i][j] = (f32x4){0.f,0.f,0.f,0.f};

    for (int kt = 0; kt < 8; ++kt) {
        __syncthreads();
        #pragma unroll
        for (int i = 0; i < 16; ++i) {
            int l = lh*16 + i;
            size_t pos = (size_t)bb*NN + kc*256 + kt*32 + l;
            unsigned short qu = qb[pos*128 + c];
            unsigned short ku = kb[pos*128 + c];
            float qv = bf2f(qu), kvv = bf2f(ku);
            qa += qv*qv; ka += kvv*kvv;
            qTs[c][l] = qu;
            kTs[c][l] = ku;
        }
        __syncthreads();
        bf16x8 af[4];
        #pragma unroll
        for (int mi = 0; mi < 4; ++mi)
            af[mi] = *reinterpret_cast<const bf16x8*>(&qTs[wm*64 + mi*16 + (lane & 15)][(lane >> 4)*8]);
        #pragma unroll
        for (int ni = 0; ni < 4; ++ni) {
            bf16x8 bfr = *reinterpret_cast<const bf16x8*>(&kTs[wn*64 + ni*16 + (lane & 15)][(lane >> 4)*8]);
            #pragma unroll
            for (int mi = 0; mi < 4; ++mi)
                acc[mi][ni] = __builtin_amdgcn_mfma_f32_16x16x32_bf16(af[mi], bfr, acc[mi][ni], 0, 0, 0);
        }
    }
    size_t gb = ((size_t)(bb*64 + kc))*16384;
    #pragma unroll
    for (int mi = 0; mi < 4; ++mi) {
        #pragma unroll
        for (int ni = 0; ni < 4; ++ni) {
            int d = wn*64 + ni*16 + (lane & 15);
            #pragma unroll
            for (int r = 0; r < 4; ++r) {
                int cc = wm*64 + mi*16 + (lane >> 4)*4 + r;
                Gpart[gb + (size_t)cc*128 + d] = acc[mi][ni][r];
            }
        }
    }
    atomicAdd(&qn2[bb*128 + c], qa);
    atomicAdd(&kn2[bb*128 + c], ka);
}

// ---------------------------------------------------------------- channel attention softmax (fused Gpart reduction)
__global__ __launch_bounds__(128) void k_attnsm(const float* __restrict__ Gpart, const float* __restrict__ qn2,
    const float* __restrict__ kn2, const float* __restrict__ temp, float* __restrict__ attn)
{
    __shared__ float red[128];
    int row = blockIdx.x;
    int b = row >> 7, c = row & 127;
    int t = threadIdx.x;
    float s0 = 0.f;
    for (int kc = 0; kc < 64; ++kc)
        s0 += Gpart[((size_t)(b*64 + kc))*16384 + (size_t)c*128 + t];
    float qn = fmaxf(sqrtf(qn2[b*128 + c]), 1e-12f);
    float kn = fmaxf(sqrtf(kn2[b*128 + t]), 1e-12f);
    float val = s0 / (qn*kn) * temp[c];
    red[t] = val; __syncthreads();
    for (int s = 64; s > 0; s >>= 1) { if (t < s) red[t] = fmaxf(red[t], red[t+s]); __syncthreads(); }
    float mm = red[0]; __syncthreads();
    float ev = expf(val - mm);
    red[t] = ev; __syncthreads();
    for (int s = 64; s > 0; s >>= 1) { if (t < s) red[t] += red[t+s]; __syncthreads(); }
    attn[(size_t)row*128 + t] = ev / red[0];
}

// ---------------------------------------------------------------- per-batch B matrix, transposed bf16
__global__ __launch_bounds__(256) void k_bmat(const float* __restrict__ attn, const float* __restrict__ Wp,
                                              unsigned short* __restrict__ BmatT)
{
    int b = blockIdx.y, kk = blockIdx.x, o = threadIdx.x;
    float val;
    if (kk < 128) {
        val = Wp[(size_t)o*256 + kk];
    } else {
        int d = kk - 128;
        __shared__ float a[128];
        if (o < 128) a[o] = attn[((size_t)b*128 + o)*128 + d];
        __syncthreads();
        float acc = 0.f;
        for (int c = 0; c < 128; ++c) acc += a[c] * Wp[(size_t)o*256 + 128 + c];
        val = acc;
    }
    BmatT[((size_t)b*256 + o)*256 + kk] = f2bf(val);
}

// ---------------------------------------------------------------- final MFMA GEMM with T14 prefetch
__global__ __launch_bounds__(256) void k_out_mfma(const unsigned short* __restrict__ xsb,
    const unsigned short* __restrict__ vb, const unsigned short* __restrict__ BmatT,
    const float* __restrict__ bp, float* __restrict__ out)
{
    __shared__ unsigned short Asm[128*64];
    __shared__ unsigned short Bsm[128*64];
    int t = threadIdx.x;
    int lin = blockIdx.y*2 + blockIdx.x;
    int logical = (lin & 7)*256 + (lin >> 3);
    int ntile = logical & 1;
    int mtile = logical >> 1;
    int m0 = mtile * 128;
    int n0 = ntile * 128;
    int b = mtile >> 7;
    int wave = t >> 6, lane = t & 63;
    int wm = wave >> 1, wn = wave & 1;
    int lrow = lane & 15, lk = lane >> 4;
    f32x4 acc[4][4];
    #pragma unroll
    for (int i = 0; i < 4; ++i)
        #pragma unroll
        for (int j = 0; j < 4; ++j) acc[i][j] = (f32x4){0.f,0.f,0.f,0.f};

    int am = t >> 3, ak8 = t & 7;
    uint4 pa4[4];
    #pragma unroll
    for (int p = 0; p < 4; ++p)
        pa4[p] = *reinterpret_cast<const uint4*>(&xsb[(size_t)(m0 + am + p*32)*128 + ak8*8]);

    #pragma unroll
    for (int kt = 0; kt < 4; ++kt) {
        if (kt) __syncthreads();
        #pragma unroll
        for (int p = 0; p < 4; ++p) {
            int m = am + p*32;
            int byte = m*128 + ((ak8 ^ (m & 7)) << 4);
            *reinterpret_cast<uint4*>(reinterpret_cast<char*>(Asm) + byte) = pa4[p];
        }
        {
            int n = t >> 3, k8 = t & 7;
            #pragma unroll
            for (int p = 0; p < 4; ++p, n += 32) {
                uint4 u4 = *reinterpret_cast<const uint4*>(&BmatT[((size_t)b*256 + n0 + n)*256 + kt*64 + k8*8]);
                int byte = n*128 + ((k8 ^ (n & 7)) << 4);
                *reinterpret_cast<uint4*>(reinterpret_cast<char*>(Bsm) + byte) = u4;
            }
        }
        if (kt < 3) {
            const unsigned short* Asrc = ((kt+1) < 2) ? xsb : vb;
            int ka0 = ((kt+1) & 1) * 64;
            #pragma unroll
            for (int p = 0; p < 4; ++p)
                pa4[p] = *reinterpret_cast<const uint4*>(&Asrc[(size_t)(m0 + am + p*32)*128 + ka0 + ak8*8]);
        }
        __syncthreads();
        #pragma unroll
        for (int ks = 0; ks < 2; ++ks) {
            bf16x8 af[4], bfv[4];
            #pragma unroll
            for (int mi = 0; mi < 4; ++mi) {
                int m = wm*64 + mi*16 + lrow;
                int u = (ks*4 + lk) ^ (m & 7);
                af[mi] = *reinterpret_cast<const bf16x8*>(reinterpret_cast<const char*>(Asm) + m*128 + u*16);
            }
            #pragma unroll
            for (int ni = 0; ni < 4; ++ni) {
                int n = wn*64 + ni*16 + lrow;
                int u = (ks*4 + lk) ^ (n & 7);
                bfv[ni] = *reinterpret_cast<const bf16x8*>(reinterpret_cast<const char*>(Bsm) + n*128 + u*16);
            }
            #pragma unroll
            for (int mi = 0; mi < 4; ++mi)
                #pragma unroll
                for (int ni = 0; ni < 4; ++ni)
                    acc[mi][ni] = __builtin_amdgcn_mfma_f32_16x16x32_bf16(af[mi], bfv[ni], acc[mi][ni], 0, 0, 0);
        }
    }
    #pragma unroll
    for (int mi = 0; mi < 4; ++mi) {
        #pragma unroll
        for (int ni = 0; ni < 4; ++ni) {
            int gcol = n0 + wn*64 + ni*16 + lrow;
            float bias = bp[gcol];
            #pragma unroll
            for (int r = 0; r < 4; ++r) {
                size_t grow = (size_t)m0 + wm*64 + mi*16 + lk*4 + r;
                out[grow*256 + gcol] = acc[mi][ni][r] + bias;
            }
        }
    }
}

extern "C" void kernel_launch(void* const* d_in, const int* in_sizes, int n_in,
                              void* d_out, int out_size, void* d_ws, size_t ws_size,
                              hipStream_t stream)
{
    (void)in_sizes; (void)n_in; (void)out_size; (void)ws_size;
    const float* x    = (const float*)d_in[0];
    const float* Wq   = (const float*)d_in[1];
    const float* bq   = (const float*)d_in[2];
    const float* Wk   = (const float*)d_in[3];
    const float* bk   = (const float*)d_in[4];
    const float* Wv   = (const float*)d_in[5];
    const float* bv   = (const float*)d_in[6];
    const float* Whq  = (const float*)d_in[7];
    const float* bhq  = (const float*)d_in[8];
    const float* Whk  = (const float*)d_in[9];
    const float* bhk  = (const float*)d_in[10];
    const float* sinc = (const float*)d_in[11];
    const float* cosc = (const float*)d_in[12];
    const float* lw   = (const float*)d_in[13];
    const float* lb   = (const float*)d_in[14];
    const float* temp = (const float*)d_in[15];
    const float* Wp   = (const float*)d_in[16];
    const float* bp   = (const float*)d_in[17];

    float* out = (float*)d_out;
    float* q   = out + 33554432;
    float* k   = out + 50331648;
    float* ws  = (float*)d_ws;

    unsigned short* xspb = (unsigned short*)(ws + WS_XSPB);
    float* Gpart  = ws + WS_GPART;
    unsigned short* vbuf = (unsigned short*)(ws + WS_VB);
    unsigned short* xsb  = (unsigned short*)(ws + WS_XSB);
    unsigned int* fsc = (unsigned int*)(ws + WS_FS);
    float* inv    = ws + WS_INV;
    float* cs     = ws + WS_CS;
    float* cc     = ws + WS_CC;
    unsigned short* Wc = (unsigned short*)(ws + WS_WCAT);
    float* bcat   = ws + WS_BCAT;
    float* kvpart = ws + WS_KVPART;
    float* kmpart = ws + WS_KMPART;
    unsigned short* kvT = (unsigned short*)(ws + WS_KV);
    float* kmean  = ws + WS_KMEAN;
    float* qn2    = ws + WS_QN2;
    float* kn2    = ws + WS_KN2;
    float* attn   = ws + WS_ATTN;
    unsigned short* BmatT = (unsigned short*)(ws + WS_BMATT);
    unsigned short* qbuf  = (unsigned short*)(ws + WS_QB);
    unsigned short* kbuf  = (unsigned short*)(ws + WS_KB);

    hipMemsetAsync(qn2, 0, 2048*sizeof(float), stream);

    k_setup<<<1, 64, 0, stream>>>(sinc, cosc, inv, cs, cc);
    k_tables<<<4096, 256, 0, stream>>>(inv, cs, cc, fsc);
    k_wprep<<<384, 256, 0, stream>>>(Wq, Wk, Wv, bq, bk, bv, Wc, bcat);
    k_qkv_mfma<<<dim3(3, 1024), 256, 0, stream>>>(x, Wc, bcat, q, k, qbuf, kbuf, vbuf);
    k_conv<<<dim3(8, 128, 8), 256, 0, stream>>>(vbuf, lw, lb, xspb);
    k_featkv<<<dim3(32, 32), 256, 0, stream>>>(kbuf, vbuf, Whk, bhk, fsc, kvpart, kmpart);
    k_kvred2<<<256, 256, 0, stream>>>(kvpart, kmpart, kvT, kmean);
    k_featxs<<<dim3(32, 32), 256, 0, stream>>>(qbuf, Whq, bhq, fsc, kvT, kmean, xspb, xsb);
    k_gram<<<dim3(64, 8), 256, 0, stream>>>(qbuf, kbuf, Gpart, qn2, kn2);
    k_attnsm<<<1024, 128, 0, stream>>>(Gpart, qn2, kn2, temp, attn);
    k_bmat<<<dim3(256, 8), 256, 0, stream>>>(attn, Wp, BmatT);
    k_out_mfma<<<dim3(2, 1024), 256, 0, stream>>>(xsb, vbuf, BmatT, bp, out);
}